// Round 2
// baseline (17529.187 us; speedup 1.0000x reference)
//
#include <hip/hip_runtime.h>
#include <math.h>

#define CCH 256
#define HWP 65536

// ---- ws layout (bytes) ----
static const size_t BUF_B_OFF = 67108864;        // bufA @0 (64MB), bufB @64MB
static const size_t TAIL_OFF  = 134217728;
static const size_t KEYS_OFF  = TAIL_OFF;                // 65536*4
static const size_t HIST_OFF  = TAIL_OFF + 262144;       // 256*4
static const size_t STATE_OFF = TAIL_OFF + 263168;       // small struct
static const size_t IDX_OFF   = TAIL_OFF + 263424;       // 2048*4
static const size_t EQ_OFF    = TAIL_OFF + 271616;       // 4096*4
// overlaid into bufA region (bufA dead after deconvq<128> consumes it):
static const size_t Q_OFF     = 0;
static const size_t K_OFF     = 2097152;
static const size_t V_OFF     = 4194304;
static const size_t OA_OFF    = 6291456;
static const size_t WTI_OFF   = 8388608;                 // in_w^T 768*256*4
static const size_t WTO_OFF   = 9175040;                 // out_w^T 256*256*4
static const size_t SROWS_OFF = 10485760;                // 2048*256*4 sparse s rows

struct SelState { unsigned int P; int kneed; int nGreater; int nEqual; };

__global__ void k_init(unsigned int* hist, SelState* st) {
  int t = threadIdx.x;
  hist[t] = 0;
  if (t == 0) { st->P = 0u; st->kneed = 2048; st->nGreater = 0; st->nEqual = 0; }
}

// 1x1 conv 768->256 on 8x8
__global__ void k_wtconv(const float* __restrict__ swint, const float* __restrict__ w,
                         const float* __restrict__ b, float* __restrict__ out) {
  int co = blockIdx.x, p = threadIdx.x;
  float acc = b[co];
  for (int ci = 0; ci < 768; ++ci) acc += swint[ci * 64 + p] * w[co * 768 + ci];
  out[co * 64 + p] = acc;
}

// deconv 4x4 stride2 pad2 + bias + relu (small stage only, S=8)
template <int S>
__global__ __launch_bounds__(256) void k_deconv(const float* __restrict__ x,
                                                const float* __restrict__ w,
                                                const float* __restrict__ bias,
                                                float* __restrict__ y) {
  const int SO = 2 * S;
  const int TX = SO / 16;
  int co = blockIdx.y;
  int tile = blockIdx.x;
  int ty0 = (tile / TX) * 16, tx0 = (tile % TX) * 16;
  int t = threadIdx.x;
  int ly = t >> 4, lx = t & 15;
  int oy = ty0 + ly, ox = tx0 + lx;
  int iyb = (ty0 >> 1) - 1, ixb = (tx0 >> 1) - 1;
  int p = oy & 1, q = ox & 1;
  int iyA = ((oy + p - 2) >> 1) - iyb;
  int ixA = ((ox + q - 2) >> 1) - ixb;
  int i00 = (3 - p) * 4 + (3 - q);
  int i01 = (3 - p) * 4 + (1 - q);
  int i10 = (1 - p) * 4 + (3 - q);
  int i11 = (1 - p) * 4 + (1 - q);
  __shared__ float lx_s[8][10][10];
  __shared__ float lw_s[8][16];
  float acc = bias[co];
  for (int c0 = 0; c0 < CCH; c0 += 8) {
    __syncthreads();
    for (int i = t; i < 800; i += 256) {
      int u = i / 100, rem = i % 100;
      int r = rem / 10, c = rem % 10;
      int gy = iyb + r, gx = ixb + c;
      float v = 0.f;
      if (gy >= 0 && gy < S && gx >= 0 && gx < S)
        v = x[(size_t)(c0 + u) * S * S + gy * S + gx];
      lx_s[u][r][c] = v;
    }
    if (t < 128) {
      int u = t >> 4, e = t & 15;
      lw_s[u][e] = w[(size_t)(c0 + u) * 4096 + co * 16 + e];
    }
    __syncthreads();
#pragma unroll
    for (int u = 0; u < 8; ++u) {
      acc += lx_s[u][iyA][ixA]     * lw_s[u][i00]
           + lx_s[u][iyA][ixA + 1] * lw_s[u][i01]
           + lx_s[u][iyA + 1][ixA]     * lw_s[u][i10]
           + lx_s[u][iyA + 1][ixA + 1] * lw_s[u][i11];
    }
  }
  acc = fmaxf(acc, 0.f);
  y[(size_t)co * SO * SO + oy * SO + ox] = acc;
}

// deconv 4x4 s2 p2 + relu, multi-co quad kernel: thread owns 2x2 outputs x G co.
// All weight tap indices are wave-uniform -> s_load + v_fma(sgpr operand).
template <int S, int G>
__global__ __launch_bounds__(256) void k_deconvq(const float* __restrict__ x,
                                                 const float* __restrict__ w,
                                                 const float* __restrict__ bias,
                                                 float* __restrict__ y) {
  const int SO = 2 * S;
  const int TX = SO / 32;
  int co0 = blockIdx.y * G;
  int tile = blockIdx.x;
  int ty0 = (tile / TX) * 32, tx0 = (tile % TX) * 32;
  int t = threadIdx.x;
  int qy = t >> 4, qx = t & 15;
  int iyb = (ty0 >> 1) - 1, ixb = (tx0 >> 1) - 1;
  __shared__ float lds[8][18][18];
  float a00[G], a01[G], a10[G], a11[G];
#pragma unroll
  for (int g = 0; g < G; ++g) {
    float bv = bias[co0 + g];
    a00[g] = bv; a01[g] = bv; a10[g] = bv; a11[g] = bv;
  }
  for (int c0 = 0; c0 < CCH; c0 += 8) {
    __syncthreads();
    for (int i = t; i < 2592; i += 256) {
      int u = i / 324, rem = i % 324;
      int r = rem / 18, c = rem % 18;
      int gy = iyb + r, gx = ixb + c;
      float v = 0.f;
      if (gy >= 0 && gy < S && gx >= 0 && gx < S)
        v = x[(size_t)(c0 + u) * S * S + gy * S + gx];
      lds[u][r][c] = v;
    }
    __syncthreads();
#pragma unroll
    for (int u = 0; u < 8; ++u) {
      float P00 = lds[u][qy][qx],     P01 = lds[u][qy][qx + 1],     P02 = lds[u][qy][qx + 2];
      float P10 = lds[u][qy + 1][qx], P11 = lds[u][qy + 1][qx + 1], P12 = lds[u][qy + 1][qx + 2];
      float P20 = lds[u][qy + 2][qx], P21 = lds[u][qy + 2][qx + 1], P22 = lds[u][qy + 2][qx + 2];
#pragma unroll
      for (int g = 0; g < G; ++g) {
        const float* wp = w + ((size_t)(c0 + u) * 256 + co0 + g) * 16;
        a00[g] += P00 * wp[15] + P01 * wp[13] + P10 * wp[7] + P11 * wp[5];
        a01[g] += P01 * wp[14] + P02 * wp[12] + P11 * wp[6] + P12 * wp[4];
        a10[g] += P10 * wp[11] + P11 * wp[9]  + P20 * wp[3] + P21 * wp[1];
        a11[g] += P11 * wp[10] + P12 * wp[8]  + P21 * wp[2] + P22 * wp[0];
      }
    }
  }
  int oy = ty0 + 2 * qy, ox = tx0 + 2 * qx;
#pragma unroll
  for (int g = 0; g < G; ++g) {
    float2 r0 = make_float2(fmaxf(a00[g], 0.f), fmaxf(a01[g], 0.f));
    float2 r1 = make_float2(fmaxf(a10[g], 0.f), fmaxf(a11[g], 0.f));
    *(float2*)&y[(size_t)(co0 + g) * SO * SO + (size_t)oy * SO + ox] = r0;
    *(float2*)&y[(size_t)(co0 + g) * SO * SO + (size_t)(oy + 1) * SO + ox] = r1;
  }
}

// conv 3x3 pad1 + bias, multi-co: thread owns 1 pos x G co; weights wave-uniform.
template <int S, int G>
__global__ __launch_bounds__(256) void k_conv3m(const float* __restrict__ x,
                                                const float* __restrict__ w,
                                                const float* __restrict__ bias,
                                                float* __restrict__ y) {
  const int TX = S / 16;
  int co0 = blockIdx.y * G;
  int tile = blockIdx.x;
  int ty0 = (tile / TX) * 16, tx0 = (tile % TX) * 16;
  int t = threadIdx.x;
  int ly = t >> 4, lx = t & 15;
  __shared__ float lds[8][18][18];
  float acc[G];
#pragma unroll
  for (int g = 0; g < G; ++g) acc[g] = bias[co0 + g];
  for (int c0 = 0; c0 < CCH; c0 += 8) {
    __syncthreads();
    for (int i = t; i < 2592; i += 256) {
      int u = i / 324, rem = i % 324;
      int r = rem / 18, c = rem % 18;
      int gy = ty0 - 1 + r, gx = tx0 - 1 + c;
      float v = 0.f;
      if (gy >= 0 && gy < S && gx >= 0 && gx < S)
        v = x[(size_t)(c0 + u) * S * S + gy * S + gx];
      lds[u][r][c] = v;
    }
    __syncthreads();
#pragma unroll
    for (int u = 0; u < 8; ++u) {
      float p0 = lds[u][ly][lx],     p1 = lds[u][ly][lx + 1],     p2 = lds[u][ly][lx + 2];
      float p3 = lds[u][ly + 1][lx], p4 = lds[u][ly + 1][lx + 1], p5 = lds[u][ly + 1][lx + 2];
      float p6 = lds[u][ly + 2][lx], p7 = lds[u][ly + 2][lx + 1], p8 = lds[u][ly + 2][lx + 2];
#pragma unroll
      for (int g = 0; g < G; ++g) {
        const float* wp = w + ((size_t)(co0 + g) * 256 + (c0 + u)) * 9;
        acc[g] += p0 * wp[0] + p1 * wp[1] + p2 * wp[2]
                + p3 * wp[3] + p4 * wp[4] + p5 * wp[5]
                + p6 * wp[6] + p7 * wp[7] + p8 * wp[8];
      }
    }
  }
#pragma unroll
  for (int g = 0; g < G; ++g)
    y[(size_t)(co0 + g) * S * S + (size_t)(ty0 + ly) * S + (tx0 + lx)] = acc[g];
}

// sparse conv3: compute final conv only at 4 gathered positions per block.
// out[j][co], j = 4*blockIdx.x + jj ; thread = co.
__global__ __launch_bounds__(256) void k_conv3s(const float* __restrict__ x,
                                                const float* __restrict__ w,
                                                const float* __restrict__ bias,
                                                const int* __restrict__ idx,
                                                float* __restrict__ out) {
  __shared__ float sp[4][2304];
  int t = threadIdx.x;
  int j0 = blockIdx.x * 4;
  for (int i = t; i < 9216; i += 256) {
    int jj = i / 2304, r = i % 2304;
    int ci = r / 9, e = r % 9;
    int p = idx[j0 + jj];
    int py = p >> 8, px = p & 255;
    int gy = py - 1 + e / 3, gx = px - 1 + e % 3;
    float v = 0.f;
    if (gy >= 0 && gy < 256 && gx >= 0 && gx < 256)
      v = x[(size_t)ci * HWP + gy * 256 + gx];
    sp[jj][r] = v;
  }
  __syncthreads();
  const float4* w4 = (const float4*)(w + (size_t)t * 2304);
  float bv = bias[t];
  float a0 = bv, a1 = bv, a2 = bv, a3 = bv;
#pragma unroll 2
  for (int i4 = 0; i4 < 576; ++i4) {
    float4 wv = w4[i4];
    int b = i4 * 4;
    a0 += sp[0][b] * wv.x + sp[0][b + 1] * wv.y + sp[0][b + 2] * wv.z + sp[0][b + 3] * wv.w;
    a1 += sp[1][b] * wv.x + sp[1][b + 1] * wv.y + sp[1][b + 2] * wv.z + sp[1][b + 3] * wv.w;
    a2 += sp[2][b] * wv.x + sp[2][b + 1] * wv.y + sp[2][b + 2] * wv.z + sp[2][b + 3] * wv.w;
    a3 += sp[3][b] * wv.x + sp[3][b + 1] * wv.y + sp[3][b + 2] * wv.z + sp[3][b + 3] * wv.w;
  }
  out[(size_t)(j0 + 0) * 256 + t] = a0;
  out[(size_t)(j0 + 1) * 256 + t] = a1;
  out[(size_t)(j0 + 2) * 256 + t] = a2;
  out[(size_t)(j0 + 3) * 256 + t] = a3;
}

// gate logit (sigmoid/bias monotonic -> rank raw dot), to orderable uint key
__global__ void k_gate(const float* __restrict__ down, const float* __restrict__ gw,
                       unsigned int* __restrict__ keys) {
  int p = blockIdx.x * 256 + threadIdx.x;
  float acc = 0.f;
  for (int c = 0; c < CCH; ++c) acc += down[(size_t)c * HWP + p] * gw[c];
  unsigned int u = __float_as_uint(acc);
  keys[p] = (u & 0x80000000u) ? ~u : (u | 0x80000000u);
}

__global__ void k_hist(const unsigned int* __restrict__ keys, unsigned int* hist,
                       const SelState* st, int r) {
  __shared__ unsigned int lh[256];
  int t = threadIdx.x;
  lh[t] = 0;
  __syncthreads();
  unsigned int key = keys[blockIdx.x * 256 + t];
  bool ok = (r == 0) || ((key >> (32 - 8 * r)) == st->P);
  if (ok) atomicAdd(&lh[(key >> (24 - 8 * r)) & 255u], 1u);
  __syncthreads();
  if (lh[t]) atomicAdd(&hist[t], lh[t]);
}

__global__ void k_scan(unsigned int* hist, SelState* st) {
  if (threadIdx.x == 0) {
    int need = st->kneed;
    unsigned int cum = 0;
    for (int b = 255; b >= 0; --b) {
      unsigned int h = hist[b];
      if (cum + h >= (unsigned int)need) {
        st->P = (st->P << 8) | (unsigned int)b;
        st->kneed = need - (int)cum;
        break;
      }
      cum += h;
    }
  }
  __syncthreads();
  hist[threadIdx.x] = 0;
}

__global__ void k_compact(const unsigned int* __restrict__ keys, SelState* st,
                          int* __restrict__ idx, int* __restrict__ eq) {
  int p = blockIdx.x * 256 + threadIdx.x;
  unsigned int key = keys[p];
  unsigned int P = st->P;
  if (key > P) {
    int pos = atomicAdd(&st->nGreater, 1);
    idx[pos] = p;
  } else if (key == P) {
    int e = atomicAdd(&st->nEqual, 1);
    if (e < 4096) eq[e] = p;
  }
}

__global__ void k_finalize(SelState* st, int* idx, int* eq) {
  if (threadIdx.x != 0) return;
  int n = st->nEqual;
  if (n > 4096) n = 4096;
  for (int i = 1; i < n; ++i) {
    int v = eq[i], j = i - 1;
    while (j >= 0 && eq[j] > v) { eq[j + 1] = eq[j]; --j; }
    eq[j + 1] = v;
  }
  int g = st->nGreater;
  for (int i = 0; i < st->kneed; ++i) idx[g + i] = eq[i];
}

__global__ void k_transpose(const float* __restrict__ in, float* __restrict__ out, int rows) {
  int o = blockIdx.x, c = threadIdx.x;
  out[(size_t)c * rows + o] = in[(size_t)o * 256 + c];
}

// gather rows at idx and project to Q,K,V (2048 x 256 each)
__global__ void k_qkv(const float* __restrict__ down, const float* __restrict__ srows,
                      const int* __restrict__ idx, const float* __restrict__ wT,
                      const float* __restrict__ bias, float* __restrict__ Q,
                      float* __restrict__ K, float* __restrict__ V) {
  __shared__ float xq[256], xk[256];
  int j = blockIdx.x, c = threadIdx.x;
  int p = idx[j];
  xq[c] = down[(size_t)c * HWP + p];
  xk[c] = srows[(size_t)j * 256 + c];
  __syncthreads();
  float aq = bias[c], ak = bias[256 + c], av = bias[512 + c];
  for (int i = 0; i < 256; ++i) {
    float xv = xq[i], kv = xk[i];
    aq += xv * wT[i * 768 + c];
    ak += kv * wT[i * 768 + 256 + c];
    av += kv * wT[i * 768 + 512 + c];
  }
  Q[j * 256 + c] = aq;
  K[j * 256 + c] = ak;
  V[j * 256 + c] = av;
}

// one block per (query row, head): full-softmax attention over 2048 keys
__global__ __launch_bounds__(256) void k_attn(const float* __restrict__ Q,
                                              const float* __restrict__ K,
                                              const float* __restrict__ V,
                                              float* __restrict__ O) {
  int jq = blockIdx.x, h = blockIdx.y, t = threadIdx.x;
  int hd0 = h * 32;
  __shared__ float qv[32];
  __shared__ float red[256];
  __shared__ float mat[256 * 33];
  if (t < 32) qv[t] = Q[jq * 256 + hd0 + t];
  __syncthreads();
  const float scale = 0.17677669529663687f;
  float sc[8];
#pragma unroll
  for (int r = 0; r < 8; ++r) {
    const float* kp = K + (size_t)(r * 256 + t) * 256 + hd0;
    float a = 0.f;
#pragma unroll
    for (int d = 0; d < 32; ++d) a += qv[d] * kp[d];
    sc[r] = a * scale;
  }
  float m = sc[0];
#pragma unroll
  for (int r = 1; r < 8; ++r) m = fmaxf(m, sc[r]);
  float s = 0.f;
  float acc[32];
#pragma unroll
  for (int d = 0; d < 32; ++d) acc[d] = 0.f;
#pragma unroll
  for (int r = 0; r < 8; ++r) {
    float wv = __expf(sc[r] - m);
    s += wv;
    const float* vp = V + (size_t)(r * 256 + t) * 256 + hd0;
#pragma unroll
    for (int d = 0; d < 32; ++d) acc[d] += wv * vp[d];
  }
  red[t] = m;
  __syncthreads();
  for (int off = 128; off > 0; off >>= 1) {
    if (t < off) red[t] = fmaxf(red[t], red[t + off]);
    __syncthreads();
  }
  float M = red[0];
  __syncthreads();
  float wsc = __expf(m - M);
  red[t] = s * wsc;
  __syncthreads();
  for (int off = 128; off > 0; off >>= 1) {
    if (t < off) red[t] += red[t + off];
    __syncthreads();
  }
  float S = red[0];
#pragma unroll
  for (int d = 0; d < 32; ++d) mat[t * 33 + d] = acc[d] * wsc;
  __syncthreads();
  if (t < 32) {
    float o = 0.f;
    for (int i = 0; i < 256; ++i) o += mat[i * 33 + t];
    O[jq * 256 + hd0 + t] = o / S;
  }
}

__global__ void k_copy(const float4* __restrict__ in, float4* __restrict__ out, int n4) {
  int i = blockIdx.x * blockDim.x + threadIdx.x;
  int stride = gridDim.x * blockDim.x;
  for (; i < n4; i += stride) out[i] = in[i];
}

// out-projection fused with scatter into final output columns
__global__ void k_outproj(const float* __restrict__ Oa, const float* __restrict__ owT,
                          const float* __restrict__ ob, const int* __restrict__ idx,
                          float* __restrict__ out) {
  __shared__ float xo[256];
  int j = blockIdx.x, c = threadIdx.x;
  xo[c] = Oa[j * 256 + c];
  __syncthreads();
  float a = ob[c];
  for (int i = 0; i < 256; ++i) a += xo[i] * owT[i * 256 + c];
  out[(size_t)c * HWP + idx[j]] = a;
}

extern "C" void kernel_launch(void* const* d_in, const int* in_sizes, int n_in,
                              void* d_out, int out_size, void* d_ws, size_t ws_size,
                              hipStream_t stream) {
  const float* down  = (const float*)d_in[0];
  const float* swint = (const float*)d_in[1];
  const float* wt_w  = (const float*)d_in[2];
  const float* wt_b  = (const float*)d_in[3];
  const float* up_dw = (const float*)d_in[4];
  const float* up_db = (const float*)d_in[5];
  const float* up_cw = (const float*)d_in[6];
  const float* up_cb = (const float*)d_in[7];
  const float* gate_w = (const float*)d_in[8];
  const float* in_w  = (const float*)d_in[10];
  const float* in_b  = (const float*)d_in[11];
  const float* out_w = (const float*)d_in[12];
  const float* out_b = (const float*)d_in[13];
  float* out = (float*)d_out;
  char* ws = (char*)d_ws;

  float* bufA = (float*)ws;
  float* bufB = (float*)(ws + BUF_B_OFF);
  unsigned int* keys = (unsigned int*)(ws + KEYS_OFF);
  unsigned int* hist = (unsigned int*)(ws + HIST_OFF);
  SelState* st = (SelState*)(ws + STATE_OFF);
  int* idx = (int*)(ws + IDX_OFF);
  int* eq = (int*)(ws + EQ_OFF);
  float* Q = (float*)(ws + Q_OFF);
  float* Km = (float*)(ws + K_OFF);
  float* V = (float*)(ws + V_OFF);
  float* Oa = (float*)(ws + OA_OFF);
  float* wTi = (float*)(ws + WTI_OFF);
  float* wTo = (float*)(ws + WTO_OFF);
  float* srows = (float*)(ws + SROWS_OFF);

  k_init<<<1, 256, 0, stream>>>(hist, st);

  // gate + exact top-k (radix select over orderable keys)
  k_gate<<<256, 256, 0, stream>>>(down, gate_w, keys);
  for (int r = 0; r < 4; ++r) {
    k_hist<<<256, 256, 0, stream>>>(keys, hist, st, r);
    k_scan<<<1, 256, 0, stream>>>(hist, st);
  }
  k_compact<<<256, 256, 0, stream>>>(keys, st, idx, eq);
  k_finalize<<<1, 64, 0, stream>>>(st, idx, eq);

  // passthrough copy of down into output
  k_copy<<<4096, 256, 0, stream>>>((const float4*)down, (float4*)out, 4194304);

  // upsampler chain (A/B ping-pong)
  k_wtconv<<<256, 64, 0, stream>>>(swint, wt_w, wt_b, bufA);
  k_deconv<8><<<dim3(1, 256), 256, 0, stream>>>(bufA, up_dw, up_db, bufB);
  k_conv3m<16, 4><<<dim3(1, 64), 256, 0, stream>>>(bufB, up_cw, up_cb, bufA);
  k_deconvq<16, 4><<<dim3(1, 64), 256, 0, stream>>>(bufA, up_dw + 1048576, up_db + 256, bufB);
  k_conv3m<32, 8><<<dim3(4, 32), 256, 0, stream>>>(bufB, up_cw + 589824, up_cb + 256, bufA);
  k_deconvq<32, 8><<<dim3(4, 32), 256, 0, stream>>>(bufA, up_dw + 2097152, up_db + 512, bufB);
  k_conv3m<64, 16><<<dim3(16, 16), 256, 0, stream>>>(bufB, up_cw + 1179648, up_cb + 512, bufA);
  k_deconvq<64, 16><<<dim3(16, 16), 256, 0, stream>>>(bufA, up_dw + 3145728, up_db + 768, bufB);
  k_conv3m<128, 16><<<dim3(64, 16), 256, 0, stream>>>(bufB, up_cw + 1769472, up_cb + 768, bufA);
  k_deconvq<128, 16><<<dim3(64, 16), 256, 0, stream>>>(bufA, up_dw + 4194304, up_db + 1024, bufB);

  // final conv3 computed only at the 2048 gathered positions
  k_conv3s<<<512, 256, 0, stream>>>(bufB, up_cw + 2359296, up_cb + 1024, idx, srows);

  // attention path (bufA region is dead now; Q/K/V/O/wT/srows live there)
  k_transpose<<<768, 256, 0, stream>>>(in_w, wTi, 768);
  k_transpose<<<256, 256, 0, stream>>>(out_w, wTo, 256);
  k_qkv<<<2048, 256, 0, stream>>>(down, srows, idx, wTi, in_b, Q, Km, V);
  k_attn<<<dim3(2048, 8), 256, 0, stream>>>(Q, Km, V, Oa);
  k_outproj<<<2048, 256, 0, stream>>>(Oa, wTo, out_b, idx, out);
}

// Round 3
// 5654.329 us; speedup vs baseline: 3.1001x; 3.1001x over previous
//
#include <hip/hip_runtime.h>
#include <math.h>

#define CCH 256
#define HWP 65536

// ---- ws layout (bytes) ----
static const size_t BUF_B_OFF = 67108864;        // bufA @0 (64MB), bufB @64MB
static const size_t TAIL_OFF  = 134217728;
static const size_t KEYS_OFF  = TAIL_OFF;                // 65536*4
static const size_t HIST_OFF  = TAIL_OFF + 262144;       // 256*4
static const size_t STATE_OFF = TAIL_OFF + 263168;       // small struct
static const size_t IDX_OFF   = TAIL_OFF + 263424;       // 2048*4
static const size_t EQ_OFF    = TAIL_OFF + 271616;       // 4096*4
// overlaid into bufA region (bufA dead once deconv2<128> has consumed it):
static const size_t Q_OFF     = 0;
static const size_t K_OFF     = 2097152;
static const size_t V_OFF     = 4194304;
static const size_t OA_OFF    = 6291456;
static const size_t WTI_OFF   = 8388608;                 // in_w^T 768*256*4
static const size_t WTO_OFF   = 9437184;                 // out_w^T 256*256*4
static const size_t SROWS_OFF = 10485760;                // 2048*256*4 sparse s rows
static const size_t WT5_OFF   = 20971520;                // transposed stage-5 conv w 2304*256*4

struct SelState { unsigned int P; int kneed; int nGreater; int nEqual; };

__global__ void k_init(unsigned int* hist, SelState* st) {
  int t = threadIdx.x;
  hist[t] = 0;
  if (t == 0) { st->P = 0u; st->kneed = 2048; st->nGreater = 0; st->nEqual = 0; }
}

// 1x1 conv 768->256 on 8x8
__global__ void k_wtconv(const float* __restrict__ swint, const float* __restrict__ w,
                         const float* __restrict__ b, float* __restrict__ out) {
  int co = blockIdx.x, p = threadIdx.x;
  float acc = b[co];
  for (int ci = 0; ci < 768; ++ci) acc += swint[ci * 64 + p] * w[co * 768 + ci];
  out[co * 64 + p] = acc;
}

// deconv 4x4 stride2 pad2 + bias + relu (S=8 only; LDS weights, known-good)
template <int S>
__global__ __launch_bounds__(256) void k_deconv(const float* __restrict__ x,
                                                const float* __restrict__ w,
                                                const float* __restrict__ bias,
                                                float* __restrict__ y) {
  const int SO = 2 * S;
  const int TX = SO / 16;
  int co = blockIdx.y;
  int tile = blockIdx.x;
  int ty0 = (tile / TX) * 16, tx0 = (tile % TX) * 16;
  int t = threadIdx.x;
  int ly = t >> 4, lx = t & 15;
  int oy = ty0 + ly, ox = tx0 + lx;
  int iyb = (ty0 >> 1) - 1, ixb = (tx0 >> 1) - 1;
  int p = oy & 1, q = ox & 1;
  int iyA = ((oy + p - 2) >> 1) - iyb;
  int ixA = ((ox + q - 2) >> 1) - ixb;
  int i00 = (3 - p) * 4 + (3 - q);
  int i01 = (3 - p) * 4 + (1 - q);
  int i10 = (1 - p) * 4 + (3 - q);
  int i11 = (1 - p) * 4 + (1 - q);
  __shared__ float lx_s[8][10][10];
  __shared__ float lw_s[8][16];
  float acc = bias[co];
  for (int c0 = 0; c0 < CCH; c0 += 8) {
    __syncthreads();
    for (int i = t; i < 800; i += 256) {
      int u = i / 100, rem = i % 100;
      int r = rem / 10, c = rem % 10;
      int gy = iyb + r, gx = ixb + c;
      float v = 0.f;
      if (gy >= 0 && gy < S && gx >= 0 && gx < S)
        v = x[(size_t)(c0 + u) * S * S + gy * S + gx];
      lx_s[u][r][c] = v;
    }
    if (t < 128) {
      int u = t >> 4, e = t & 15;
      lw_s[u][e] = w[(size_t)(c0 + u) * 4096 + co * 16 + e];
    }
    __syncthreads();
#pragma unroll
    for (int u = 0; u < 8; ++u) {
      acc += lx_s[u][iyA][ixA]     * lw_s[u][i00]
           + lx_s[u][iyA][ixA + 1] * lw_s[u][i01]
           + lx_s[u][iyA + 1][ixA]     * lw_s[u][i10]
           + lx_s[u][iyA + 1][ixA + 1] * lw_s[u][i11];
    }
  }
  acc = fmaxf(acc, 0.f);
  y[(size_t)co * SO * SO + oy * SO + ox] = acc;
}

// deconv v2: 32x32 out tile, thread = 2x2 quad, G co, LDS weights (broadcast).
template <int S, int G>
__global__ __launch_bounds__(256) void k_deconv2(const float* __restrict__ x,
                                                 const float* __restrict__ w,
                                                 const float* __restrict__ bias,
                                                 float* __restrict__ y) {
  const int SO = 2 * S;
  const int TX = SO / 32;
  int co0 = blockIdx.y * G;
  int tile = blockIdx.x;
  int ty0 = (tile / TX) * 32, tx0 = (tile % TX) * 32;
  int t = threadIdx.x;
  int qy = t >> 4, qx = t & 15;
  int iyb = (ty0 >> 1) - 1, ixb = (tx0 >> 1) - 1;
  __shared__ float in_s[8][18][19];
  __shared__ float wg_s[8 * G * 16];
  float a[G][2][2];
#pragma unroll
  for (int g = 0; g < G; ++g) {
    float bv = bias[co0 + g];
    a[g][0][0] = bv; a[g][0][1] = bv; a[g][1][0] = bv; a[g][1][1] = bv;
  }
  for (int c0 = 0; c0 < CCH; c0 += 8) {
    __syncthreads();
    for (int i = t; i < 8 * 18 * 19; i += 256) {
      int u = i / 342, rem = i % 342;
      int r = rem / 19, c = rem % 19;
      if (c < 18) {
        int gy = iyb + r, gx = ixb + c;
        float v = 0.f;
        if (gy >= 0 && gy < S && gx >= 0 && gx < S)
          v = x[(size_t)(c0 + u) * S * S + gy * S + gx];
        in_s[u][r][c] = v;
      }
    }
    for (int i = t; i < 8 * G * 16; i += 256) {
      int u = i / (G * 16), rem = i % (G * 16);
      int g = rem / 16, e = rem % 16;
      wg_s[i] = w[((size_t)(c0 + u) * 256 + co0 + g) * 16 + e];
    }
    __syncthreads();
#pragma unroll
    for (int u = 0; u < 8; ++u) {
      float P00 = in_s[u][qy][qx],     P01 = in_s[u][qy][qx + 1],     P02 = in_s[u][qy][qx + 2];
      float P10 = in_s[u][qy + 1][qx], P11 = in_s[u][qy + 1][qx + 1], P12 = in_s[u][qy + 1][qx + 2];
      float P20 = in_s[u][qy + 2][qx], P21 = in_s[u][qy + 2][qx + 1], P22 = in_s[u][qy + 2][qx + 2];
#pragma unroll
      for (int g = 0; g < G; ++g) {
        const float4* wf = (const float4*)&wg_s[(u * G + g) * 16];
        float4 A = wf[0], B = wf[1], C = wf[2], D = wf[3];
        a[g][0][0] += P00 * D.w + P01 * D.y + P10 * B.w + P11 * B.y;
        a[g][0][1] += P01 * D.z + P02 * D.x + P11 * B.z + P12 * B.x;
        a[g][1][0] += P10 * C.w + P11 * C.y + P20 * A.w + P21 * A.y;
        a[g][1][1] += P11 * C.z + P12 * C.x + P21 * A.z + P22 * A.x;
      }
    }
  }
  int oy = ty0 + 2 * qy, ox = tx0 + 2 * qx;
#pragma unroll
  for (int g = 0; g < G; ++g) {
    float2 r0 = make_float2(fmaxf(a[g][0][0], 0.f), fmaxf(a[g][0][1], 0.f));
    float2 r1 = make_float2(fmaxf(a[g][1][0], 0.f), fmaxf(a[g][1][1], 0.f));
    *(float2*)&y[(size_t)(co0 + g) * SO * SO + (size_t)oy * SO + ox] = r0;
    *(float2*)&y[(size_t)(co0 + g) * SO * SO + (size_t)(oy + 1) * SO + ox] = r1;
  }
}

// conv3 v2: 32x32 tile, thread = 2x2 quad, G co, LDS weights (broadcast).
template <int S, int G>
__global__ __launch_bounds__(256) void k_conv3q(const float* __restrict__ x,
                                                const float* __restrict__ w,
                                                const float* __restrict__ bias,
                                                float* __restrict__ y) {
  const int TX = S / 32;
  int co0 = blockIdx.y * G;
  int tile = blockIdx.x;
  int ty0 = (tile / TX) * 32, tx0 = (tile % TX) * 32;
  int t = threadIdx.x;
  int qy = t >> 4, qx = t & 15;
  __shared__ float in_s[4][34][35];
  __shared__ float wg_s[4 * G * 12];
  float acc[G][2][2];
#pragma unroll
  for (int g = 0; g < G; ++g) {
    float bv = bias[co0 + g];
    acc[g][0][0] = bv; acc[g][0][1] = bv; acc[g][1][0] = bv; acc[g][1][1] = bv;
  }
  for (int c0 = 0; c0 < CCH; c0 += 4) {
    __syncthreads();
    for (int i = t; i < 4 * 34 * 35; i += 256) {
      int u = i / 1190, rem = i % 1190;
      int r = rem / 35, c = rem % 35;
      if (c < 34) {
        int gy = ty0 - 1 + r, gx = tx0 - 1 + c;
        float v = 0.f;
        if (gy >= 0 && gy < S && gx >= 0 && gx < S)
          v = x[(size_t)(c0 + u) * S * S + gy * S + gx];
        in_s[u][r][c] = v;
      }
    }
    for (int i = t; i < 4 * G * 9; i += 256) {
      int u = i / (G * 9), rem = i % (G * 9);
      int g = rem / 9, e = rem % 9;
      wg_s[(u * G + g) * 12 + e] = w[((size_t)(co0 + g) * 256 + c0 + u) * 9 + e];
    }
    __syncthreads();
#pragma unroll
    for (int u = 0; u < 4; ++u) {
      float p[4][4];
#pragma unroll
      for (int r = 0; r < 4; ++r)
#pragma unroll
        for (int c = 0; c < 4; ++c) p[r][c] = in_s[u][2 * qy + r][2 * qx + c];
#pragma unroll
      for (int g = 0; g < G; ++g) {
        const float* wp = &wg_s[(u * G + g) * 12];
        float w0 = wp[0], w1 = wp[1], w2 = wp[2], w3 = wp[3], w4v = wp[4],
              w5 = wp[5], w6 = wp[6], w7 = wp[7], w8 = wp[8];
#pragma unroll
        for (int sy = 0; sy < 2; ++sy)
#pragma unroll
          for (int sx = 0; sx < 2; ++sx)
            acc[g][sy][sx] += p[sy][sx] * w0 + p[sy][sx + 1] * w1 + p[sy][sx + 2] * w2
                            + p[sy + 1][sx] * w3 + p[sy + 1][sx + 1] * w4v + p[sy + 1][sx + 2] * w5
                            + p[sy + 2][sx] * w6 + p[sy + 2][sx + 1] * w7 + p[sy + 2][sx + 2] * w8;
      }
    }
  }
#pragma unroll
  for (int g = 0; g < G; ++g)
#pragma unroll
    for (int sy = 0; sy < 2; ++sy) {
      float2 r2 = make_float2(acc[g][sy][0], acc[g][sy][1]);
      *(float2*)&y[(size_t)(co0 + g) * S * S + (size_t)(ty0 + 2 * qy + sy) * S + (tx0 + 2 * qx)] = r2;
    }
}

// conv3 for S=16: single tile 16x16, 1 pos/thread, G co, LDS weights.
template <int G>
__global__ __launch_bounds__(256) void k_conv3t(const float* __restrict__ x,
                                                const float* __restrict__ w,
                                                const float* __restrict__ bias,
                                                float* __restrict__ y) {
  int co0 = blockIdx.y * G;
  int t = threadIdx.x;
  int ly = t >> 4, lx = t & 15;
  __shared__ float in_s[4][18][19];
  __shared__ float wg_s[4 * G * 12];
  float acc[G];
#pragma unroll
  for (int g = 0; g < G; ++g) acc[g] = bias[co0 + g];
  for (int c0 = 0; c0 < CCH; c0 += 4) {
    __syncthreads();
    for (int i = t; i < 4 * 18 * 19; i += 256) {
      int u = i / 342, rem = i % 342;
      int r = rem / 19, c = rem % 19;
      if (c < 18) {
        int gy = r - 1, gx = c - 1;
        float v = 0.f;
        if (gy >= 0 && gy < 16 && gx >= 0 && gx < 16)
          v = x[(size_t)(c0 + u) * 256 + gy * 16 + gx];
        in_s[u][r][c] = v;
      }
    }
    for (int i = t; i < 4 * G * 9; i += 256) {
      int u = i / (G * 9), rem = i % (G * 9);
      int g = rem / 9, e = rem % 9;
      wg_s[(u * G + g) * 12 + e] = w[((size_t)(co0 + g) * 256 + c0 + u) * 9 + e];
    }
    __syncthreads();
#pragma unroll
    for (int u = 0; u < 4; ++u) {
      float p[3][3];
#pragma unroll
      for (int r = 0; r < 3; ++r)
#pragma unroll
        for (int c = 0; c < 3; ++c) p[r][c] = in_s[u][ly + r][lx + c];
#pragma unroll
      for (int g = 0; g < G; ++g) {
        const float* wp = &wg_s[(u * G + g) * 12];
        acc[g] += p[0][0] * wp[0] + p[0][1] * wp[1] + p[0][2] * wp[2]
                + p[1][0] * wp[3] + p[1][1] * wp[4] + p[1][2] * wp[5]
                + p[2][0] * wp[6] + p[2][1] * wp[7] + p[2][2] * wp[8];
      }
    }
  }
#pragma unroll
  for (int g = 0; g < G; ++g)
    y[(size_t)(co0 + g) * 256 + ly * 16 + lx] = acc[g];
}

// transpose stage-5 conv weights: w[co][ci*9+e] -> wt[(ci*9+e)][co]
__global__ void k_wt5(const float* __restrict__ w, float* __restrict__ wt) {
  int e9 = blockIdx.x;
  int co = threadIdx.x;
  int ci = e9 / 9, e = e9 % 9;
  wt[(size_t)e9 * 256 + co] = w[((size_t)co * 256 + ci) * 9 + e];
}

// sparse final conv3 at 8 gathered positions per block, transposed weights.
__global__ __launch_bounds__(256) void k_conv3sT(const float* __restrict__ x,
                                                 const float* __restrict__ wt,
                                                 const float* __restrict__ bias,
                                                 const int* __restrict__ idx,
                                                 float* __restrict__ out) {
  __shared__ float sp[8][2304];
  int t = threadIdx.x;
  int j0 = blockIdx.x * 8;
  for (int i = t; i < 8 * 2304; i += 256) {
    int jj = i / 2304, r = i % 2304;
    int ci = r / 9, e = r % 9;
    int p = idx[j0 + jj];
    int py = p >> 8, px = p & 255;
    int gy = py - 1 + e / 3, gx = px - 1 + e % 3;
    float v = 0.f;
    if (gy >= 0 && gy < 256 && gx >= 0 && gx < 256)
      v = x[(size_t)ci * HWP + gy * 256 + gx];
    sp[jj][r] = v;
  }
  __syncthreads();
  float bv = bias[t];
  float a[8];
#pragma unroll
  for (int jj = 0; jj < 8; ++jj) a[jj] = bv;
  for (int e4 = 0; e4 < 576; ++e4) {
    float w0 = wt[(size_t)(4 * e4 + 0) * 256 + t];
    float w1 = wt[(size_t)(4 * e4 + 1) * 256 + t];
    float w2 = wt[(size_t)(4 * e4 + 2) * 256 + t];
    float w3 = wt[(size_t)(4 * e4 + 3) * 256 + t];
#pragma unroll
    for (int jj = 0; jj < 8; ++jj) {
      float4 s = ((const float4*)sp[jj])[e4];
      a[jj] += s.x * w0 + s.y * w1 + s.z * w2 + s.w * w3;
    }
  }
#pragma unroll
  for (int jj = 0; jj < 8; ++jj) out[(size_t)(j0 + jj) * 256 + t] = a[jj];
}

// fused: passthrough copy of down into out + gate keys
__global__ void k_gatecopy(const float* __restrict__ down, const float* __restrict__ gw,
                           float* __restrict__ out, unsigned int* __restrict__ keys) {
  int p = blockIdx.x * 256 + threadIdx.x;
  float acc = 0.f;
  for (int c = 0; c < CCH; ++c) {
    float v = down[(size_t)c * HWP + p];
    out[(size_t)c * HWP + p] = v;
    acc += v * gw[c];
  }
  unsigned int u = __float_as_uint(acc);
  keys[p] = (u & 0x80000000u) ? ~u : (u | 0x80000000u);
}

__global__ void k_hist(const unsigned int* __restrict__ keys, unsigned int* hist,
                       const SelState* st, int r) {
  __shared__ unsigned int lh[256];
  int t = threadIdx.x;
  lh[t] = 0;
  __syncthreads();
  unsigned int key = keys[blockIdx.x * 256 + t];
  bool ok = (r == 0) || ((key >> (32 - 8 * r)) == st->P);
  if (ok) atomicAdd(&lh[(key >> (24 - 8 * r)) & 255u], 1u);
  __syncthreads();
  if (lh[t]) atomicAdd(&hist[t], lh[t]);
}

__global__ void k_scan(unsigned int* hist, SelState* st) {
  if (threadIdx.x == 0) {
    int need = st->kneed;
    unsigned int cum = 0;
    for (int b = 255; b >= 0; --b) {
      unsigned int h = hist[b];
      if (cum + h >= (unsigned int)need) {
        st->P = (st->P << 8) | (unsigned int)b;
        st->kneed = need - (int)cum;
        break;
      }
      cum += h;
    }
  }
  __syncthreads();
  hist[threadIdx.x] = 0;
}

__global__ void k_compact(const unsigned int* __restrict__ keys, SelState* st,
                          int* __restrict__ idx, int* __restrict__ eq) {
  int p = blockIdx.x * 256 + threadIdx.x;
  unsigned int key = keys[p];
  unsigned int P = st->P;
  if (key > P) {
    int pos = atomicAdd(&st->nGreater, 1);
    idx[pos] = p;
  } else if (key == P) {
    int e = atomicAdd(&st->nEqual, 1);
    if (e < 4096) eq[e] = p;
  }
}

__global__ void k_finalize(SelState* st, int* idx, int* eq) {
  if (threadIdx.x != 0) return;
  int n = st->nEqual;
  if (n > 4096) n = 4096;
  for (int i = 1; i < n; ++i) {
    int v = eq[i], j = i - 1;
    while (j >= 0 && eq[j] > v) { eq[j + 1] = eq[j]; --j; }
    eq[j + 1] = v;
  }
  int g = st->nGreater;
  for (int i = 0; i < st->kneed; ++i) idx[g + i] = eq[i];
}

__global__ void k_transpose(const float* __restrict__ in, float* __restrict__ out, int rows) {
  int o = blockIdx.x, c = threadIdx.x;
  out[(size_t)c * rows + o] = in[(size_t)o * 256 + c];
}

// gather rows at idx and project to Q,K,V (2048 x 256 each)
__global__ void k_qkv(const float* __restrict__ down, const float* __restrict__ srows,
                      const int* __restrict__ idx, const float* __restrict__ wT,
                      const float* __restrict__ bias, float* __restrict__ Q,
                      float* __restrict__ K, float* __restrict__ V) {
  __shared__ float xq[256], xk[256];
  int j = blockIdx.x, c = threadIdx.x;
  int p = idx[j];
  xq[c] = down[(size_t)c * HWP + p];
  xk[c] = srows[(size_t)j * 256 + c];
  __syncthreads();
  float aq = bias[c], ak = bias[256 + c], av = bias[512 + c];
  for (int i = 0; i < 256; ++i) {
    float xv = xq[i], kv = xk[i];
    aq += xv * wT[i * 768 + c];
    ak += kv * wT[i * 768 + 256 + c];
    av += kv * wT[i * 768 + 512 + c];
  }
  Q[j * 256 + c] = aq;
  K[j * 256 + c] = ak;
  V[j * 256 + c] = av;
}

// one block per (query row, head): full-softmax attention over 2048 keys
__global__ __launch_bounds__(256) void k_attn(const float* __restrict__ Q,
                                              const float* __restrict__ K,
                                              const float* __restrict__ V,
                                              float* __restrict__ O) {
  int jq = blockIdx.x, h = blockIdx.y, t = threadIdx.x;
  int hd0 = h * 32;
  __shared__ float qv[32];
  __shared__ float red[256];
  __shared__ float mat[256 * 33];
  if (t < 32) qv[t] = Q[jq * 256 + hd0 + t];
  __syncthreads();
  const float scale = 0.17677669529663687f;
  float sc[8];
#pragma unroll
  for (int r = 0; r < 8; ++r) {
    const float* kp = K + (size_t)(r * 256 + t) * 256 + hd0;
    float aa = 0.f;
#pragma unroll
    for (int d = 0; d < 32; ++d) aa += qv[d] * kp[d];
    sc[r] = aa * scale;
  }
  float m = sc[0];
#pragma unroll
  for (int r = 1; r < 8; ++r) m = fmaxf(m, sc[r]);
  float s = 0.f;
  float acc[32];
#pragma unroll
  for (int d = 0; d < 32; ++d) acc[d] = 0.f;
#pragma unroll
  for (int r = 0; r < 8; ++r) {
    float wv = __expf(sc[r] - m);
    s += wv;
    const float* vp = V + (size_t)(r * 256 + t) * 256 + hd0;
#pragma unroll
    for (int d = 0; d < 32; ++d) acc[d] += wv * vp[d];
  }
  red[t] = m;
  __syncthreads();
  for (int off = 128; off > 0; off >>= 1) {
    if (t < off) red[t] = fmaxf(red[t], red[t + off]);
    __syncthreads();
  }
  float M = red[0];
  __syncthreads();
  float wsc = __expf(m - M);
  red[t] = s * wsc;
  __syncthreads();
  for (int off = 128; off > 0; off >>= 1) {
    if (t < off) red[t] += red[t + off];
    __syncthreads();
  }
  float S = red[0];
#pragma unroll
  for (int d = 0; d < 32; ++d) mat[t * 33 + d] = acc[d] * wsc;
  __syncthreads();
  if (t < 32) {
    float o = 0.f;
    for (int i = 0; i < 256; ++i) o += mat[i * 33 + t];
    O[jq * 256 + hd0 + t] = o / S;
  }
}

// out-projection fused with scatter into final output columns
__global__ void k_outproj(const float* __restrict__ Oa, const float* __restrict__ owT,
                          const float* __restrict__ ob, const int* __restrict__ idx,
                          float* __restrict__ out) {
  __shared__ float xo[256];
  int j = blockIdx.x, c = threadIdx.x;
  xo[c] = Oa[j * 256 + c];
  __syncthreads();
  float aa = ob[c];
  for (int i = 0; i < 256; ++i) aa += xo[i] * owT[i * 256 + c];
  out[(size_t)c * HWP + idx[j]] = aa;
}

extern "C" void kernel_launch(void* const* d_in, const int* in_sizes, int n_in,
                              void* d_out, int out_size, void* d_ws, size_t ws_size,
                              hipStream_t stream) {
  const float* down  = (const float*)d_in[0];
  const float* swint = (const float*)d_in[1];
  const float* wt_w  = (const float*)d_in[2];
  const float* wt_b  = (const float*)d_in[3];
  const float* up_dw = (const float*)d_in[4];
  const float* up_db = (const float*)d_in[5];
  const float* up_cw = (const float*)d_in[6];
  const float* up_cb = (const float*)d_in[7];
  const float* gate_w = (const float*)d_in[8];
  const float* in_w  = (const float*)d_in[10];
  const float* in_b  = (const float*)d_in[11];
  const float* out_w = (const float*)d_in[12];
  const float* out_b = (const float*)d_in[13];
  float* out = (float*)d_out;
  char* ws = (char*)d_ws;

  float* bufA = (float*)ws;
  float* bufB = (float*)(ws + BUF_B_OFF);
  unsigned int* keys = (unsigned int*)(ws + KEYS_OFF);
  unsigned int* hist = (unsigned int*)(ws + HIST_OFF);
  SelState* st = (SelState*)(ws + STATE_OFF);
  int* idx = (int*)(ws + IDX_OFF);
  int* eq = (int*)(ws + EQ_OFF);
  float* Q = (float*)(ws + Q_OFF);
  float* Km = (float*)(ws + K_OFF);
  float* V = (float*)(ws + V_OFF);
  float* Oa = (float*)(ws + OA_OFF);
  float* wTi = (float*)(ws + WTI_OFF);
  float* wTo = (float*)(ws + WTO_OFF);
  float* srows = (float*)(ws + SROWS_OFF);
  float* wt5 = (float*)(ws + WT5_OFF);

  k_init<<<1, 256, 0, stream>>>(hist, st);

  // fused gate + passthrough copy, then exact top-k (radix select)
  k_gatecopy<<<256, 256, 0, stream>>>(down, gate_w, out, keys);
  for (int r = 0; r < 4; ++r) {
    k_hist<<<256, 256, 0, stream>>>(keys, hist, st, r);
    k_scan<<<1, 256, 0, stream>>>(hist, st);
  }
  k_compact<<<256, 256, 0, stream>>>(keys, st, idx, eq);
  k_finalize<<<1, 64, 0, stream>>>(st, idx, eq);

  // upsampler chain (A/B ping-pong)
  k_wtconv<<<256, 64, 0, stream>>>(swint, wt_w, wt_b, bufA);
  k_deconv<8><<<dim3(1, 256), 256, 0, stream>>>(bufA, up_dw, up_db, bufB);
  k_conv3t<4><<<dim3(1, 64), 256, 0, stream>>>(bufB, up_cw, up_cb, bufA);
  k_deconv2<16, 4><<<dim3(1, 64), 256, 0, stream>>>(bufA, up_dw + 1048576, up_db + 256, bufB);
  k_conv3q<32, 4><<<dim3(1, 64), 256, 0, stream>>>(bufB, up_cw + 589824, up_cb + 256, bufA);
  k_deconv2<32, 4><<<dim3(4, 64), 256, 0, stream>>>(bufA, up_dw + 2097152, up_db + 512, bufB);
  k_conv3q<64, 4><<<dim3(4, 64), 256, 0, stream>>>(bufB, up_cw + 1179648, up_cb + 512, bufA);
  k_deconv2<64, 8><<<dim3(16, 32), 256, 0, stream>>>(bufA, up_dw + 3145728, up_db + 768, bufB);
  k_conv3q<128, 8><<<dim3(16, 32), 256, 0, stream>>>(bufB, up_cw + 1769472, up_cb + 768, bufA);
  k_deconv2<128, 8><<<dim3(64, 32), 256, 0, stream>>>(bufA, up_dw + 4194304, up_db + 1024, bufB);

  // bufA is dead now: transposed weights + attention overlays live there
  k_wt5<<<2304, 256, 0, stream>>>(up_cw + 2359296, wt5);
  k_transpose<<<768, 256, 0, stream>>>(in_w, wTi, 768);
  k_transpose<<<256, 256, 0, stream>>>(out_w, wTo, 256);

  // final conv3 only at the 2048 gathered positions
  k_conv3sT<<<256, 256, 0, stream>>>(bufB, wt5, up_cb + 1024, idx, srows);

  // attention path
  k_qkv<<<2048, 256, 0, stream>>>(down, srows, idx, wTi, in_b, Q, Km, V);
  k_attn<<<dim3(2048, 8), 256, 0, stream>>>(Q, Km, V, Oa);
  k_outproj<<<2048, 256, 0, stream>>>(Oa, wTo, out_b, idx, out);
}

// Round 4
// 2183.607 us; speedup vs baseline: 8.0276x; 2.5894x over previous
//
#include <hip/hip_runtime.h>
#include <math.h>

#define CCH 256
#define HWP 65536
#define PCI 40   // padded ci stride (shorts) in LDS: 80B rows -> 16B aligned, ~2-way banks

typedef short short8 __attribute__((ext_vector_type(8)));
typedef float f32x4 __attribute__((ext_vector_type(4)));
typedef unsigned short us4 __attribute__((ext_vector_type(4)));

__device__ inline unsigned short f2bf(float f) {
  unsigned u = __float_as_uint(f);
  return (unsigned short)((u + 0x7FFFu + ((u >> 16) & 1u)) >> 16);
}

__device__ inline void mfma_bf16(f32x4& d, short8 a, short8 b) {
  asm volatile("v_mfma_f32_16x16x32_bf16 %0, %1, %2, %0" : "+v"(d) : "v"(a), "v"(b));
}

// ---- ws layout (bytes) ----
static const size_t BUF_B_OFF = 67108864;        // bufA @0 (64MB), bufB @64MB
static const size_t TAIL_OFF  = 134217728;
static const size_t KEYS_OFF  = TAIL_OFF;
static const size_t HIST_OFF  = TAIL_OFF + 262144;
static const size_t STATE_OFF = TAIL_OFF + 263168;
static const size_t IDX_OFF   = TAIL_OFF + 263424;
static const size_t EQ_OFF    = TAIL_OFF + 271616;
// overlaid into bufA region (activations there stay < 17MB; these used later/elsewhere):
static const size_t Q_OFF     = 0;
static const size_t K_OFF     = 2097152;
static const size_t V_OFF     = 4194304;
static const size_t OA_OFF    = 6291456;
static const size_t WTI_OFF   = 8388608;
static const size_t WTO_OFF   = 9437184;
static const size_t SROWS_OFF = 10485760;
static const size_t WT5_OFF   = 20971520;        // 2304*256*4 = 2.36MB
static const size_t CPK_OFF   = 25165824;        // bf16 conv3 pack 9*256*256*2 = 1.18MB
static const size_t DPK_OFF   = 27262976;        // bf16 deconv pack 16*256*256*2 = 2.1MB

struct SelState { unsigned int P; int kneed; int nGreater; int nEqual; };

__global__ void k_init(unsigned int* hist, SelState* st) {
  int t = threadIdx.x;
  hist[t] = 0;
  if (t == 0) { st->P = 0u; st->kneed = 2048; st->nGreater = 0; st->nEqual = 0; }
}

// 1x1 conv 768->256 on 8x8
__global__ void k_wtconv(const float* __restrict__ swint, const float* __restrict__ w,
                         const float* __restrict__ b, float* __restrict__ out) {
  int co = blockIdx.x, p = threadIdx.x;
  float acc = b[co];
  for (int ci = 0; ci < 768; ++ci) acc += swint[ci * 64 + p] * w[co * 768 + ci];
  out[co * 64 + p] = acc;
}

// deconv 4x4 stride2 pad2 + bias + relu, f32 (S=8 only)
template <int S>
__global__ __launch_bounds__(256) void k_deconv(const float* __restrict__ x,
                                                const float* __restrict__ w,
                                                const float* __restrict__ bias,
                                                float* __restrict__ y) {
  const int SO = 2 * S;
  const int TX = SO / 16;
  int co = blockIdx.y;
  int tile = blockIdx.x;
  int ty0 = (tile / TX) * 16, tx0 = (tile % TX) * 16;
  int t = threadIdx.x;
  int ly = t >> 4, lx = t & 15;
  int oy = ty0 + ly, ox = tx0 + lx;
  int iyb = (ty0 >> 1) - 1, ixb = (tx0 >> 1) - 1;
  int p = oy & 1, q = ox & 1;
  int iyA = ((oy + p - 2) >> 1) - iyb;
  int ixA = ((ox + q - 2) >> 1) - ixb;
  int i00 = (3 - p) * 4 + (3 - q);
  int i01 = (3 - p) * 4 + (1 - q);
  int i10 = (1 - p) * 4 + (3 - q);
  int i11 = (1 - p) * 4 + (1 - q);
  __shared__ float lx_s[8][10][10];
  __shared__ float lw_s[8][16];
  float acc = bias[co];
  for (int c0 = 0; c0 < CCH; c0 += 8) {
    __syncthreads();
    for (int i = t; i < 800; i += 256) {
      int u = i / 100, rem = i % 100;
      int r = rem / 10, c = rem % 10;
      int gy = iyb + r, gx = ixb + c;
      float v = 0.f;
      if (gy >= 0 && gy < S && gx >= 0 && gx < S)
        v = x[(size_t)(c0 + u) * S * S + gy * S + gx];
      lx_s[u][r][c] = v;
    }
    if (t < 128) {
      int u = t >> 4, e = t & 15;
      lw_s[u][e] = w[(size_t)(c0 + u) * 4096 + co * 16 + e];
    }
    __syncthreads();
#pragma unroll
    for (int u = 0; u < 8; ++u) {
      acc += lx_s[u][iyA][ixA]     * lw_s[u][i00]
           + lx_s[u][iyA][ixA + 1] * lw_s[u][i01]
           + lx_s[u][iyA + 1][ixA]     * lw_s[u][i10]
           + lx_s[u][iyA + 1][ixA + 1] * lw_s[u][i11];
    }
  }
  acc = fmaxf(acc, 0.f);
  y[(size_t)co * SO * SO + oy * SO + ox] = acc;
}

// pack conv3 weights: [co][ci][9] f32 -> bf16 [tap][co][ci]
__global__ void k_packc3(const float* __restrict__ w, short* __restrict__ wpk) {
  int co = blockIdx.x, ci = threadIdx.x;
  for (int tap = 0; tap < 9; ++tap)
    wpk[((size_t)(tap * 256 + co) * 256) + ci] = (short)f2bf(w[((size_t)(co * 256 + ci)) * 9 + tap]);
}

// pack deconv weights: [ci][co][4][4] f32 -> bf16 [pq][tt][co][ci]
__global__ void k_packdc(const float* __restrict__ w, short* __restrict__ wpk) {
  int co = blockIdx.x, ci = threadIdx.x;
  for (int pq = 0; pq < 4; ++pq) {
    int p = pq >> 1, q = pq & 1;
    for (int tt = 0; tt < 4; ++tt) {
      int dyi = tt >> 1, dxi = tt & 1;
      int wr = dyi ? (1 - p) : (3 - p);
      int wc = dxi ? (1 - q) : (3 - q);
      wpk[((size_t)((pq * 4 + tt) * 256 + co) * 256) + ci] =
          (short)f2bf(w[((size_t)(ci * 256 + co)) * 16 + wr * 4 + wc]);
    }
  }
}

// MFMA conv3x3 pad1 + bias. Block: 64 co x S pos (one row). bf16 in, f32 acc.
template <int S>
__global__ __launch_bounds__(256) void k_conv3x(const float* __restrict__ x,
                                                const short* __restrict__ wpk,
                                                const float* __restrict__ bias,
                                                float* __restrict__ y) {
  constexpr int SEG = S;
  constexpr int WPC = (SEG >= 64) ? 2 : 1;
  constexpr int WCO = 4 / WPC;
  constexpr int COS = 64 / WCO;
  constexpr int MR = COS / 16;
  constexpr int PSP = SEG / WPC;
  constexpr int NR = PSP / 16;
  __shared__ short x_s[3 * (SEG + 2) * PCI];
  __shared__ short w_s[3 * 64 * PCI];
  int t = threadIdx.x;
  int l = t & 63, wv = t >> 6;
  int wcob = (wv % WCO) * COS;
  int wposb = (wv / WCO) * PSP;
  int row = blockIdx.x;
  int co0 = blockIdx.y * 64;
  f32x4 acc[MR][NR];
#pragma unroll
  for (int m = 0; m < MR; ++m)
#pragma unroll
    for (int n = 0; n < NR; ++n) { f32x4 z = {0.f, 0.f, 0.f, 0.f}; acc[m][n] = z; }
  for (int c0 = 0; c0 < CCH; c0 += 32) {
    __syncthreads();
    // stage x: 3 rows x (SEG+2) cols x 32 ci, ci-pairs packed into b32 writes
    for (int i = t; i < 3 * (SEG + 2) * 16; i += 256) {
      int rc = i % (3 * (SEG + 2));
      int cp = i / (3 * (SEG + 2));
      int r = rc / (SEG + 2), col = rc % (SEG + 2);
      int gy = row - 1 + r, gx = col - 1;
      int ci = 2 * cp;
      float v0 = 0.f, v1 = 0.f;
      if (gy >= 0 && gy < S && gx >= 0 && gx < S) {
        v0 = x[(size_t)(c0 + ci) * S * S + (size_t)gy * S + gx];
        v1 = x[(size_t)(c0 + ci + 1) * S * S + (size_t)gy * S + gx];
      }
      unsigned pk = (unsigned)f2bf(v0) | ((unsigned)f2bf(v1) << 16);
      *(unsigned*)&x_s[rc * PCI + ci] = pk;
    }
    for (int dyg = 0; dyg < 3; ++dyg) {
      if (dyg) __syncthreads();
      // stage w: 3 taps (dy=dyg) x 64 co x 32 ci
      for (int i = t; i < 1536; i += 256) {
        int ci4 = i & 7;
        int tc = i >> 3;  // dx*64 + co
        int dx = tc >> 6, co = tc & 63;
        us4 wv4 = *(const us4*)&wpk[((size_t)((dyg * 3 + dx) * 256 + co0 + co) * 256) + c0 + ci4 * 4];
        *(us4*)&w_s[tc * PCI + ci4 * 4] = wv4;
      }
      __syncthreads();
#pragma unroll
      for (int dx = 0; dx < 3; ++dx) {
        short8 a[MR], b[NR];
#pragma unroll
        for (int m = 0; m < MR; ++m)
          a[m] = *(const short8*)&w_s[(dx * 64 + wcob + m * 16 + (l & 15)) * PCI + (l >> 4) * 8];
#pragma unroll
        for (int n = 0; n < NR; ++n)
          b[n] = *(const short8*)&x_s[(dyg * (SEG + 2) + wposb + n * 16 + (l & 15) + dx) * PCI + (l >> 4) * 8];
#pragma unroll
        for (int m = 0; m < MR; ++m)
#pragma unroll
          for (int n = 0; n < NR; ++n) mfma_bf16(acc[m][n], a[m], b[n]);
      }
    }
  }
  asm volatile("s_nop 7\n\ts_nop 7" ::);
#pragma unroll
  for (int m = 0; m < MR; ++m)
#pragma unroll
    for (int n = 0; n < NR; ++n)
#pragma unroll
      for (int r4 = 0; r4 < 4; ++r4) {
        int co = co0 + wcob + m * 16 + (l >> 4) * 4 + r4;
        int px = wposb + n * 16 + (l & 15);
        y[(size_t)co * S * S + (size_t)row * S + px] = acc[m][n][r4] + bias[co];
      }
}

// MFMA deconv4x4 s2 p2 + bias + relu. Block: parity pq, 64 co x S pos (input row).
template <int S>
__global__ __launch_bounds__(256) void k_deconvx(const float* __restrict__ x,
                                                 const short* __restrict__ wpk,
                                                 const float* __restrict__ bias,
                                                 float* __restrict__ y) {
  constexpr int SEG = S;
  constexpr int WPC = (SEG >= 64) ? 2 : 1;
  constexpr int WCO = 4 / WPC;
  constexpr int COS = 64 / WCO;
  constexpr int MR = COS / 16;
  constexpr int PSP = SEG / WPC;
  constexpr int NR = PSP / 16;
  const int SO = 2 * S;
  __shared__ short x_s[2 * (SEG + 1) * PCI];
  __shared__ short w_s[4 * 64 * PCI];
  int t = threadIdx.x;
  int l = t & 63, wv = t >> 6;
  int wcob = (wv % WCO) * COS;
  int wposb = (wv / WCO) * PSP;
  int row = blockIdx.x;
  int co0 = blockIdx.y * 64;
  int pq = blockIdx.z;
  int p = pq >> 1, q = pq & 1;
  f32x4 acc[MR][NR];
#pragma unroll
  for (int m = 0; m < MR; ++m)
#pragma unroll
    for (int n = 0; n < NR; ++n) { f32x4 z = {0.f, 0.f, 0.f, 0.f}; acc[m][n] = z; }
  for (int c0 = 0; c0 < CCH; c0 += 32) {
    __syncthreads();
    for (int i = t; i < 2 * (SEG + 1) * 16; i += 256) {
      int rc = i % (2 * (SEG + 1));
      int cp = i / (2 * (SEG + 1));
      int r = rc / (SEG + 1), col = rc % (SEG + 1);
      int gy = row + p - 1 + r, gx = col + q - 1;
      int ci = 2 * cp;
      float v0 = 0.f, v1 = 0.f;
      if (gy >= 0 && gy < S && gx >= 0 && gx < S) {
        v0 = x[(size_t)(c0 + ci) * S * S + (size_t)gy * S + gx];
        v1 = x[(size_t)(c0 + ci + 1) * S * S + (size_t)gy * S + gx];
      }
      unsigned pk = (unsigned)f2bf(v0) | ((unsigned)f2bf(v1) << 16);
      *(unsigned*)&x_s[rc * PCI + ci] = pk;
    }
    for (int i = t; i < 2048; i += 256) {
      int ci4 = i & 7;
      int tc = i >> 3;  // tt*64 + co
      int tt = tc >> 6, co = tc & 63;
      us4 wv4 = *(const us4*)&wpk[((size_t)((pq * 4 + tt) * 256 + co0 + co) * 256) + c0 + ci4 * 4];
      *(us4*)&w_s[tc * PCI + ci4 * 4] = wv4;
    }
    __syncthreads();
#pragma unroll
    for (int tt = 0; tt < 4; ++tt) {
      int dyi = tt >> 1, dxi = tt & 1;
      short8 a[MR], b[NR];
#pragma unroll
      for (int m = 0; m < MR; ++m)
        a[m] = *(const short8*)&w_s[(tt * 64 + wcob + m * 16 + (l & 15)) * PCI + (l >> 4) * 8];
#pragma unroll
      for (int n = 0; n < NR; ++n)
        b[n] = *(const short8*)&x_s[(dyi * (SEG + 1) + wposb + n * 16 + (l & 15) + dxi) * PCI + (l >> 4) * 8];
#pragma unroll
      for (int m = 0; m < MR; ++m)
#pragma unroll
        for (int n = 0; n < NR; ++n) mfma_bf16(acc[m][n], a[m], b[n]);
    }
  }
  asm volatile("s_nop 7\n\ts_nop 7" ::);
#pragma unroll
  for (int m = 0; m < MR; ++m)
#pragma unroll
    for (int n = 0; n < NR; ++n)
#pragma unroll
      for (int r4 = 0; r4 < 4; ++r4) {
        int co = co0 + wcob + m * 16 + (l >> 4) * 4 + r4;
        int px = wposb + n * 16 + (l & 15);
        float v = fmaxf(acc[m][n][r4] + bias[co], 0.f);
        y[(size_t)co * SO * SO + (size_t)(2 * row + p) * SO + (2 * px + q)] = v;
      }
}

// transpose stage-5 conv weights: w[co][ci*9+e] -> wt[(ci*9+e)][co]
__global__ void k_wt5(const float* __restrict__ w, float* __restrict__ wt) {
  int e9 = blockIdx.x;
  int co = threadIdx.x;
  int ci = e9 / 9, e = e9 % 9;
  wt[(size_t)e9 * 256 + co] = w[((size_t)co * 256 + ci) * 9 + e];
}

// sparse final conv3 at 8 gathered positions per block, transposed weights.
__global__ __launch_bounds__(256) void k_conv3sT(const float* __restrict__ x,
                                                 const float* __restrict__ wt,
                                                 const float* __restrict__ bias,
                                                 const int* __restrict__ idx,
                                                 float* __restrict__ out) {
  __shared__ float sp[8][2304];
  int t = threadIdx.x;
  int j0 = blockIdx.x * 8;
  for (int i = t; i < 8 * 2304; i += 256) {
    int jj = i / 2304, r = i % 2304;
    int ci = r / 9, e = r % 9;
    int p = idx[j0 + jj];
    int py = p >> 8, px = p & 255;
    int gy = py - 1 + e / 3, gx = px - 1 + e % 3;
    float v = 0.f;
    if (gy >= 0 && gy < 256 && gx >= 0 && gx < 256)
      v = x[(size_t)ci * HWP + gy * 256 + gx];
    sp[jj][r] = v;
  }
  __syncthreads();
  float bv = bias[t];
  float a[8];
#pragma unroll
  for (int jj = 0; jj < 8; ++jj) a[jj] = bv;
  for (int e4 = 0; e4 < 576; ++e4) {
    float w0 = wt[(size_t)(4 * e4 + 0) * 256 + t];
    float w1 = wt[(size_t)(4 * e4 + 1) * 256 + t];
    float w2 = wt[(size_t)(4 * e4 + 2) * 256 + t];
    float w3 = wt[(size_t)(4 * e4 + 3) * 256 + t];
#pragma unroll
    for (int jj = 0; jj < 8; ++jj) {
      float4 s = ((const float4*)sp[jj])[e4];
      a[jj] += s.x * w0 + s.y * w1 + s.z * w2 + s.w * w3;
    }
  }
#pragma unroll
  for (int jj = 0; jj < 8; ++jj) out[(size_t)(j0 + jj) * 256 + t] = a[jj];
}

// fused: passthrough copy of down into out + gate keys
__global__ void k_gatecopy(const float* __restrict__ down, const float* __restrict__ gw,
                           float* __restrict__ out, unsigned int* __restrict__ keys) {
  int p = blockIdx.x * 256 + threadIdx.x;
  float acc = 0.f;
  for (int c = 0; c < CCH; ++c) {
    float v = down[(size_t)c * HWP + p];
    out[(size_t)c * HWP + p] = v;
    acc += v * gw[c];
  }
  unsigned int u = __float_as_uint(acc);
  keys[p] = (u & 0x80000000u) ? ~u : (u | 0x80000000u);
}

__global__ void k_hist(const unsigned int* __restrict__ keys, unsigned int* hist,
                       const SelState* st, int r) {
  __shared__ unsigned int lh[256];
  int t = threadIdx.x;
  lh[t] = 0;
  __syncthreads();
  unsigned int key = keys[blockIdx.x * 256 + t];
  bool ok = (r == 0) || ((key >> (32 - 8 * r)) == st->P);
  if (ok) atomicAdd(&lh[(key >> (24 - 8 * r)) & 255u], 1u);
  __syncthreads();
  if (lh[t]) atomicAdd(&hist[t], lh[t]);
}

__global__ void k_scan(unsigned int* hist, SelState* st) {
  if (threadIdx.x == 0) {
    int need = st->kneed;
    unsigned int cum = 0;
    for (int b = 255; b >= 0; --b) {
      unsigned int h = hist[b];
      if (cum + h >= (unsigned int)need) {
        st->P = (st->P << 8) | (unsigned int)b;
        st->kneed = need - (int)cum;
        break;
      }
      cum += h;
    }
  }
  __syncthreads();
  hist[threadIdx.x] = 0;
}

__global__ void k_compact(const unsigned int* __restrict__ keys, SelState* st,
                          int* __restrict__ idx, int* __restrict__ eq) {
  int p = blockIdx.x * 256 + threadIdx.x;
  unsigned int key = keys[p];
  unsigned int P = st->P;
  if (key > P) {
    int pos = atomicAdd(&st->nGreater, 1);
    idx[pos] = p;
  } else if (key == P) {
    int e = atomicAdd(&st->nEqual, 1);
    if (e < 4096) eq[e] = p;
  }
}

__global__ void k_finalize(SelState* st, int* idx, int* eq) {
  if (threadIdx.x != 0) return;
  int n = st->nEqual;
  if (n > 4096) n = 4096;
  for (int i = 1; i < n; ++i) {
    int v = eq[i], j = i - 1;
    while (j >= 0 && eq[j] > v) { eq[j + 1] = eq[j]; --j; }
    eq[j + 1] = v;
  }
  int g = st->nGreater;
  for (int i = 0; i < st->kneed; ++i) idx[g + i] = eq[i];
}

__global__ void k_transpose(const float* __restrict__ in, float* __restrict__ out, int rows) {
  int o = blockIdx.x, c = threadIdx.x;
  out[(size_t)c * rows + o] = in[(size_t)o * 256 + c];
}

// gather rows at idx and project to Q,K,V (2048 x 256 each)
__global__ void k_qkv(const float* __restrict__ down, const float* __restrict__ srows,
                      const int* __restrict__ idx, const float* __restrict__ wT,
                      const float* __restrict__ bias, float* __restrict__ Q,
                      float* __restrict__ K, float* __restrict__ V) {
  __shared__ float xq[256], xk[256];
  int j = blockIdx.x, c = threadIdx.x;
  int p = idx[j];
  xq[c] = down[(size_t)c * HWP + p];
  xk[c] = srows[(size_t)j * 256 + c];
  __syncthreads();
  float aq = bias[c], ak = bias[256 + c], av = bias[512 + c];
  for (int i = 0; i < 256; ++i) {
    float xv = xq[i], kv = xk[i];
    aq += xv * wT[i * 768 + c];
    ak += kv * wT[i * 768 + 256 + c];
    av += kv * wT[i * 768 + 512 + c];
  }
  Q[j * 256 + c] = aq;
  K[j * 256 + c] = ak;
  V[j * 256 + c] = av;
}

// one block per (query row, head): full-softmax attention over 2048 keys
__global__ __launch_bounds__(256) void k_attn(const float* __restrict__ Q,
                                              const float* __restrict__ K,
                                              const float* __restrict__ V,
                                              float* __restrict__ O) {
  int jq = blockIdx.x, h = blockIdx.y, t = threadIdx.x;
  int hd0 = h * 32;
  __shared__ float qv[32];
  __shared__ float red[256];
  __shared__ float mat[256 * 33];
  if (t < 32) qv[t] = Q[jq * 256 + hd0 + t];
  __syncthreads();
  const float scale = 0.17677669529663687f;
  float sc[8];
#pragma unroll
  for (int r = 0; r < 8; ++r) {
    const float* kp = K + (size_t)(r * 256 + t) * 256 + hd0;
    float aa = 0.f;
#pragma unroll
    for (int d = 0; d < 32; ++d) aa += qv[d] * kp[d];
    sc[r] = aa * scale;
  }
  float m = sc[0];
#pragma unroll
  for (int r = 1; r < 8; ++r) m = fmaxf(m, sc[r]);
  float s = 0.f;
  float acc[32];
#pragma unroll
  for (int d = 0; d < 32; ++d) acc[d] = 0.f;
#pragma unroll
  for (int r = 0; r < 8; ++r) {
    float wv = __expf(sc[r] - m);
    s += wv;
    const float* vp = V + (size_t)(r * 256 + t) * 256 + hd0;
#pragma unroll
    for (int d = 0; d < 32; ++d) acc[d] += wv * vp[d];
  }
  red[t] = m;
  __syncthreads();
  for (int off = 128; off > 0; off >>= 1) {
    if (t < off) red[t] = fmaxf(red[t], red[t + off]);
    __syncthreads();
  }
  float M = red[0];
  __syncthreads();
  float wsc = __expf(m - M);
  red[t] = s * wsc;
  __syncthreads();
  for (int off = 128; off > 0; off >>= 1) {
    if (t < off) red[t] += red[t + off];
    __syncthreads();
  }
  float S = red[0];
#pragma unroll
  for (int d = 0; d < 32; ++d) mat[t * 33 + d] = acc[d] * wsc;
  __syncthreads();
  if (t < 32) {
    float o = 0.f;
    for (int i = 0; i < 256; ++i) o += mat[i * 33 + t];
    O[jq * 256 + hd0 + t] = o / S;
  }
}

// out-projection fused with scatter into final output columns
__global__ void k_outproj(const float* __restrict__ Oa, const float* __restrict__ owT,
                          const float* __restrict__ ob, const int* __restrict__ idx,
                          float* __restrict__ out) {
  __shared__ float xo[256];
  int j = blockIdx.x, c = threadIdx.x;
  xo[c] = Oa[j * 256 + c];
  __syncthreads();
  float aa = ob[c];
  for (int i = 0; i < 256; ++i) aa += xo[i] * owT[i * 256 + c];
  out[(size_t)c * HWP + idx[j]] = aa;
}

extern "C" void kernel_launch(void* const* d_in, const int* in_sizes, int n_in,
                              void* d_out, int out_size, void* d_ws, size_t ws_size,
                              hipStream_t stream) {
  const float* down  = (const float*)d_in[0];
  const float* swint = (const float*)d_in[1];
  const float* wt_w  = (const float*)d_in[2];
  const float* wt_b  = (const float*)d_in[3];
  const float* up_dw = (const float*)d_in[4];
  const float* up_db = (const float*)d_in[5];
  const float* up_cw = (const float*)d_in[6];
  const float* up_cb = (const float*)d_in[7];
  const float* gate_w = (const float*)d_in[8];
  const float* in_w  = (const float*)d_in[10];
  const float* in_b  = (const float*)d_in[11];
  const float* out_w = (const float*)d_in[12];
  const float* out_b = (const float*)d_in[13];
  float* out = (float*)d_out;
  char* ws = (char*)d_ws;

  float* bufA = (float*)ws;
  float* bufB = (float*)(ws + BUF_B_OFF);
  unsigned int* keys = (unsigned int*)(ws + KEYS_OFF);
  unsigned int* hist = (unsigned int*)(ws + HIST_OFF);
  SelState* st = (SelState*)(ws + STATE_OFF);
  int* idx = (int*)(ws + IDX_OFF);
  int* eq = (int*)(ws + EQ_OFF);
  float* Q = (float*)(ws + Q_OFF);
  float* Km = (float*)(ws + K_OFF);
  float* V = (float*)(ws + V_OFF);
  float* Oa = (float*)(ws + OA_OFF);
  float* wTi = (float*)(ws + WTI_OFF);
  float* wTo = (float*)(ws + WTO_OFF);
  float* srows = (float*)(ws + SROWS_OFF);
  float* wt5 = (float*)(ws + WT5_OFF);
  short* cpk = (short*)(ws + CPK_OFF);
  short* dpk = (short*)(ws + DPK_OFF);

  k_init<<<1, 256, 0, stream>>>(hist, st);

  // fused gate + passthrough copy, then exact top-k (radix select)
  k_gatecopy<<<256, 256, 0, stream>>>(down, gate_w, out, keys);
  for (int r = 0; r < 4; ++r) {
    k_hist<<<256, 256, 0, stream>>>(keys, hist, st, r);
    k_scan<<<1, 256, 0, stream>>>(hist, st);
  }
  k_compact<<<256, 256, 0, stream>>>(keys, st, idx, eq);
  k_finalize<<<1, 64, 0, stream>>>(st, idx, eq);

  // upsampler chain: MFMA bf16 implicit-GEMM (A/B ping-pong)
  k_wtconv<<<256, 64, 0, stream>>>(swint, wt_w, wt_b, bufA);
  k_deconv<8><<<dim3(1, 256), 256, 0, stream>>>(bufA, up_dw, up_db, bufB);

  k_packc3<<<256, 256, 0, stream>>>(up_cw, cpk);
  k_conv3x<16><<<dim3(16, 4), 256, 0, stream>>>(bufB, cpk, up_cb, bufA);
  k_packdc<<<256, 256, 0, stream>>>(up_dw + 1048576, dpk);
  k_deconvx<16><<<dim3(16, 4, 4), 256, 0, stream>>>(bufA, dpk, up_db + 256, bufB);

  k_packc3<<<256, 256, 0, stream>>>(up_cw + 589824, cpk);
  k_conv3x<32><<<dim3(32, 4), 256, 0, stream>>>(bufB, cpk, up_cb + 256, bufA);
  k_packdc<<<256, 256, 0, stream>>>(up_dw + 2097152, dpk);
  k_deconvx<32><<<dim3(32, 4, 4), 256, 0, stream>>>(bufA, dpk, up_db + 512, bufB);

  k_packc3<<<256, 256, 0, stream>>>(up_cw + 1179648, cpk);
  k_conv3x<64><<<dim3(64, 4), 256, 0, stream>>>(bufB, cpk, up_cb + 512, bufA);
  k_packdc<<<256, 256, 0, stream>>>(up_dw + 3145728, dpk);
  k_deconvx<64><<<dim3(64, 4, 4), 256, 0, stream>>>(bufA, dpk, up_db + 768, bufB);

  k_packc3<<<256, 256, 0, stream>>>(up_cw + 1769472, cpk);
  k_conv3x<128><<<dim3(128, 4), 256, 0, stream>>>(bufB, cpk, up_cb + 768, bufA);
  k_packdc<<<256, 256, 0, stream>>>(up_dw + 4194304, dpk);
  k_deconvx<128><<<dim3(128, 4, 4), 256, 0, stream>>>(bufA, dpk, up_db + 1024, bufB);

  // transposed weights + attention overlays (bufA activations are dead now)
  k_wt5<<<2304, 256, 0, stream>>>(up_cw + 2359296, wt5);
  k_transpose<<<768, 256, 0, stream>>>(in_w, wTi, 768);
  k_transpose<<<256, 256, 0, stream>>>(out_w, wTo, 256);

  // final conv3 only at the 2048 gathered positions
  k_conv3sT<<<256, 256, 0, stream>>>(bufB, wt5, up_cb + 1024, idx, srows);

  // attention path
  k_qkv<<<2048, 256, 0, stream>>>(down, srows, idx, wTi, in_b, Q, Km, V);
  k_attn<<<dim3(2048, 8), 256, 0, stream>>>(Q, Km, V, Oa);
  k_outproj<<<2048, 256, 0, stream>>>(Oa, wTo, out_b, idx, out);
}

// Round 5
// 1095.116 us; speedup vs baseline: 16.0067x; 1.9940x over previous
//
#include <hip/hip_runtime.h>
#include <math.h>

#define CCH 256
#define HWP 65536
#define PCI 40   // padded ci stride (shorts) in LDS

typedef short short8 __attribute__((ext_vector_type(8)));
typedef float f32x4 __attribute__((ext_vector_type(4)));
typedef unsigned short us4 __attribute__((ext_vector_type(4)));

__device__ inline unsigned short f2bf(float f) {
  unsigned u = __float_as_uint(f);
  return (unsigned short)((u + 0x7FFFu + ((u >> 16) & 1u)) >> 16);
}
__device__ inline float bf2f(unsigned short s) {
  return __uint_as_float(((unsigned)s) << 16);
}

__device__ inline void mfma_bf16(f32x4& d, short8 a, short8 b) {
  asm volatile("v_mfma_f32_16x16x32_bf16 %0, %1, %2, %0" : "+v"(d) : "v"(a), "v"(b));
}

// ---- ws layout (bytes) ----
static const size_t BUF_B_OFF = 67108864;        // bufA @0 (64MB), bufB @64MB
static const size_t TAIL_OFF  = 134217728;
static const size_t KEYS_OFF  = TAIL_OFF;
static const size_t HIST_OFF  = TAIL_OFF + 262144;
static const size_t STATE_OFF = TAIL_OFF + 263168;
static const size_t IDX_OFF   = TAIL_OFF + 263424;
static const size_t EQ_OFF    = TAIL_OFF + 271616;
// overlaid into bufA region (conv activations there stay < 17MB):
static const size_t OA_OFF    = 6291456;         // f32 O accum 2048*256*4
static const size_t WTI_OFF   = 8388608;         // in_w^T 768*256*4
static const size_t WTO_OFF   = 9437184;         // out_w^T 256*256*4
static const size_t SROWS_OFF = 10485760;        // 2048*256*4 sparse s rows
static const size_t WT5_OFF   = 20971520;        // 2304*256*4
static const size_t QB_OFF    = 31457280;        // bf16 Q [8][2048][32] 1MB
static const size_t KB_OFF    = 32505856;        // bf16 K [8][2048][32] 1MB
static const size_t VT_OFF    = 33554432;        // bf16 V^T [8][32][2048] 1MB
static const size_t CPK_OFF   = 37748736;        // bf16 conv packs 4 layers x 589824 sh
static const size_t DPK_OFF   = 44040192;        // bf16 deconv packs 4 layers x 1048576 sh
// S / P bf16 [8][2048][2048] = 64MB lives in bufB after conv3sT consumed it.

struct SelState { unsigned int P; int kneed; int nGreater; int nEqual; };

__global__ void k_init(unsigned int* hist, SelState* st) {
  int t = threadIdx.x;
  hist[t] = 0;
  if (t == 0) { st->P = 0u; st->kneed = 2048; st->nGreater = 0; st->nEqual = 0; }
}

// 1x1 conv 768->256 on 8x8
__global__ void k_wtconv(const float* __restrict__ swint, const float* __restrict__ w,
                         const float* __restrict__ b, float* __restrict__ out) {
  int co = blockIdx.x, p = threadIdx.x;
  float acc = b[co];
  for (int ci = 0; ci < 768; ++ci) acc += swint[ci * 64 + p] * w[co * 768 + ci];
  out[co * 64 + p] = acc;
}

// deconv 4x4 stride2 pad2 + bias + relu, f32 (S=8 only)
template <int S>
__global__ __launch_bounds__(256) void k_deconv(const float* __restrict__ x,
                                                const float* __restrict__ w,
                                                const float* __restrict__ bias,
                                                float* __restrict__ y) {
  const int SO = 2 * S;
  const int TX = SO / 16;
  int co = blockIdx.y;
  int tile = blockIdx.x;
  int ty0 = (tile / TX) * 16, tx0 = (tile % TX) * 16;
  int t = threadIdx.x;
  int ly = t >> 4, lx = t & 15;
  int oy = ty0 + ly, ox = tx0 + lx;
  int iyb = (ty0 >> 1) - 1, ixb = (tx0 >> 1) - 1;
  int p = oy & 1, q = ox & 1;
  int iyA = ((oy + p - 2) >> 1) - iyb;
  int ixA = ((ox + q - 2) >> 1) - ixb;
  int i00 = (3 - p) * 4 + (3 - q);
  int i01 = (3 - p) * 4 + (1 - q);
  int i10 = (1 - p) * 4 + (3 - q);
  int i11 = (1 - p) * 4 + (1 - q);
  __shared__ float lx_s[8][10][10];
  __shared__ float lw_s[8][16];
  float acc = bias[co];
  for (int c0 = 0; c0 < CCH; c0 += 8) {
    __syncthreads();
    for (int i = t; i < 800; i += 256) {
      int u = i / 100, rem = i % 100;
      int r = rem / 10, c = rem % 10;
      int gy = iyb + r, gx = ixb + c;
      float v = 0.f;
      if (gy >= 0 && gy < S && gx >= 0 && gx < S)
        v = x[(size_t)(c0 + u) * S * S + gy * S + gx];
      lx_s[u][r][c] = v;
    }
    if (t < 128) {
      int u = t >> 4, e = t & 15;
      lw_s[u][e] = w[(size_t)(c0 + u) * 4096 + co * 16 + e];
    }
    __syncthreads();
#pragma unroll
    for (int u = 0; u < 8; ++u) {
      acc += lx_s[u][iyA][ixA]     * lw_s[u][i00]
           + lx_s[u][iyA][ixA + 1] * lw_s[u][i01]
           + lx_s[u][iyA + 1][ixA]     * lw_s[u][i10]
           + lx_s[u][iyA + 1][ixA + 1] * lw_s[u][i11];
    }
  }
  acc = fmaxf(acc, 0.f);
  y[(size_t)co * SO * SO + oy * SO + ox] = acc;
}

// pack conv3 weights (4 layers): [co][ci][9] f32 -> bf16 [tap][co][ci]
__global__ void k_packc3(const float* __restrict__ w, short* __restrict__ wpk) {
  int layer = blockIdx.y;
  const float* wl = w + (size_t)layer * 589824;
  short* wo = wpk + (size_t)layer * 589824;
  int co = blockIdx.x, ci = threadIdx.x;
  for (int tap = 0; tap < 9; ++tap)
    wo[((size_t)(tap * 256 + co) * 256) + ci] = (short)f2bf(wl[((size_t)(co * 256 + ci)) * 9 + tap]);
}

// pack deconv weights (layers 1..4): [ci][co][4][4] f32 -> bf16 [pq][tt][co][ci]
__global__ void k_packdc(const float* __restrict__ w, short* __restrict__ wpk) {
  int layer = blockIdx.y;
  const float* wl = w + (size_t)(layer + 1) * 1048576;
  short* wo = wpk + (size_t)layer * 1048576;
  int co = blockIdx.x, ci = threadIdx.x;
  for (int pq = 0; pq < 4; ++pq) {
    int p = pq >> 1, q = pq & 1;
    for (int tt = 0; tt < 4; ++tt) {
      int dyi = tt >> 1, dxi = tt & 1;
      int wr = dyi ? (1 - p) : (3 - p);
      int wc = dxi ? (1 - q) : (3 - q);
      wpk[((size_t)layer * 1048576) + ((size_t)((pq * 4 + tt) * 256 + co) * 256) + ci] =
          (short)f2bf(wl[((size_t)(ci * 256 + co)) * 16 + wr * 4 + wc]);
    }
  }
}

// MFMA conv3x3 pad1 + bias. Block: 64 co x S pos (one row). bf16 in, f32 acc.
template <int S>
__global__ __launch_bounds__(256) void k_conv3x(const float* __restrict__ x,
                                                const short* __restrict__ wpk,
                                                const float* __restrict__ bias,
                                                float* __restrict__ y) {
  constexpr int SEG = S;
  constexpr int WPC = (SEG >= 64) ? 2 : 1;
  constexpr int WCO = 4 / WPC;
  constexpr int COS = 64 / WCO;
  constexpr int MR = COS / 16;
  constexpr int PSP = SEG / WPC;
  constexpr int NR = PSP / 16;
  __shared__ short x_s[3 * (SEG + 2) * PCI];
  __shared__ short w_s[3 * 64 * PCI];
  int t = threadIdx.x;
  int l = t & 63, wv = t >> 6;
  int wcob = (wv % WCO) * COS;
  int wposb = (wv / WCO) * PSP;
  int row = blockIdx.x;
  int co0 = blockIdx.y * 64;
  f32x4 acc[MR][NR];
#pragma unroll
  for (int m = 0; m < MR; ++m)
#pragma unroll
    for (int n = 0; n < NR; ++n) { f32x4 z = {0.f, 0.f, 0.f, 0.f}; acc[m][n] = z; }
  for (int c0 = 0; c0 < CCH; c0 += 32) {
    __syncthreads();
    for (int i = t; i < 3 * (SEG + 2) * 16; i += 256) {
      int rc = i % (3 * (SEG + 2));
      int cp = i / (3 * (SEG + 2));
      int r = rc / (SEG + 2), col = rc % (SEG + 2);
      int gy = row - 1 + r, gx = col - 1;
      int ci = 2 * cp;
      float v0 = 0.f, v1 = 0.f;
      if (gy >= 0 && gy < S && gx >= 0 && gx < S) {
        v0 = x[(size_t)(c0 + ci) * S * S + (size_t)gy * S + gx];
        v1 = x[(size_t)(c0 + ci + 1) * S * S + (size_t)gy * S + gx];
      }
      unsigned pk = (unsigned)f2bf(v0) | ((unsigned)f2bf(v1) << 16);
      *(unsigned*)&x_s[rc * PCI + ci] = pk;
    }
    for (int dyg = 0; dyg < 3; ++dyg) {
      if (dyg) __syncthreads();
      for (int i = t; i < 1536; i += 256) {
        int ci4 = i & 7;
        int tc = i >> 3;
        int dx = tc >> 6, co = tc & 63;
        us4 wv4 = *(const us4*)&wpk[((size_t)((dyg * 3 + dx) * 256 + co0 + co) * 256) + c0 + ci4 * 4];
        *(us4*)&w_s[tc * PCI + ci4 * 4] = wv4;
      }
      __syncthreads();
#pragma unroll
      for (int dx = 0; dx < 3; ++dx) {
        short8 a[MR], b[NR];
#pragma unroll
        for (int m = 0; m < MR; ++m)
          a[m] = *(const short8*)&w_s[(dx * 64 + wcob + m * 16 + (l & 15)) * PCI + (l >> 4) * 8];
#pragma unroll
        for (int n = 0; n < NR; ++n)
          b[n] = *(const short8*)&x_s[(dyg * (SEG + 2) + wposb + n * 16 + (l & 15) + dx) * PCI + (l >> 4) * 8];
#pragma unroll
        for (int m = 0; m < MR; ++m)
#pragma unroll
          for (int n = 0; n < NR; ++n) mfma_bf16(acc[m][n], a[m], b[n]);
      }
    }
  }
  asm volatile("s_nop 7\n\ts_nop 7" ::);
#pragma unroll
  for (int m = 0; m < MR; ++m)
#pragma unroll
    for (int n = 0; n < NR; ++n)
#pragma unroll
      for (int r4 = 0; r4 < 4; ++r4) {
        int co = co0 + wcob + m * 16 + (l >> 4) * 4 + r4;
        int px = wposb + n * 16 + (l & 15);
        y[(size_t)co * S * S + (size_t)row * S + px] = acc[m][n][r4] + bias[co];
      }
}

// MFMA deconv4x4 s2 p2 + bias + relu. Block: parity pq, 64 co x S pos (input row).
template <int S>
__global__ __launch_bounds__(256) void k_deconvx(const float* __restrict__ x,
                                                 const short* __restrict__ wpk,
                                                 const float* __restrict__ bias,
                                                 float* __restrict__ y) {
  constexpr int SEG = S;
  constexpr int WPC = (SEG >= 64) ? 2 : 1;
  constexpr int WCO = 4 / WPC;
  constexpr int COS = 64 / WCO;
  constexpr int MR = COS / 16;
  constexpr int PSP = SEG / WPC;
  constexpr int NR = PSP / 16;
  const int SO = 2 * S;
  __shared__ short x_s[2 * (SEG + 1) * PCI];
  __shared__ short w_s[4 * 64 * PCI];
  int t = threadIdx.x;
  int l = t & 63, wv = t >> 6;
  int wcob = (wv % WCO) * COS;
  int wposb = (wv / WCO) * PSP;
  int row = blockIdx.x;
  int co0 = blockIdx.y * 64;
  int pq = blockIdx.z;
  int p = pq >> 1, q = pq & 1;
  f32x4 acc[MR][NR];
#pragma unroll
  for (int m = 0; m < MR; ++m)
#pragma unroll
    for (int n = 0; n < NR; ++n) { f32x4 z = {0.f, 0.f, 0.f, 0.f}; acc[m][n] = z; }
  for (int c0 = 0; c0 < CCH; c0 += 32) {
    __syncthreads();
    for (int i = t; i < 2 * (SEG + 1) * 16; i += 256) {
      int rc = i % (2 * (SEG + 1));
      int cp = i / (2 * (SEG + 1));
      int r = rc / (SEG + 1), col = rc % (SEG + 1);
      int gy = row + p - 1 + r, gx = col + q - 1;
      int ci = 2 * cp;
      float v0 = 0.f, v1 = 0.f;
      if (gy >= 0 && gy < S && gx >= 0 && gx < S) {
        v0 = x[(size_t)(c0 + ci) * S * S + (size_t)gy * S + gx];
        v1 = x[(size_t)(c0 + ci + 1) * S * S + (size_t)gy * S + gx];
      }
      unsigned pk = (unsigned)f2bf(v0) | ((unsigned)f2bf(v1) << 16);
      *(unsigned*)&x_s[rc * PCI + ci] = pk;
    }
    for (int i = t; i < 2048; i += 256) {
      int ci4 = i & 7;
      int tc = i >> 3;
      int tt = tc >> 6, co = tc & 63;
      us4 wv4 = *(const us4*)&wpk[((size_t)((pq * 4 + tt) * 256 + co0 + co) * 256) + c0 + ci4 * 4];
      *(us4*)&w_s[tc * PCI + ci4 * 4] = wv4;
    }
    __syncthreads();
#pragma unroll
    for (int tt = 0; tt < 4; ++tt) {
      int dyi = tt >> 1, dxi = tt & 1;
      short8 a[MR], b[NR];
#pragma unroll
      for (int m = 0; m < MR; ++m)
        a[m] = *(const short8*)&w_s[(tt * 64 + wcob + m * 16 + (l & 15)) * PCI + (l >> 4) * 8];
#pragma unroll
      for (int n = 0; n < NR; ++n)
        b[n] = *(const short8*)&x_s[(dyi * (SEG + 1) + wposb + n * 16 + (l & 15) + dxi) * PCI + (l >> 4) * 8];
#pragma unroll
      for (int m = 0; m < MR; ++m)
#pragma unroll
        for (int n = 0; n < NR; ++n) mfma_bf16(acc[m][n], a[m], b[n]);
    }
  }
  asm volatile("s_nop 7\n\ts_nop 7" ::);
#pragma unroll
  for (int m = 0; m < MR; ++m)
#pragma unroll
    for (int n = 0; n < NR; ++n)
#pragma unroll
      for (int r4 = 0; r4 < 4; ++r4) {
        int co = co0 + wcob + m * 16 + (l >> 4) * 4 + r4;
        int px = wposb + n * 16 + (l & 15);
        float v = fmaxf(acc[m][n][r4] + bias[co], 0.f);
        y[(size_t)co * SO * SO + (size_t)(2 * row + p) * SO + (2 * px + q)] = v;
      }
}

// transpose stage-5 conv weights: w[co][ci*9+e] -> wt[(ci*9+e)][co]
__global__ void k_wt5(const float* __restrict__ w, float* __restrict__ wt) {
  int e9 = blockIdx.x;
  int co = threadIdx.x;
  int ci = e9 / 9, e = e9 % 9;
  wt[(size_t)e9 * 256 + co] = w[((size_t)co * 256 + ci) * 9 + e];
}

// sparse final conv3 at 8 gathered positions per block, transposed weights.
__global__ __launch_bounds__(256) void k_conv3sT(const float* __restrict__ x,
                                                 const float* __restrict__ wt,
                                                 const float* __restrict__ bias,
                                                 const int* __restrict__ idx,
                                                 float* __restrict__ out) {
  __shared__ float sp[8][2304];
  int t = threadIdx.x;
  int j0 = blockIdx.x * 8;
  for (int i = t; i < 8 * 2304; i += 256) {
    int jj = i / 2304, r = i % 2304;
    int ci = r / 9, e = r % 9;
    int p = idx[j0 + jj];
    int py = p >> 8, px = p & 255;
    int gy = py - 1 + e / 3, gx = px - 1 + e % 3;
    float v = 0.f;
    if (gy >= 0 && gy < 256 && gx >= 0 && gx < 256)
      v = x[(size_t)ci * HWP + gy * 256 + gx];
    sp[jj][r] = v;
  }
  __syncthreads();
  float bv = bias[t];
  float a[8];
#pragma unroll
  for (int jj = 0; jj < 8; ++jj) a[jj] = bv;
  for (int e4 = 0; e4 < 576; ++e4) {
    float w0 = wt[(size_t)(4 * e4 + 0) * 256 + t];
    float w1 = wt[(size_t)(4 * e4 + 1) * 256 + t];
    float w2 = wt[(size_t)(4 * e4 + 2) * 256 + t];
    float w3 = wt[(size_t)(4 * e4 + 3) * 256 + t];
#pragma unroll
    for (int jj = 0; jj < 8; ++jj) {
      float4 s = ((const float4*)sp[jj])[e4];
      a[jj] += s.x * w0 + s.y * w1 + s.z * w2 + s.w * w3;
    }
  }
#pragma unroll
  for (int jj = 0; jj < 8; ++jj) out[(size_t)(j0 + jj) * 256 + t] = a[jj];
}

// fused: passthrough copy of down into out + gate keys
__global__ void k_gatecopy(const float* __restrict__ down, const float* __restrict__ gw,
                           float* __restrict__ out, unsigned int* __restrict__ keys) {
  int p = blockIdx.x * 256 + threadIdx.x;
  float acc = 0.f;
  for (int c = 0; c < CCH; ++c) {
    float v = down[(size_t)c * HWP + p];
    out[(size_t)c * HWP + p] = v;
    acc += v * gw[c];
  }
  unsigned int u = __float_as_uint(acc);
  keys[p] = (u & 0x80000000u) ? ~u : (u | 0x80000000u);
}

__global__ void k_hist(const unsigned int* __restrict__ keys, unsigned int* hist,
                       const SelState* st, int r) {
  __shared__ unsigned int lh[256];
  int t = threadIdx.x;
  lh[t] = 0;
  __syncthreads();
  unsigned int key = keys[blockIdx.x * 256 + t];
  bool ok = (r == 0) || ((key >> (32 - 8 * r)) == st->P);
  if (ok) atomicAdd(&lh[(key >> (24 - 8 * r)) & 255u], 1u);
  __syncthreads();
  if (lh[t]) atomicAdd(&hist[t], lh[t]);
}

__global__ void k_scan(unsigned int* hist, SelState* st) {
  if (threadIdx.x == 0) {
    int need = st->kneed;
    unsigned int cum = 0;
    for (int b = 255; b >= 0; --b) {
      unsigned int h = hist[b];
      if (cum + h >= (unsigned int)need) {
        st->P = (st->P << 8) | (unsigned int)b;
        st->kneed = need - (int)cum;
        break;
      }
      cum += h;
    }
  }
  __syncthreads();
  hist[threadIdx.x] = 0;
}

__global__ void k_compact(const unsigned int* __restrict__ keys, SelState* st,
                          int* __restrict__ idx, int* __restrict__ eq) {
  int p = blockIdx.x * 256 + threadIdx.x;
  unsigned int key = keys[p];
  unsigned int P = st->P;
  if (key > P) {
    int pos = atomicAdd(&st->nGreater, 1);
    idx[pos] = p;
  } else if (key == P) {
    int e = atomicAdd(&st->nEqual, 1);
    if (e < 4096) eq[e] = p;
  }
}

__global__ void k_finalize(SelState* st, int* idx, int* eq) {
  if (threadIdx.x != 0) return;
  int n = st->nEqual;
  if (n > 4096) n = 4096;
  for (int i = 1; i < n; ++i) {
    int v = eq[i], j = i - 1;
    while (j >= 0 && eq[j] > v) { eq[j + 1] = eq[j]; --j; }
    eq[j + 1] = v;
  }
  int g = st->nGreater;
  for (int i = 0; i < st->kneed; ++i) idx[g + i] = eq[i];
}

__global__ void k_transpose(const float* __restrict__ in, float* __restrict__ out, int rows) {
  int o = blockIdx.x, c = threadIdx.x;
  out[(size_t)c * rows + o] = in[(size_t)o * 256 + c];
}

// gather rows at idx, project to Q,K,V, emit bf16 Qb/Kb[h][q][d] and Vt[h][d][q]
__global__ __launch_bounds__(256) void k_qkv2(const float* __restrict__ down,
                                              const float* __restrict__ srows,
                                              const int* __restrict__ idx,
                                              const float* __restrict__ wT,
                                              const float* __restrict__ bias,
                                              short* __restrict__ Qb,
                                              short* __restrict__ Kb,
                                              short* __restrict__ Vt) {
  __shared__ float xq[4][256], xk[4][256];
  int j0 = blockIdx.x * 4;
  int c = threadIdx.x;
  for (int r = 0; r < 4; ++r) {
    int p = idx[j0 + r];
    xq[r][c] = down[(size_t)c * HWP + p];
    xk[r][c] = srows[(size_t)(j0 + r) * 256 + c];
  }
  __syncthreads();
  float aq[4], ak[4], av[4];
#pragma unroll
  for (int r = 0; r < 4; ++r) {
    aq[r] = bias[c]; ak[r] = bias[256 + c]; av[r] = bias[512 + c];
  }
  for (int i = 0; i < 256; ++i) {
    float wq = wT[i * 768 + c];
    float wk = wT[i * 768 + 256 + c];
    float wv = wT[i * 768 + 512 + c];
#pragma unroll
    for (int r = 0; r < 4; ++r) {
      float xv = xq[r][i], kv = xk[r][i];
      aq[r] += xv * wq;
      ak[r] += kv * wk;
      av[r] += kv * wv;
    }
  }
  int h = c >> 5, d = c & 31;
#pragma unroll
  for (int r = 0; r < 4; ++r) {
    int j = j0 + r;
    Qb[((size_t)h * 2048 + j) * 32 + d] = (short)f2bf(aq[r]);
    Kb[((size_t)h * 2048 + j) * 32 + d] = (short)f2bf(ak[r]);
    Vt[((size_t)h * 32 + d) * 2048 + j] = (short)f2bf(av[r]);
  }
}

// S[h][q][k] = Q K^T (bf16 out). grid (qt=32, kt=16, h=8), 4 waves: wave = 16q x 128k.
__global__ __launch_bounds__(256) void k_sgemm(const short* __restrict__ Qb,
                                               const short* __restrict__ Kb,
                                               short* __restrict__ S) {
  int t = threadIdx.x;
  int l = t & 63, wv = t >> 6;
  int h = blockIdx.z;
  int q0 = blockIdx.x * 64 + wv * 16;
  int k0 = blockIdx.y * 128;
  short8 a = *(const short8*)&Qb[((size_t)h * 2048 + q0 + (l & 15)) * 32 + (l >> 4) * 8];
  f32x4 acc[8];
#pragma unroll
  for (int kt = 0; kt < 8; ++kt) { f32x4 z = {0.f, 0.f, 0.f, 0.f}; acc[kt] = z; }
#pragma unroll
  for (int kt = 0; kt < 8; ++kt) {
    short8 b = *(const short8*)&Kb[((size_t)h * 2048 + k0 + kt * 16 + (l & 15)) * 32 + (l >> 4) * 8];
    mfma_bf16(acc[kt], a, b);
  }
  asm volatile("s_nop 7\n\ts_nop 7" ::);
#pragma unroll
  for (int kt = 0; kt < 8; ++kt)
#pragma unroll
    for (int r = 0; r < 4; ++r)
      S[((size_t)h * 2048 + q0 + (l >> 4) * 4 + r) * 2048 + k0 + kt * 16 + (l & 15)] =
          (short)f2bf(acc[kt][r]);
}

// row softmax over 2048 keys, in place, normalized P bf16. grid (2048, 8), 256 thr.
__global__ __launch_bounds__(256) void k_softmax(short* __restrict__ S) {
  __shared__ float redm[4], reds[4];
  int t = threadIdx.x;
  int l = t & 63, wv = t >> 6;
  size_t base = ((size_t)blockIdx.y * 2048 + blockIdx.x) * 2048;
  short8 v = *(const short8*)&S[base + t * 8];
  const float scale = 0.17677669529663687f;
  float f[8];
#pragma unroll
  for (int i = 0; i < 8; ++i) f[i] = bf2f((unsigned short)v[i]) * scale;
  float m = f[0];
#pragma unroll
  for (int i = 1; i < 8; ++i) m = fmaxf(m, f[i]);
  for (int off = 1; off < 64; off <<= 1) m = fmaxf(m, __shfl_xor(m, off));
  if (l == 0) redm[wv] = m;
  __syncthreads();
  m = fmaxf(fmaxf(redm[0], redm[1]), fmaxf(redm[2], redm[3]));
  float e[8], ls = 0.f;
#pragma unroll
  for (int i = 0; i < 8; ++i) { e[i] = __expf(f[i] - m); ls += e[i]; }
  for (int off = 1; off < 64; off <<= 1) ls += __shfl_xor(ls, off);
  if (l == 0) reds[wv] = ls;
  __syncthreads();
  float L = reds[0] + reds[1] + reds[2] + reds[3];
  float rinv = 1.f / L;
  short8 o;
#pragma unroll
  for (int i = 0; i < 8; ++i) o[i] = (short)f2bf(e[i] * rinv);
  *(short8*)&S[base + t * 8] = o;
}

// O = P V. grid (32 qtiles, 8 h), 4 waves: wave = 16q x 32d, K=2048.
__global__ __launch_bounds__(256) void k_pvgemm(const short* __restrict__ P,
                                                const short* __restrict__ Vt,
                                                float* __restrict__ Oa) {
  int t = threadIdx.x;
  int l = t & 63, wv = t >> 6;
  int h = blockIdx.y;
  int q0 = blockIdx.x * 64 + wv * 16;
  f32x4 acc[2];
  { f32x4 z = {0.f, 0.f, 0.f, 0.f}; acc[0] = z; acc[1] = z; }
  const short* prow = P + ((size_t)h * 2048 + q0 + (l & 15)) * 2048 + (l >> 4) * 8;
  const short* vt0 = Vt + ((size_t)h * 32 + (l & 15)) * 2048 + (l >> 4) * 8;
#pragma unroll 4
  for (int k0 = 0; k0 < 2048; k0 += 32) {
    short8 a = *(const short8*)(prow + k0);
    short8 b0 = *(const short8*)(vt0 + k0);
    short8 b1 = *(const short8*)(vt0 + 16 * 2048 + k0);
    mfma_bf16(acc[0], a, b0);
    mfma_bf16(acc[1], a, b1);
  }
  asm volatile("s_nop 7\n\ts_nop 7" ::);
#pragma unroll
  for (int n = 0; n < 2; ++n)
#pragma unroll
    for (int r = 0; r < 4; ++r)
      Oa[(size_t)(q0 + (l >> 4) * 4 + r) * 256 + h * 32 + n * 16 + (l & 15)] = acc[n][r];
}

// out-projection (8 rows/block) fused with scatter into final output columns
__global__ __launch_bounds__(256) void k_outproj8(const float* __restrict__ Oa,
                                                  const float* __restrict__ owT,
                                                  const float* __restrict__ ob,
                                                  const int* __restrict__ idx,
                                                  float* __restrict__ out) {
  __shared__ float xo[8][256];
  int j0 = blockIdx.x * 8;
  int c = threadIdx.x;
  for (int r = 0; r < 8; ++r) xo[r][c] = Oa[(size_t)(j0 + r) * 256 + c];
  __syncthreads();
  float a[8];
#pragma unroll
  for (int r = 0; r < 8; ++r) a[r] = ob[c];
  for (int i = 0; i < 256; ++i) {
    float wv = owT[i * 256 + c];
#pragma unroll
    for (int r = 0; r < 8; ++r) a[r] += xo[r][i] * wv;
  }
#pragma unroll
  for (int r = 0; r < 8; ++r) out[(size_t)c * HWP + idx[j0 + r]] = a[r];
}

extern "C" void kernel_launch(void* const* d_in, const int* in_sizes, int n_in,
                              void* d_out, int out_size, void* d_ws, size_t ws_size,
                              hipStream_t stream) {
  const float* down  = (const float*)d_in[0];
  const float* swint = (const float*)d_in[1];
  const float* wt_w  = (const float*)d_in[2];
  const float* wt_b  = (const float*)d_in[3];
  const float* up_dw = (const float*)d_in[4];
  const float* up_db = (const float*)d_in[5];
  const float* up_cw = (const float*)d_in[6];
  const float* up_cb = (const float*)d_in[7];
  const float* gate_w = (const float*)d_in[8];
  const float* in_w  = (const float*)d_in[10];
  const float* in_b  = (const float*)d_in[11];
  const float* out_w = (const float*)d_in[12];
  const float* out_b = (const float*)d_in[13];
  float* out = (float*)d_out;
  char* ws = (char*)d_ws;

  float* bufA = (float*)ws;
  float* bufB = (float*)(ws + BUF_B_OFF);
  unsigned int* keys = (unsigned int*)(ws + KEYS_OFF);
  unsigned int* hist = (unsigned int*)(ws + HIST_OFF);
  SelState* st = (SelState*)(ws + STATE_OFF);
  int* idx = (int*)(ws + IDX_OFF);
  int* eq = (int*)(ws + EQ_OFF);
  float* Oa = (float*)(ws + OA_OFF);
  float* wTi = (float*)(ws + WTI_OFF);
  float* wTo = (float*)(ws + WTO_OFF);
  float* srows = (float*)(ws + SROWS_OFF);
  float* wt5 = (float*)(ws + WT5_OFF);
  short* Qb = (short*)(ws + QB_OFF);
  short* Kb = (short*)(ws + KB_OFF);
  short* Vt = (short*)(ws + VT_OFF);
  short* cpk = (short*)(ws + CPK_OFF);
  short* dpk = (short*)(ws + DPK_OFF);
  short* S = (short*)(ws + BUF_B_OFF);

  k_init<<<1, 256, 0, stream>>>(hist, st);

  // fused gate + passthrough copy, then exact top-k (radix select)
  k_gatecopy<<<256, 256, 0, stream>>>(down, gate_w, out, keys);
  for (int r = 0; r < 4; ++r) {
    k_hist<<<256, 256, 0, stream>>>(keys, hist, st, r);
    k_scan<<<1, 256, 0, stream>>>(hist, st);
  }
  k_compact<<<256, 256, 0, stream>>>(keys, st, idx, eq);
  k_finalize<<<1, 64, 0, stream>>>(st, idx, eq);

  // weight packs (batched over layers)
  k_packc3<<<dim3(256, 4), 256, 0, stream>>>(up_cw, cpk);
  k_packdc<<<dim3(256, 4), 256, 0, stream>>>(up_dw, dpk);

  // upsampler chain: MFMA bf16 implicit-GEMM (A/B ping-pong)
  k_wtconv<<<256, 64, 0, stream>>>(swint, wt_w, wt_b, bufA);
  k_deconv<8><<<dim3(1, 256), 256, 0, stream>>>(bufA, up_dw, up_db, bufB);
  k_conv3x<16><<<dim3(16, 4), 256, 0, stream>>>(bufB, cpk, up_cb, bufA);
  k_deconvx<16><<<dim3(16, 4, 4), 256, 0, stream>>>(bufA, dpk, up_db + 256, bufB);
  k_conv3x<32><<<dim3(32, 4), 256, 0, stream>>>(bufB, cpk + 589824, up_cb + 256, bufA);
  k_deconvx<32><<<dim3(32, 4, 4), 256, 0, stream>>>(bufA, dpk + 1048576, up_db + 512, bufB);
  k_conv3x<64><<<dim3(64, 4), 256, 0, stream>>>(bufB, cpk + 2 * 589824, up_cb + 512, bufA);
  k_deconvx<64><<<dim3(64, 4, 4), 256, 0, stream>>>(bufA, dpk + 2 * 1048576, up_db + 768, bufB);
  k_conv3x<128><<<dim3(128, 4), 256, 0, stream>>>(bufB, cpk + 3 * 589824, up_cb + 768, bufA);
  k_deconvx<128><<<dim3(128, 4, 4), 256, 0, stream>>>(bufA, dpk + 3 * 1048576, up_db + 1024, bufB);

  // transposed weights (bufA conv activations dead now)
  k_wt5<<<2304, 256, 0, stream>>>(up_cw + 2359296, wt5);
  k_transpose<<<768, 256, 0, stream>>>(in_w, wTi, 768);
  k_transpose<<<256, 256, 0, stream>>>(out_w, wTo, 256);

  // final conv3 only at the 2048 gathered positions (reads bufB)
  k_conv3sT<<<256, 256, 0, stream>>>(bufB, wt5, up_cb + 1024, idx, srows);

  // attention path: bf16 QKV, then 3-phase MFMA attention (S/P overlays bufB)
  k_qkv2<<<512, 256, 0, stream>>>(down, srows, idx, wTi, in_b, Qb, Kb, Vt);
  k_sgemm<<<dim3(32, 16, 8), 256, 0, stream>>>(Qb, Kb, S);
  k_softmax<<<dim3(2048, 8), 256, 0, stream>>>(S);
  k_pvgemm<<<dim3(32, 8), 256, 0, stream>>>(S, Vt, Oa);
  k_outproj8<<<256, 256, 0, stream>>>(Oa, wTo, out_b, idx, out);
}

// Round 6
// 1067.248 us; speedup vs baseline: 16.4247x; 1.0261x over previous
//
#include <hip/hip_runtime.h>
#include <math.h>

#define CCH 256
#define HWP 65536
#define PCI 40   // padded ci stride (shorts) in LDS

typedef short short8 __attribute__((ext_vector_type(8)));
typedef float f32x4 __attribute__((ext_vector_type(4)));
typedef unsigned short us4 __attribute__((ext_vector_type(4)));

__device__ inline unsigned short f2bf(float f) {
  unsigned u = __float_as_uint(f);
  return (unsigned short)((u + 0x7FFFu + ((u >> 16) & 1u)) >> 16);
}
__device__ inline float bf2f(unsigned short s) {
  return __uint_as_float(((unsigned)s) << 16);
}

__device__ inline void mfma_bf16(f32x4& d, short8 a, short8 b) {
  asm volatile("v_mfma_f32_16x16x32_bf16 %0, %1, %2, %0" : "+v"(d) : "v"(a), "v"(b));
}

// ---- ws layout (bytes) ----
static const size_t BUF_B_OFF = 67108864;        // bufA @0 (64MB), bufB @64MB
static const size_t TAIL_OFF  = 134217728;
static const size_t KEYS_OFF  = TAIL_OFF;
static const size_t HIST_OFF  = TAIL_OFF + 262144;
static const size_t STATE_OFF = TAIL_OFF + 263168;
static const size_t IDX_OFF   = TAIL_OFF + 263424;
static const size_t EQ_OFF    = TAIL_OFF + 271616;
// overlaid into bufA region (packed conv activations there stay <= 8.4MB):
static const size_t OA_OFF    = 6291456;  // written after conv chain only... (Oa used post-chain)
static const size_t WTI_OFF   = 8388608;
static const size_t WTO_OFF   = 9437184;
static const size_t SROWS_OFF = 10485760;
static const size_t WT5_OFF   = 20971520;
static const size_t QB_OFF    = 31457280;
static const size_t KB_OFF    = 32505856;
static const size_t VT_OFF    = 33554432;
static const size_t CPK_OFF   = 37748736;
static const size_t DPK_OFF   = 44040192;
// S / P bf16 [8][2048][2048] = 64MB lives in bufB after conv3sT consumed it.

struct SelState { unsigned int P; int kneed; int nGreater; int nEqual; };

__global__ void k_init(unsigned int* hist, SelState* st) {
  int t = threadIdx.x;
  hist[t] = 0;
  if (t == 0) { st->P = 0u; st->kneed = 2048; st->nGreater = 0; st->nEqual = 0; }
}

// 1x1 conv 768->256 on 8x8
__global__ void k_wtconv(const float* __restrict__ swint, const float* __restrict__ w,
                         const float* __restrict__ b, float* __restrict__ out) {
  int co = blockIdx.x, p = threadIdx.x;
  float acc = b[co];
  for (int ci = 0; ci < 768; ++ci) acc += swint[ci * 64 + p] * w[co * 768 + ci];
  out[co * 64 + p] = acc;
}

// deconv 4x4 stride2 pad2 + bias + relu, f32 in (S=8), packed-bf16 out
template <int S>
__global__ __launch_bounds__(256) void k_deconv(const float* __restrict__ x,
                                                const float* __restrict__ w,
                                                const float* __restrict__ bias,
                                                unsigned short* __restrict__ yp) {
  const int SO = 2 * S;
  const int TX = SO / 16;
  int co = blockIdx.y;
  int tile = blockIdx.x;
  int ty0 = (tile / TX) * 16, tx0 = (tile % TX) * 16;
  int t = threadIdx.x;
  int ly = t >> 4, lx = t & 15;
  int oy = ty0 + ly, ox = tx0 + lx;
  int iyb = (ty0 >> 1) - 1, ixb = (tx0 >> 1) - 1;
  int p = oy & 1, q = ox & 1;
  int iyA = ((oy + p - 2) >> 1) - iyb;
  int ixA = ((ox + q - 2) >> 1) - ixb;
  int i00 = (3 - p) * 4 + (3 - q);
  int i01 = (3 - p) * 4 + (1 - q);
  int i10 = (1 - p) * 4 + (3 - q);
  int i11 = (1 - p) * 4 + (1 - q);
  __shared__ float lx_s[8][10][10];
  __shared__ float lw_s[8][16];
  float acc = bias[co];
  for (int c0 = 0; c0 < CCH; c0 += 8) {
    __syncthreads();
    for (int i = t; i < 800; i += 256) {
      int u = i / 100, rem = i % 100;
      int r = rem / 10, c = rem % 10;
      int gy = iyb + r, gx = ixb + c;
      float v = 0.f;
      if (gy >= 0 && gy < S && gx >= 0 && gx < S)
        v = x[(size_t)(c0 + u) * S * S + gy * S + gx];
      lx_s[u][r][c] = v;
    }
    if (t < 128) {
      int u = t >> 4, e = t & 15;
      lw_s[u][e] = w[(size_t)(c0 + u) * 4096 + co * 16 + e];
    }
    __syncthreads();
#pragma unroll
    for (int u = 0; u < 8; ++u) {
      acc += lx_s[u][iyA][ixA]     * lw_s[u][i00]
           + lx_s[u][iyA][ixA + 1] * lw_s[u][i01]
           + lx_s[u][iyA + 1][ixA]     * lw_s[u][i10]
           + lx_s[u][iyA + 1][ixA + 1] * lw_s[u][i11];
    }
  }
  acc = fmaxf(acc, 0.f);
  yp[((size_t)(co >> 1) * SO * SO + (size_t)oy * SO + ox) * 2 + (co & 1)] = f2bf(acc);
}

// pack conv3 weights (4 layers): [co][ci][9] f32 -> bf16 [tap][co][ci]
__global__ void k_packc3(const float* __restrict__ w, short* __restrict__ wpk) {
  int layer = blockIdx.y;
  const float* wl = w + (size_t)layer * 589824;
  short* wo = wpk + (size_t)layer * 589824;
  int co = blockIdx.x, ci = threadIdx.x;
  for (int tap = 0; tap < 9; ++tap)
    wo[((size_t)(tap * 256 + co) * 256) + ci] = (short)f2bf(wl[((size_t)(co * 256 + ci)) * 9 + tap]);
}

// pack deconv weights (layers 1..4): [ci][co][4][4] f32 -> bf16 [pq][tt][co][ci]
__global__ void k_packdc(const float* __restrict__ w, short* __restrict__ wpk) {
  int layer = blockIdx.y;
  const float* wl = w + (size_t)(layer + 1) * 1048576;
  int co = blockIdx.x, ci = threadIdx.x;
  for (int pq = 0; pq < 4; ++pq) {
    int p = pq >> 1, q = pq & 1;
    for (int tt = 0; tt < 4; ++tt) {
      int dyi = tt >> 1, dxi = tt & 1;
      int wr = dyi ? (1 - p) : (3 - p);
      int wc = dxi ? (1 - q) : (3 - q);
      wpk[((size_t)layer * 1048576) + ((size_t)((pq * 4 + tt) * 256 + co) * 256) + ci] =
          (short)f2bf(wl[((size_t)(ci * 256 + co)) * 16 + wr * 4 + wc]);
    }
  }
}

// MFMA conv3x3 pad1 + bias. Packed bf16 in/out. Block: 64 co x S pos (one row).
template <int S>
__global__ __launch_bounds__(256) void k_conv3x(const unsigned* __restrict__ xp,
                                                const short* __restrict__ wpk,
                                                const float* __restrict__ bias,
                                                unsigned* __restrict__ yp) {
  constexpr int SEG = S;
  constexpr int WPC = (SEG >= 64) ? 2 : 1;
  constexpr int WCO = 4 / WPC;
  constexpr int COS = 64 / WCO;
  constexpr int MR = COS / 16;
  constexpr int PSP = SEG / WPC;
  constexpr int NR = PSP / 16;
  __shared__ short x_s[3 * (SEG + 2) * PCI];
  __shared__ short w_s[3 * 64 * PCI];
  unsigned* x_s32 = (unsigned*)x_s;
  int t = threadIdx.x;
  int l = t & 63, wv = t >> 6;
  int wcob = (wv % WCO) * COS;
  int wposb = (wv / WCO) * PSP;
  int row = blockIdx.x;
  int co0 = blockIdx.y * 64;
  f32x4 acc[MR][NR];
#pragma unroll
  for (int m = 0; m < MR; ++m)
#pragma unroll
    for (int n = 0; n < NR; ++n) { f32x4 z = {0.f, 0.f, 0.f, 0.f}; acc[m][n] = z; }
  for (int c0 = 0; c0 < CCH; c0 += 32) {
    int cb = c0 >> 1;
    __syncthreads();
    // stage x: 3 rows x (SEG+2) cols x 16 ci2 packed u32
    for (int i = t; i < 3 * (SEG + 2) * 16; i += 256) {
      int ci2 = i / (3 * (SEG + 2));
      int rc  = i % (3 * (SEG + 2));
      int r = rc / (SEG + 2), col = rc % (SEG + 2);
      int gy = row - 1 + r, gx = col - 1;
      unsigned v = 0;
      if (gy >= 0 && gy < S && gx >= 0 && gx < S)
        v = xp[(size_t)(cb + ci2) * S * S + (size_t)gy * S + gx];
      x_s32[rc * (PCI / 2) + ci2] = v;
    }
    for (int dyg = 0; dyg < 3; ++dyg) {
      if (dyg) __syncthreads();
      for (int i = t; i < 1536; i += 256) {
        int ci4 = i & 7;
        int tc = i >> 3;
        int dx = tc >> 6, co = tc & 63;
        us4 wv4 = *(const us4*)&wpk[((size_t)((dyg * 3 + dx) * 256 + co0 + co) * 256) + c0 + ci4 * 4];
        *(us4*)&w_s[tc * PCI + ci4 * 4] = wv4;
      }
      __syncthreads();
#pragma unroll
      for (int dx = 0; dx < 3; ++dx) {
        short8 a[MR], b[NR];
#pragma unroll
        for (int m = 0; m < MR; ++m)
          a[m] = *(const short8*)&w_s[(dx * 64 + wcob + m * 16 + (l & 15)) * PCI + (l >> 4) * 8];
#pragma unroll
        for (int n = 0; n < NR; ++n)
          b[n] = *(const short8*)&x_s[(dyg * (SEG + 2) + wposb + n * 16 + (l & 15) + dx) * PCI + (l >> 4) * 8];
#pragma unroll
        for (int m = 0; m < MR; ++m)
#pragma unroll
          for (int n = 0; n < NR; ++n) mfma_bf16(acc[m][n], a[m], b[n]);
      }
    }
  }
  asm volatile("s_nop 7\n\ts_nop 7" ::);
#pragma unroll
  for (int m = 0; m < MR; ++m)
#pragma unroll
    for (int n = 0; n < NR; ++n) {
      int cob = co0 + wcob + m * 16 + (l >> 4) * 4;
      int px = wposb + n * 16 + (l & 15);
#pragma unroll
      for (int r4p = 0; r4p < 2; ++r4p) {
        unsigned pk = (unsigned)f2bf(acc[m][n][2 * r4p] + bias[cob + 2 * r4p])
                    | ((unsigned)f2bf(acc[m][n][2 * r4p + 1] + bias[cob + 2 * r4p + 1]) << 16);
        yp[(size_t)((cob >> 1) + r4p) * S * S + (size_t)row * S + px] = pk;
      }
    }
}

// MFMA deconv4x4 s2 p2 + bias + relu, both q parities per block. Packed bf16 in/out.
template <int S>
__global__ __launch_bounds__(256) void k_deconvx2(const unsigned* __restrict__ xp,
                                                  const short* __restrict__ wpk,
                                                  const float* __restrict__ bias,
                                                  unsigned* __restrict__ yp) {
  constexpr int SEG = S;
  constexpr int WPC = (SEG >= 64) ? 2 : 1;
  constexpr int WCO = 4 / WPC;
  constexpr int COS = 64 / WCO;
  constexpr int MR = COS / 16;
  constexpr int PSP = SEG / WPC;
  constexpr int NR = PSP / 16;
  const int SO = 2 * S;
  __shared__ short x_s[2 * (SEG + 2) * PCI];
  __shared__ short w_s[8 * 64 * PCI];
  unsigned* x_s32 = (unsigned*)x_s;
  int t = threadIdx.x;
  int l = t & 63, wv = t >> 6;
  int wcob = (wv % WCO) * COS;
  int wposb = (wv / WCO) * PSP;
  int row = blockIdx.x;
  int co0 = blockIdx.y * 64;
  int p = blockIdx.z;
  f32x4 acc[2][MR][NR];
#pragma unroll
  for (int q = 0; q < 2; ++q)
#pragma unroll
    for (int m = 0; m < MR; ++m)
#pragma unroll
      for (int n = 0; n < NR; ++n) { f32x4 z = {0.f, 0.f, 0.f, 0.f}; acc[q][m][n] = z; }
  for (int c0 = 0; c0 < CCH; c0 += 32) {
    int cb = c0 >> 1;
    __syncthreads();
    // stage x: 2 rows x (SEG+2) cols x 16 ci2 (covers both q parities)
    for (int i = t; i < 2 * (SEG + 2) * 16; i += 256) {
      int ci2 = i / (2 * (SEG + 2));
      int rc  = i % (2 * (SEG + 2));
      int r = rc / (SEG + 2), col = rc % (SEG + 2);
      int gy = row + p - 1 + r, gx = col - 1;
      unsigned v = 0;
      if (gy >= 0 && gy < S && gx >= 0 && gx < S)
        v = xp[(size_t)(cb + ci2) * S * S + (size_t)gy * S + gx];
      x_s32[rc * (PCI / 2) + ci2] = v;
    }
    // stage w: 8 classes (q*4+tt) x 64 co x 32 ci
    for (int i = t; i < 4096; i += 256) {
      int seg8 = i & 7;
      int rowi = i >> 3;
      int c8 = rowi >> 6, co = rowi & 63;
      int qq = c8 >> 2, tt = c8 & 3;
      us4 wv4 = *(const us4*)&wpk[((size_t)(((2 * p + qq) * 4 + tt) * 256 + co0 + co) * 256) + c0 + seg8 * 4];
      *(us4*)&w_s[rowi * PCI + seg8 * 4] = wv4;
    }
    __syncthreads();
#pragma unroll
    for (int dyi = 0; dyi < 2; ++dyi) {
      short8 b[3][NR];
#pragma unroll
      for (int off = 0; off < 3; ++off)
#pragma unroll
        for (int n = 0; n < NR; ++n)
          b[off][n] = *(const short8*)&x_s[(dyi * (SEG + 2) + wposb + n * 16 + (l & 15) + off) * PCI + (l >> 4) * 8];
#pragma unroll
      for (int q = 0; q < 2; ++q)
#pragma unroll
        for (int dxi = 0; dxi < 2; ++dxi) {
          int c8 = q * 4 + dyi * 2 + dxi;
          short8 a[MR];
#pragma unroll
          for (int m = 0; m < MR; ++m)
            a[m] = *(const short8*)&w_s[(c8 * 64 + wcob + m * 16 + (l & 15)) * PCI + (l >> 4) * 8];
#pragma unroll
          for (int m = 0; m < MR; ++m)
#pragma unroll
            for (int n = 0; n < NR; ++n) mfma_bf16(acc[q][m][n], a[m], b[dxi + q][n]);
        }
    }
  }
  asm volatile("s_nop 7\n\ts_nop 7" ::);
  int oy = 2 * row + p;
#pragma unroll
  for (int m = 0; m < MR; ++m)
#pragma unroll
    for (int n = 0; n < NR; ++n) {
      int px = wposb + n * 16 + (l & 15);
#pragma unroll
      for (int r4p = 0; r4p < 2; ++r4p) {
        int cob = co0 + wcob + m * 16 + (l >> 4) * 4 + 2 * r4p;
        float b0 = bias[cob], b1 = bias[cob + 1];
        unsigned pk0 = (unsigned)f2bf(fmaxf(acc[0][m][n][2 * r4p] + b0, 0.f))
                     | ((unsigned)f2bf(fmaxf(acc[0][m][n][2 * r4p + 1] + b1, 0.f)) << 16);
        unsigned pk1 = (unsigned)f2bf(fmaxf(acc[1][m][n][2 * r4p] + b0, 0.f))
                     | ((unsigned)f2bf(fmaxf(acc[1][m][n][2 * r4p + 1] + b1, 0.f)) << 16);
        uint2 pk = make_uint2(pk0, pk1);
        *(uint2*)&yp[(size_t)(cob >> 1) * SO * SO + (size_t)oy * SO + 2 * px] = pk;
      }
    }
}

// transpose stage-5 conv weights: w[co][ci*9+e] -> wt[(ci*9+e)][co]
__global__ void k_wt5(const float* __restrict__ w, float* __restrict__ wt) {
  int e9 = blockIdx.x;
  int co = threadIdx.x;
  int ci = e9 / 9, e = e9 % 9;
  wt[(size_t)e9 * 256 + co] = w[((size_t)co * 256 + ci) * 9 + e];
}

// sparse final conv3 at 8 gathered positions per block; packed bf16 input.
__global__ __launch_bounds__(256) void k_conv3sT(const unsigned* __restrict__ xp,
                                                 const float* __restrict__ wt,
                                                 const float* __restrict__ bias,
                                                 const int* __restrict__ idx,
                                                 float* __restrict__ out) {
  __shared__ float sp[8][2304];
  int t = threadIdx.x;
  int j0 = blockIdx.x * 8;
  for (int i = t; i < 8 * 1152; i += 256) {
    int jj = i / 1152, r2 = i % 1152;
    int ci2 = r2 / 9, e = r2 % 9;
    int pI = idx[j0 + jj];
    int py = pI >> 8, px = pI & 255;
    int gy = py - 1 + e / 3, gx = px - 1 + e % 3;
    unsigned v = 0;
    if (gy >= 0 && gy < 256 && gx >= 0 && gx < 256)
      v = xp[(size_t)ci2 * HWP + gy * 256 + gx];
    sp[jj][(2 * ci2) * 9 + e] = bf2f((unsigned short)(v & 0xFFFFu));
    sp[jj][(2 * ci2 + 1) * 9 + e] = bf2f((unsigned short)(v >> 16));
  }
  __syncthreads();
  float bv = bias[t];
  float a[8];
#pragma unroll
  for (int jj = 0; jj < 8; ++jj) a[jj] = bv;
  for (int e4 = 0; e4 < 576; ++e4) {
    float w0 = wt[(size_t)(4 * e4 + 0) * 256 + t];
    float w1 = wt[(size_t)(4 * e4 + 1) * 256 + t];
    float w2 = wt[(size_t)(4 * e4 + 2) * 256 + t];
    float w3 = wt[(size_t)(4 * e4 + 3) * 256 + t];
#pragma unroll
    for (int jj = 0; jj < 8; ++jj) {
      float4 s = ((const float4*)sp[jj])[e4];
      a[jj] += s.x * w0 + s.y * w1 + s.z * w2 + s.w * w3;
    }
  }
#pragma unroll
  for (int jj = 0; jj < 8; ++jj) out[(size_t)(j0 + jj) * 256 + t] = a[jj];
}

// fused: passthrough copy of down into out + gate keys
__global__ void k_gatecopy(const float* __restrict__ down, const float* __restrict__ gw,
                           float* __restrict__ out, unsigned int* __restrict__ keys) {
  int p = blockIdx.x * 256 + threadIdx.x;
  float acc = 0.f;
  for (int c = 0; c < CCH; ++c) {
    float v = down[(size_t)c * HWP + p];
    out[(size_t)c * HWP + p] = v;
    acc += v * gw[c];
  }
  unsigned int u = __float_as_uint(acc);
  keys[p] = (u & 0x80000000u) ? ~u : (u | 0x80000000u);
}

__global__ void k_hist(const unsigned int* __restrict__ keys, unsigned int* hist,
                       const SelState* st, int r) {
  __shared__ unsigned int lh[256];
  int t = threadIdx.x;
  lh[t] = 0;
  __syncthreads();
  unsigned int key = keys[blockIdx.x * 256 + t];
  bool ok = (r == 0) || ((key >> (32 - 8 * r)) == st->P);
  if (ok) atomicAdd(&lh[(key >> (24 - 8 * r)) & 255u], 1u);
  __syncthreads();
  if (lh[t]) atomicAdd(&hist[t], lh[t]);
}

__global__ void k_scan(unsigned int* hist, SelState* st) {
  if (threadIdx.x == 0) {
    int need = st->kneed;
    unsigned int cum = 0;
    for (int b = 255; b >= 0; --b) {
      unsigned int h = hist[b];
      if (cum + h >= (unsigned int)need) {
        st->P = (st->P << 8) | (unsigned int)b;
        st->kneed = need - (int)cum;
        break;
      }
      cum += h;
    }
  }
  __syncthreads();
  hist[threadIdx.x] = 0;
}

__global__ void k_compact(const unsigned int* __restrict__ keys, SelState* st,
                          int* __restrict__ idx, int* __restrict__ eq) {
  int p = blockIdx.x * 256 + threadIdx.x;
  unsigned int key = keys[p];
  unsigned int P = st->P;
  if (key > P) {
    int pos = atomicAdd(&st->nGreater, 1);
    idx[pos] = p;
  } else if (key == P) {
    int e = atomicAdd(&st->nEqual, 1);
    if (e < 4096) eq[e] = p;
  }
}

__global__ void k_finalize(SelState* st, int* idx, int* eq) {
  if (threadIdx.x != 0) return;
  int n = st->nEqual;
  if (n > 4096) n = 4096;
  for (int i = 1; i < n; ++i) {
    int v = eq[i], j = i - 1;
    while (j >= 0 && eq[j] > v) { eq[j + 1] = eq[j]; --j; }
    eq[j + 1] = v;
  }
  int g = st->nGreater;
  for (int i = 0; i < st->kneed; ++i) idx[g + i] = eq[i];
}

__global__ void k_transpose(const float* __restrict__ in, float* __restrict__ out, int rows) {
  int o = blockIdx.x, c = threadIdx.x;
  out[(size_t)c * rows + o] = in[(size_t)o * 256 + c];
}

// gather rows at idx, project to Q,K,V, emit bf16 Qb/Kb[h][q][d] and Vt[h][d][q]
__global__ __launch_bounds__(256) void k_qkv2(const float* __restrict__ down,
                                              const float* __restrict__ srows,
                                              const int* __restrict__ idx,
                                              const float* __restrict__ wT,
                                              const float* __restrict__ bias,
                                              short* __restrict__ Qb,
                                              short* __restrict__ Kb,
                                              short* __restrict__ Vt) {
  __shared__ float xq[4][256], xk[4][256];
  int j0 = blockIdx.x * 4;
  int c = threadIdx.x;
  for (int r = 0; r < 4; ++r) {
    int p = idx[j0 + r];
    xq[r][c] = down[(size_t)c * HWP + p];
    xk[r][c] = srows[(size_t)(j0 + r) * 256 + c];
  }
  __syncthreads();
  float aq[4], ak[4], av[4];
#pragma unroll
  for (int r = 0; r < 4; ++r) {
    aq[r] = bias[c]; ak[r] = bias[256 + c]; av[r] = bias[512 + c];
  }
  for (int i = 0; i < 256; ++i) {
    float wq = wT[i * 768 + c];
    float wk = wT[i * 768 + 256 + c];
    float wv = wT[i * 768 + 512 + c];
#pragma unroll
    for (int r = 0; r < 4; ++r) {
      float xv = xq[r][i], kv = xk[r][i];
      aq[r] += xv * wq;
      ak[r] += kv * wk;
      av[r] += kv * wv;
    }
  }
  int h = c >> 5, d = c & 31;
#pragma unroll
  for (int r = 0; r < 4; ++r) {
    int j = j0 + r;
    Qb[((size_t)h * 2048 + j) * 32 + d] = (short)f2bf(aq[r]);
    Kb[((size_t)h * 2048 + j) * 32 + d] = (short)f2bf(ak[r]);
    Vt[((size_t)h * 32 + d) * 2048 + j] = (short)f2bf(av[r]);
  }
}

// S[h][q][k] = Q K^T (bf16 out). grid (qt=32, kt=16, h=8), 4 waves: wave = 16q x 128k.
__global__ __launch_bounds__(256) void k_sgemm(const short* __restrict__ Qb,
                                               const short* __restrict__ Kb,
                                               short* __restrict__ S) {
  int t = threadIdx.x;
  int l = t & 63, wv = t >> 6;
  int h = blockIdx.z;
  int q0 = blockIdx.x * 64 + wv * 16;
  int k0 = blockIdx.y * 128;
  short8 a = *(const short8*)&Qb[((size_t)h * 2048 + q0 + (l & 15)) * 32 + (l >> 4) * 8];
  f32x4 acc[8];
#pragma unroll
  for (int kt = 0; kt < 8; ++kt) { f32x4 z = {0.f, 0.f, 0.f, 0.f}; acc[kt] = z; }
#pragma unroll
  for (int kt = 0; kt < 8; ++kt) {
    short8 b = *(const short8*)&Kb[((size_t)h * 2048 + k0 + kt * 16 + (l & 15)) * 32 + (l >> 4) * 8];
    mfma_bf16(acc[kt], a, b);
  }
  asm volatile("s_nop 7\n\ts_nop 7" ::);
#pragma unroll
  for (int kt = 0; kt < 8; ++kt)
#pragma unroll
    for (int r = 0; r < 4; ++r)
      S[((size_t)h * 2048 + q0 + (l >> 4) * 4 + r) * 2048 + k0 + kt * 16 + (l & 15)] =
          (short)f2bf(acc[kt][r]);
}

// row softmax over 2048 keys, in place, normalized P bf16. grid (2048, 8), 256 thr.
__global__ __launch_bounds__(256) void k_softmax(short* __restrict__ S) {
  __shared__ float redm[4], reds[4];
  int t = threadIdx.x;
  int l = t & 63, wv = t >> 6;
  size_t base = ((size_t)blockIdx.y * 2048 + blockIdx.x) * 2048;
  short8 v = *(const short8*)&S[base + t * 8];
  const float scale = 0.17677669529663687f;
  float f[8];
#pragma unroll
  for (int i = 0; i < 8; ++i) f[i] = bf2f((unsigned short)v[i]) * scale;
  float m = f[0];
#pragma unroll
  for (int i = 1; i < 8; ++i) m = fmaxf(m, f[i]);
  for (int off = 1; off < 64; off <<= 1) m = fmaxf(m, __shfl_xor(m, off));
  if (l == 0) redm[wv] = m;
  __syncthreads();
  m = fmaxf(fmaxf(redm[0], redm[1]), fmaxf(redm[2], redm[3]));
  float e[8], ls = 0.f;
#pragma unroll
  for (int i = 0; i < 8; ++i) { e[i] = __expf(f[i] - m); ls += e[i]; }
  for (int off = 1; off < 64; off <<= 1) ls += __shfl_xor(ls, off);
  if (l == 0) reds[wv] = ls;
  __syncthreads();
  float L = reds[0] + reds[1] + reds[2] + reds[3];
  float rinv = 1.f / L;
  short8 o;
#pragma unroll
  for (int i = 0; i < 8; ++i) o[i] = (short)f2bf(e[i] * rinv);
  *(short8*)&S[base + t * 8] = o;
}

// O = P V. grid (32 qtiles, 8 h), 4 waves: wave = 16q x 32d, K=2048.
__global__ __launch_bounds__(256) void k_pvgemm(const short* __restrict__ P,
                                                const short* __restrict__ Vt,
                                                float* __restrict__ Oa) {
  int t = threadIdx.x;
  int l = t & 63, wv = t >> 6;
  int h = blockIdx.y;
  int q0 = blockIdx.x * 64 + wv * 16;
  f32x4 acc[2];
  { f32x4 z = {0.f, 0.f, 0.f, 0.f}; acc[0] = z; acc[1] = z; }
  const short* prow = P + ((size_t)h * 2048 + q0 + (l & 15)) * 2048 + (l >> 4) * 8;
  const short* vt0 = Vt + ((size_t)h * 32 + (l & 15)) * 2048 + (l >> 4) * 8;
#pragma unroll 4
  for (int k0 = 0; k0 < 2048; k0 += 32) {
    short8 a = *(const short8*)(prow + k0);
    short8 b0 = *(const short8*)(vt0 + k0);
    short8 b1 = *(const short8*)(vt0 + 16 * 2048 + k0);
    mfma_bf16(acc[0], a, b0);
    mfma_bf16(acc[1], a, b1);
  }
  asm volatile("s_nop 7\n\ts_nop 7" ::);
#pragma unroll
  for (int n = 0; n < 2; ++n)
#pragma unroll
    for (int r = 0; r < 4; ++r)
      Oa[(size_t)(q0 + (l >> 4) * 4 + r) * 256 + h * 32 + n * 16 + (l & 15)] = acc[n][r];
}

// out-projection (8 rows/block) fused with scatter into final output columns
__global__ __launch_bounds__(256) void k_outproj8(const float* __restrict__ Oa,
                                                  const float* __restrict__ owT,
                                                  const float* __restrict__ ob,
                                                  const int* __restrict__ idx,
                                                  float* __restrict__ out) {
  __shared__ float xo[8][256];
  int j0 = blockIdx.x * 8;
  int c = threadIdx.x;
  for (int r = 0; r < 8; ++r) xo[r][c] = Oa[(size_t)(j0 + r) * 256 + c];
  __syncthreads();
  float a[8];
#pragma unroll
  for (int r = 0; r < 8; ++r) a[r] = ob[c];
  for (int i = 0; i < 256; ++i) {
    float wv = owT[i * 256 + c];
#pragma unroll
    for (int r = 0; r < 8; ++r) a[r] += xo[r][i] * wv;
  }
#pragma unroll
  for (int r = 0; r < 8; ++r) out[(size_t)c * HWP + idx[j0 + r]] = a[r];
}

extern "C" void kernel_launch(void* const* d_in, const int* in_sizes, int n_in,
                              void* d_out, int out_size, void* d_ws, size_t ws_size,
                              hipStream_t stream) {
  const float* down  = (const float*)d_in[0];
  const float* swint = (const float*)d_in[1];
  const float* wt_w  = (const float*)d_in[2];
  const float* wt_b  = (const float*)d_in[3];
  const float* up_dw = (const float*)d_in[4];
  const float* up_db = (const float*)d_in[5];
  const float* up_cw = (const float*)d_in[6];
  const float* up_cb = (const float*)d_in[7];
  const float* gate_w = (const float*)d_in[8];
  const float* in_w  = (const float*)d_in[10];
  const float* in_b  = (const float*)d_in[11];
  const float* out_w = (const float*)d_in[12];
  const float* out_b = (const float*)d_in[13];
  float* out = (float*)d_out;
  char* ws = (char*)d_ws;

  float* bufA = (float*)ws;
  float* bufB = (float*)(ws + BUF_B_OFF);
  unsigned* actA = (unsigned*)ws;
  unsigned* actB = (unsigned*)(ws + BUF_B_OFF);
  unsigned int* keys = (unsigned int*)(ws + KEYS_OFF);
  unsigned int* hist = (unsigned int*)(ws + HIST_OFF);
  SelState* st = (SelState*)(ws + STATE_OFF);
  int* idx = (int*)(ws + IDX_OFF);
  int* eq = (int*)(ws + EQ_OFF);
  float* Oa = (float*)(ws + OA_OFF);
  float* wTi = (float*)(ws + WTI_OFF);
  float* wTo = (float*)(ws + WTO_OFF);
  float* srows = (float*)(ws + SROWS_OFF);
  float* wt5 = (float*)(ws + WT5_OFF);
  short* Qb = (short*)(ws + QB_OFF);
  short* Kb = (short*)(ws + KB_OFF);
  short* Vt = (short*)(ws + VT_OFF);
  short* cpk = (short*)(ws + CPK_OFF);
  short* dpk = (short*)(ws + DPK_OFF);
  short* S = (short*)(ws + BUF_B_OFF);

  k_init<<<1, 256, 0, stream>>>(hist, st);

  // fused gate + passthrough copy, then exact top-k (radix select)
  k_gatecopy<<<256, 256, 0, stream>>>(down, gate_w, out, keys);
  for (int r = 0; r < 4; ++r) {
    k_hist<<<256, 256, 0, stream>>>(keys, hist, st, r);
    k_scan<<<1, 256, 0, stream>>>(hist, st);
  }
  k_compact<<<256, 256, 0, stream>>>(keys, st, idx, eq);
  k_finalize<<<1, 64, 0, stream>>>(st, idx, eq);

  // weight packs (batched over layers)
  k_packc3<<<dim3(256, 4), 256, 0, stream>>>(up_cw, cpk);
  k_packdc<<<dim3(256, 4), 256, 0, stream>>>(up_dw, dpk);

  // upsampler chain: MFMA bf16 implicit-GEMM, packed-bf16 activations (A/B ping-pong)
  k_wtconv<<<256, 64, 0, stream>>>(swint, wt_w, wt_b, bufA);
  k_deconv<8><<<dim3(1, 256), 256, 0, stream>>>(bufA, up_dw, up_db, (unsigned short*)actB);
  k_conv3x<16><<<dim3(16, 4), 256, 0, stream>>>(actB, cpk, up_cb, actA);
  k_deconvx2<16><<<dim3(16, 4, 2), 256, 0, stream>>>(actA, dpk, up_db + 256, actB);
  k_conv3x<32><<<dim3(32, 4), 256, 0, stream>>>(actB, cpk + 589824, up_cb + 256, actA);
  k_deconvx2<32><<<dim3(32, 4, 2), 256, 0, stream>>>(actA, dpk + 1048576, up_db + 512, actB);
  k_conv3x<64><<<dim3(64, 4), 256, 0, stream>>>(actB, cpk + 2 * 589824, up_cb + 512, actA);
  k_deconvx2<64><<<dim3(64, 4, 2), 256, 0, stream>>>(actA, dpk + 2 * 1048576, up_db + 768, actB);
  k_conv3x<128><<<dim3(128, 4), 256, 0, stream>>>(actB, cpk + 3 * 589824, up_cb + 768, actA);
  k_deconvx2<128><<<dim3(128, 4, 2), 256, 0, stream>>>(actA, dpk + 3 * 1048576, up_db + 1024, actB);

  // transposed weights (bufA conv activations dead now)
  k_wt5<<<2304, 256, 0, stream>>>(up_cw + 2359296, wt5);
  k_transpose<<<768, 256, 0, stream>>>(in_w, wTi, 768);
  k_transpose<<<256, 256, 0, stream>>>(out_w, wTo, 256);

  // final conv3 only at the 2048 gathered positions (reads packed actB)
  k_conv3sT<<<256, 256, 0, stream>>>(actB, wt5, up_cb + 1024, idx, srows);

  // attention path: bf16 QKV, then 3-phase MFMA attention (S/P overlays bufB)
  k_qkv2<<<512, 256, 0, stream>>>(down, srows, idx, wTi, in_b, Qb, Kb, Vt);
  k_sgemm<<<dim3(32, 16, 8), 256, 0, stream>>>(Qb, Kb, S);
  k_softmax<<<dim3(2048, 8), 256, 0, stream>>>(S);
  k_pvgemm<<<dim3(32, 8), 256, 0, stream>>>(S, Vt, Oa);
  k_outproj8<<<256, 256, 0, stream>>>(Oa, wTo, out_b, idx, out);
}

// Round 7
// 901.296 us; speedup vs baseline: 19.4489x; 1.1841x over previous
//
#include <hip/hip_runtime.h>
#include <math.h>

#define CCH 256
#define HWP 65536
#define PCI 40   // padded ci stride (shorts) in LDS

typedef short short8 __attribute__((ext_vector_type(8)));
typedef float f32x4 __attribute__((ext_vector_type(4)));
typedef unsigned short us4 __attribute__((ext_vector_type(4)));

__device__ inline unsigned short f2bf(float f) {
  unsigned u = __float_as_uint(f);
  return (unsigned short)((u + 0x7FFFu + ((u >> 16) & 1u)) >> 16);
}
__device__ inline float bf2f(unsigned short s) {
  return __uint_as_float(((unsigned)s) << 16);
}

__device__ inline void mfma_bf16(f32x4& d, short8 a, short8 b) {
  asm volatile("v_mfma_f32_16x16x32_bf16 %0, %1, %2, %0" : "+v"(d) : "v"(a), "v"(b));
}

// ---- ws layout (bytes) ----
static const size_t BUF_B_OFF = 67108864;        // bufA @0 (64MB), bufB @64MB
static const size_t TAIL_OFF  = 134217728;
static const size_t KEYS_OFF  = TAIL_OFF;
static const size_t HIST_OFF  = TAIL_OFF + 262144;
static const size_t STATE_OFF = TAIL_OFF + 263168;
static const size_t IDX_OFF   = TAIL_OFF + 263424;
static const size_t EQ_OFF    = TAIL_OFF + 271616;
// overlaid into bufA region (packed conv activations there stay <= 8.4MB):
static const size_t OA_OFF    = 6291456;
static const size_t WTI_OFF   = 8388608;
static const size_t WTO_OFF   = 9437184;
static const size_t SROWS_OFF = 10485760;
static const size_t WT5_OFF   = 20971520;
static const size_t QB_OFF    = 31457280;
static const size_t KB_OFF    = 32505856;
static const size_t VT_OFF    = 33554432;
static const size_t CPK_OFF   = 37748736;
static const size_t DPK_OFF   = 44040192;

struct SelState { unsigned int P; int kneed; int nGreater; int nEqual; };

__global__ void k_init(unsigned int* hist, SelState* st) {
  int t = threadIdx.x;
  hist[t] = 0;
  if (t == 0) { st->P = 0u; st->kneed = 2048; st->nGreater = 0; st->nEqual = 0; }
}

// 1x1 conv 768->256 on 8x8
__global__ void k_wtconv(const float* __restrict__ swint, const float* __restrict__ w,
                         const float* __restrict__ b, float* __restrict__ out) {
  int co = blockIdx.x, p = threadIdx.x;
  float acc = b[co];
  for (int ci = 0; ci < 768; ++ci) acc += swint[ci * 64 + p] * w[co * 768 + ci];
  out[co * 64 + p] = acc;
}

// deconv 4x4 stride2 pad2 + bias + relu, f32 in (S=8), packed-bf16 out
template <int S>
__global__ __launch_bounds__(256) void k_deconv(const float* __restrict__ x,
                                                const float* __restrict__ w,
                                                const float* __restrict__ bias,
                                                unsigned short* __restrict__ yp) {
  const int SO = 2 * S;
  const int TX = SO / 16;
  int co = blockIdx.y;
  int tile = blockIdx.x;
  int ty0 = (tile / TX) * 16, tx0 = (tile % TX) * 16;
  int t = threadIdx.x;
  int ly = t >> 4, lx = t & 15;
  int oy = ty0 + ly, ox = tx0 + lx;
  int iyb = (ty0 >> 1) - 1, ixb = (tx0 >> 1) - 1;
  int p = oy & 1, q = ox & 1;
  int iyA = ((oy + p - 2) >> 1) - iyb;
  int ixA = ((ox + q - 2) >> 1) - ixb;
  int i00 = (3 - p) * 4 + (3 - q);
  int i01 = (3 - p) * 4 + (1 - q);
  int i10 = (1 - p) * 4 + (3 - q);
  int i11 = (1 - p) * 4 + (1 - q);
  __shared__ float lx_s[8][10][10];
  __shared__ float lw_s[8][16];
  float acc = bias[co];
  for (int c0 = 0; c0 < CCH; c0 += 8) {
    __syncthreads();
    for (int i = t; i < 800; i += 256) {
      int u = i / 100, rem = i % 100;
      int r = rem / 10, c = rem % 10;
      int gy = iyb + r, gx = ixb + c;
      float v = 0.f;
      if (gy >= 0 && gy < S && gx >= 0 && gx < S)
        v = x[(size_t)(c0 + u) * S * S + gy * S + gx];
      lx_s[u][r][c] = v;
    }
    if (t < 128) {
      int u = t >> 4, e = t & 15;
      lw_s[u][e] = w[(size_t)(c0 + u) * 4096 + co * 16 + e];
    }
    __syncthreads();
#pragma unroll
    for (int u = 0; u < 8; ++u) {
      acc += lx_s[u][iyA][ixA]     * lw_s[u][i00]
           + lx_s[u][iyA][ixA + 1] * lw_s[u][i01]
           + lx_s[u][iyA + 1][ixA]     * lw_s[u][i10]
           + lx_s[u][iyA + 1][ixA + 1] * lw_s[u][i11];
    }
  }
  acc = fmaxf(acc, 0.f);
  yp[((size_t)(co >> 1) * SO * SO + (size_t)oy * SO + ox) * 2 + (co & 1)] = f2bf(acc);
}

// pack conv3 weights (4 layers): [co][ci][9] f32 -> bf16 [tap][co][ci]
__global__ void k_packc3(const float* __restrict__ w, short* __restrict__ wpk) {
  int layer = blockIdx.y;
  const float* wl = w + (size_t)layer * 589824;
  short* wo = wpk + (size_t)layer * 589824;
  int co = blockIdx.x, ci = threadIdx.x;
  for (int tap = 0; tap < 9; ++tap)
    wo[((size_t)(tap * 256 + co) * 256) + ci] = (short)f2bf(wl[((size_t)(co * 256 + ci)) * 9 + tap]);
}

// pack deconv weights (layers 1..4): [ci][co][4][4] f32 -> bf16 [pq][tt][co][ci]
__global__ void k_packdc(const float* __restrict__ w, short* __restrict__ wpk) {
  int layer = blockIdx.y;
  const float* wl = w + (size_t)(layer + 1) * 1048576;
  int co = blockIdx.x, ci = threadIdx.x;
  for (int pq = 0; pq < 4; ++pq) {
    int p = pq >> 1, q = pq & 1;
    for (int tt = 0; tt < 4; ++tt) {
      int dyi = tt >> 1, dxi = tt & 1;
      int wr = dyi ? (1 - p) : (3 - p);
      int wc = dxi ? (1 - q) : (3 - q);
      wpk[((size_t)layer * 1048576) + ((size_t)((pq * 4 + tt) * 256 + co) * 256) + ci] =
          (short)f2bf(wl[((size_t)(ci * 256 + co)) * 16 + wr * 4 + wc]);
    }
  }
}

// MFMA conv3x3 pad1 + bias, 2 output rows per block. Packed bf16 in/out.
template <int S>
__global__ __launch_bounds__(256) void k_conv3x2(const unsigned* __restrict__ xp,
                                                 const short* __restrict__ wpk,
                                                 const float* __restrict__ bias,
                                                 unsigned* __restrict__ yp) {
  constexpr int SEG = S;
  constexpr int WPC = (SEG >= 64) ? 2 : 1;
  constexpr int WCO = 4 / WPC;
  constexpr int COS = 64 / WCO;
  constexpr int MR = COS / 16;
  constexpr int PSP = SEG / WPC;
  constexpr int NR = PSP / 16;
  constexpr int CBK = (SEG + 2 + 31) / 32;
  __shared__ short x_s[4 * (SEG + 2) * PCI];
  __shared__ short w_s[3 * 64 * PCI];
  unsigned* x_s32 = (unsigned*)x_s;
  int t = threadIdx.x;
  int l = t & 63, wv = t >> 6;
  int wcob = (wv % WCO) * COS;
  int wposb = (wv / WCO) * PSP;
  int row0 = blockIdx.x * 2;
  int co0 = blockIdx.y * 64;
  int colb = t & 31, ci2b = t >> 5;
  f32x4 acc[2][MR][NR];
#pragma unroll
  for (int o = 0; o < 2; ++o)
#pragma unroll
    for (int m = 0; m < MR; ++m)
#pragma unroll
      for (int n = 0; n < NR; ++n) { f32x4 z = {0.f, 0.f, 0.f, 0.f}; acc[o][m][n] = z; }
  for (int c0 = 0; c0 < CCH; c0 += 32) {
    int cb = c0 >> 1;
    __syncthreads();
    // stage x: rows row0-1 .. row0+2, 16 ci2; shift/add index math only
#pragma unroll
    for (int r = 0; r < 4; ++r) {
      int gy = row0 - 1 + r;
      bool yok = (gy >= 0 && gy < S);
#pragma unroll
      for (int cbk = 0; cbk < CBK; ++cbk) {
        int col = colb + cbk * 32;
        if (col < SEG + 2) {
          int gx = col - 1;
          bool ok = yok && (gx >= 0) && (gx < S);
          unsigned v0 = 0, v1 = 0;
          if (ok) {
            size_t gbase = (size_t)(cb + ci2b) * S * S + (size_t)gy * S + gx;
            v0 = xp[gbase];
            v1 = xp[gbase + (size_t)8 * S * S];
          }
          int lb = (r * (SEG + 2) + col) * (PCI / 2);
          x_s32[lb + ci2b] = v0;
          x_s32[lb + ci2b + 8] = v1;
        }
      }
    }
    for (int dyg = 0; dyg < 3; ++dyg) {
      if (dyg) __syncthreads();
      for (int i = t; i < 1536; i += 256) {
        int ci4 = i & 7;
        int tc = i >> 3;
        int dx = tc >> 6, co = tc & 63;
        us4 wv4 = *(const us4*)&wpk[((size_t)((dyg * 3 + dx) * 256 + co0 + co) * 256) + c0 + ci4 * 4];
        *(us4*)&w_s[tc * PCI + ci4 * 4] = wv4;
      }
      __syncthreads();
#pragma unroll
      for (int o = 0; o < 2; ++o)
#pragma unroll
        for (int dx = 0; dx < 3; ++dx) {
          short8 a[MR], b[NR];
#pragma unroll
          for (int m = 0; m < MR; ++m)
            a[m] = *(const short8*)&w_s[(dx * 64 + wcob + m * 16 + (l & 15)) * PCI + (l >> 4) * 8];
#pragma unroll
          for (int n = 0; n < NR; ++n)
            b[n] = *(const short8*)&x_s[((dyg + o) * (SEG + 2) + wposb + n * 16 + (l & 15) + dx) * PCI + (l >> 4) * 8];
#pragma unroll
          for (int m = 0; m < MR; ++m)
#pragma unroll
            for (int n = 0; n < NR; ++n) mfma_bf16(acc[o][m][n], a[m], b[n]);
        }
    }
  }
  asm volatile("s_nop 7\n\ts_nop 7" ::);
#pragma unroll
  for (int o = 0; o < 2; ++o)
#pragma unroll
    for (int m = 0; m < MR; ++m)
#pragma unroll
      for (int n = 0; n < NR; ++n) {
        int cob = co0 + wcob + m * 16 + (l >> 4) * 4;
        int px = wposb + n * 16 + (l & 15);
#pragma unroll
        for (int r4p = 0; r4p < 2; ++r4p) {
          unsigned pk = (unsigned)f2bf(acc[o][m][n][2 * r4p] + bias[cob + 2 * r4p])
                      | ((unsigned)f2bf(acc[o][m][n][2 * r4p + 1] + bias[cob + 2 * r4p + 1]) << 16);
          yp[(size_t)((cob >> 1) + r4p) * S * S + (size_t)(row0 + o) * S + px] = pk;
        }
      }
}

// MFMA deconv4x4 s2 p2 + bias + relu, 2 input rows + both q parities per block.
template <int S>
__global__ __launch_bounds__(256) void k_deconvx3(const unsigned* __restrict__ xp,
                                                  const short* __restrict__ wpk,
                                                  const float* __restrict__ bias,
                                                  unsigned* __restrict__ yp) {
  constexpr int SEG = S;
  constexpr int WPC = (SEG >= 64) ? 2 : 1;
  constexpr int WCO = 4 / WPC;
  constexpr int COS = 64 / WCO;
  constexpr int MR = COS / 16;
  constexpr int PSP = SEG / WPC;
  constexpr int NR = PSP / 16;
  constexpr int CBK = (SEG + 2 + 31) / 32;
  const int SO = 2 * S;
  __shared__ short x_s[3 * (SEG + 2) * PCI];
  __shared__ short w_s[8 * 64 * PCI];
  unsigned* x_s32 = (unsigned*)x_s;
  int t = threadIdx.x;
  int l = t & 63, wv = t >> 6;
  int wcob = (wv % WCO) * COS;
  int wposb = (wv / WCO) * PSP;
  int row0 = blockIdx.x * 2;
  int co0 = blockIdx.y * 64;
  int p = blockIdx.z;
  int colb = t & 31, ci2b = t >> 5;
  f32x4 acc[2][2][MR][NR];  // [q][o][m][n]
#pragma unroll
  for (int q = 0; q < 2; ++q)
#pragma unroll
    for (int o = 0; o < 2; ++o)
#pragma unroll
      for (int m = 0; m < MR; ++m)
#pragma unroll
        for (int n = 0; n < NR; ++n) { f32x4 z = {0.f, 0.f, 0.f, 0.f}; acc[q][o][m][n] = z; }
  for (int c0 = 0; c0 < CCH; c0 += 32) {
    int cb = c0 >> 1;
    __syncthreads();
    // stage x: rows row0+p-1 .. row0+p+1
#pragma unroll
    for (int r = 0; r < 3; ++r) {
      int gy = row0 + p - 1 + r;
      bool yok = (gy >= 0 && gy < S);
#pragma unroll
      for (int cbk = 0; cbk < CBK; ++cbk) {
        int col = colb + cbk * 32;
        if (col < SEG + 2) {
          int gx = col - 1;
          bool ok = yok && (gx >= 0) && (gx < S);
          unsigned v0 = 0, v1 = 0;
          if (ok) {
            size_t gbase = (size_t)(cb + ci2b) * S * S + (size_t)gy * S + gx;
            v0 = xp[gbase];
            v1 = xp[gbase + (size_t)8 * S * S];
          }
          int lb = (r * (SEG + 2) + col) * (PCI / 2);
          x_s32[lb + ci2b] = v0;
          x_s32[lb + ci2b + 8] = v1;
        }
      }
    }
    // stage w: 8 classes (q*4+tt) x 64 co x 32 ci
    for (int i = t; i < 4096; i += 256) {
      int seg8 = i & 7;
      int rowi = i >> 3;
      int c8 = rowi >> 6, co = rowi & 63;
      int qq = c8 >> 2, tt = c8 & 3;
      us4 wv4 = *(const us4*)&wpk[((size_t)(((2 * p + qq) * 4 + tt) * 256 + co0 + co) * 256) + c0 + seg8 * 4];
      *(us4*)&w_s[rowi * PCI + seg8 * 4] = wv4;
    }
    __syncthreads();
#pragma unroll
    for (int dyi = 0; dyi < 2; ++dyi)
#pragma unroll
      for (int o = 0; o < 2; ++o) {
        short8 b[3][NR];
#pragma unroll
        for (int off = 0; off < 3; ++off)
#pragma unroll
          for (int n = 0; n < NR; ++n)
            b[off][n] = *(const short8*)&x_s[((dyi + o) * (SEG + 2) + wposb + n * 16 + (l & 15) + off) * PCI + (l >> 4) * 8];
#pragma unroll
        for (int q = 0; q < 2; ++q)
#pragma unroll
          for (int dxi = 0; dxi < 2; ++dxi) {
            int c8 = q * 4 + dyi * 2 + dxi;
            short8 a[MR];
#pragma unroll
            for (int m = 0; m < MR; ++m)
              a[m] = *(const short8*)&w_s[(c8 * 64 + wcob + m * 16 + (l & 15)) * PCI + (l >> 4) * 8];
#pragma unroll
            for (int m = 0; m < MR; ++m)
#pragma unroll
              for (int n = 0; n < NR; ++n) mfma_bf16(acc[q][o][m][n], a[m], b[dxi + q][n]);
          }
      }
  }
  asm volatile("s_nop 7\n\ts_nop 7" ::);
#pragma unroll
  for (int o = 0; o < 2; ++o) {
    int oy = 2 * (row0 + o) + p;
#pragma unroll
    for (int m = 0; m < MR; ++m)
#pragma unroll
      for (int n = 0; n < NR; ++n) {
        int px = wposb + n * 16 + (l & 15);
#pragma unroll
        for (int r4p = 0; r4p < 2; ++r4p) {
          int cob = co0 + wcob + m * 16 + (l >> 4) * 4 + 2 * r4p;
          float b0 = bias[cob], b1 = bias[cob + 1];
          unsigned pk0 = (unsigned)f2bf(fmaxf(acc[0][o][m][n][2 * r4p] + b0, 0.f))
                       | ((unsigned)f2bf(fmaxf(acc[0][o][m][n][2 * r4p + 1] + b1, 0.f)) << 16);
          unsigned pk1 = (unsigned)f2bf(fmaxf(acc[1][o][m][n][2 * r4p] + b0, 0.f))
                       | ((unsigned)f2bf(fmaxf(acc[1][o][m][n][2 * r4p + 1] + b1, 0.f)) << 16);
          uint2 pk = make_uint2(pk0, pk1);
          *(uint2*)&yp[(size_t)(cob >> 1) * SO * SO + (size_t)oy * SO + 2 * px] = pk;
        }
      }
  }
}

// transpose stage-5 conv weights: w[co][ci*9+e] -> wt[(ci*9+e)][co]
__global__ void k_wt5(const float* __restrict__ w, float* __restrict__ wt) {
  int e9 = blockIdx.x;
  int co = threadIdx.x;
  int ci = e9 / 9, e = e9 % 9;
  wt[(size_t)e9 * 256 + co] = w[((size_t)co * 256 + ci) * 9 + e];
}

// sparse final conv3 at 8 gathered positions per block; packed bf16 input.
__global__ __launch_bounds__(256) void k_conv3sT(const unsigned* __restrict__ xp,
                                                 const float* __restrict__ wt,
                                                 const float* __restrict__ bias,
                                                 const int* __restrict__ idx,
                                                 float* __restrict__ out) {
  __shared__ float sp[8][2304];
  int t = threadIdx.x;
  int j0 = blockIdx.x * 8;
  for (int i = t; i < 8 * 1152; i += 256) {
    int jj = i / 1152, r2 = i % 1152;
    int ci2 = r2 / 9, e = r2 % 9;
    int pI = idx[j0 + jj];
    int py = pI >> 8, px = pI & 255;
    int gy = py - 1 + e / 3, gx = px - 1 + e % 3;
    unsigned v = 0;
    if (gy >= 0 && gy < 256 && gx >= 0 && gx < 256)
      v = xp[(size_t)ci2 * HWP + gy * 256 + gx];
    sp[jj][(2 * ci2) * 9 + e] = bf2f((unsigned short)(v & 0xFFFFu));
    sp[jj][(2 * ci2 + 1) * 9 + e] = bf2f((unsigned short)(v >> 16));
  }
  __syncthreads();
  float bv = bias[t];
  float a[8];
#pragma unroll
  for (int jj = 0; jj < 8; ++jj) a[jj] = bv;
  for (int e4 = 0; e4 < 576; ++e4) {
    float w0 = wt[(size_t)(4 * e4 + 0) * 256 + t];
    float w1 = wt[(size_t)(4 * e4 + 1) * 256 + t];
    float w2 = wt[(size_t)(4 * e4 + 2) * 256 + t];
    float w3 = wt[(size_t)(4 * e4 + 3) * 256 + t];
#pragma unroll
    for (int jj = 0; jj < 8; ++jj) {
      float4 s = ((const float4*)sp[jj])[e4];
      a[jj] += s.x * w0 + s.y * w1 + s.z * w2 + s.w * w3;
    }
  }
#pragma unroll
  for (int jj = 0; jj < 8; ++jj) out[(size_t)(j0 + jj) * 256 + t] = a[jj];
}

// fused: passthrough copy of down into out + gate keys
__global__ void k_gatecopy(const float* __restrict__ down, const float* __restrict__ gw,
                           float* __restrict__ out, unsigned int* __restrict__ keys) {
  int p = blockIdx.x * 256 + threadIdx.x;
  float acc = 0.f;
  for (int c = 0; c < CCH; ++c) {
    float v = down[(size_t)c * HWP + p];
    out[(size_t)c * HWP + p] = v;
    acc += v * gw[c];
  }
  unsigned int u = __float_as_uint(acc);
  keys[p] = (u & 0x80000000u) ? ~u : (u | 0x80000000u);
}

__global__ void k_hist(const unsigned int* __restrict__ keys, unsigned int* hist,
                       const SelState* st, int r) {
  __shared__ unsigned int lh[256];
  int t = threadIdx.x;
  lh[t] = 0;
  __syncthreads();
  unsigned int key = keys[blockIdx.x * 256 + t];
  bool ok = (r == 0) || ((key >> (32 - 8 * r)) == st->P);
  if (ok) atomicAdd(&lh[(key >> (24 - 8 * r)) & 255u], 1u);
  __syncthreads();
  if (lh[t]) atomicAdd(&hist[t], lh[t]);
}

__global__ void k_scan(unsigned int* hist, SelState* st) {
  if (threadIdx.x == 0) {
    int need = st->kneed;
    unsigned int cum = 0;
    for (int b = 255; b >= 0; --b) {
      unsigned int h = hist[b];
      if (cum + h >= (unsigned int)need) {
        st->P = (st->P << 8) | (unsigned int)b;
        st->kneed = need - (int)cum;
        break;
      }
      cum += h;
    }
  }
  __syncthreads();
  hist[threadIdx.x] = 0;
}

__global__ void k_compact(const unsigned int* __restrict__ keys, SelState* st,
                          int* __restrict__ idx, int* __restrict__ eq) {
  int p = blockIdx.x * 256 + threadIdx.x;
  unsigned int key = keys[p];
  unsigned int P = st->P;
  if (key > P) {
    int pos = atomicAdd(&st->nGreater, 1);
    idx[pos] = p;
  } else if (key == P) {
    int e = atomicAdd(&st->nEqual, 1);
    if (e < 4096) eq[e] = p;
  }
}

__global__ void k_finalize(SelState* st, int* idx, int* eq) {
  if (threadIdx.x != 0) return;
  int n = st->nEqual;
  if (n > 4096) n = 4096;
  for (int i = 1; i < n; ++i) {
    int v = eq[i], j = i - 1;
    while (j >= 0 && eq[j] > v) { eq[j + 1] = eq[j]; --j; }
    eq[j + 1] = v;
  }
  int g = st->nGreater;
  for (int i = 0; i < st->kneed; ++i) idx[g + i] = eq[i];
}

__global__ void k_transpose(const float* __restrict__ in, float* __restrict__ out, int rows) {
  int o = blockIdx.x, c = threadIdx.x;
  out[(size_t)c * rows + o] = in[(size_t)o * 256 + c];
}

// gather rows at idx, project to Q,K,V, emit bf16 Qb/Kb[h][q][d] and Vt[h][d][q]
__global__ __launch_bounds__(256) void k_qkv2(const float* __restrict__ down,
                                              const float* __restrict__ srows,
                                              const int* __restrict__ idx,
                                              const float* __restrict__ wT,
                                              const float* __restrict__ bias,
                                              short* __restrict__ Qb,
                                              short* __restrict__ Kb,
                                              short* __restrict__ Vt) {
  __shared__ float xq[4][256], xk[4][256];
  int j0 = blockIdx.x * 4;
  int c = threadIdx.x;
  for (int r = 0; r < 4; ++r) {
    int p = idx[j0 + r];
    xq[r][c] = down[(size_t)c * HWP + p];
    xk[r][c] = srows[(size_t)(j0 + r) * 256 + c];
  }
  __syncthreads();
  float aq[4], ak[4], av[4];
#pragma unroll
  for (int r = 0; r < 4; ++r) {
    aq[r] = bias[c]; ak[r] = bias[256 + c]; av[r] = bias[512 + c];
  }
  for (int i = 0; i < 256; ++i) {
    float wq = wT[i * 768 + c];
    float wk = wT[i * 768 + 256 + c];
    float wv = wT[i * 768 + 512 + c];
#pragma unroll
    for (int r = 0; r < 4; ++r) {
      float xv = xq[r][i], kv = xk[r][i];
      aq[r] += xv * wq;
      ak[r] += kv * wk;
      av[r] += kv * wv;
    }
  }
  int h = c >> 5, d = c & 31;
#pragma unroll
  for (int r = 0; r < 4; ++r) {
    int j = j0 + r;
    Qb[((size_t)h * 2048 + j) * 32 + d] = (short)f2bf(aq[r]);
    Kb[((size_t)h * 2048 + j) * 32 + d] = (short)f2bf(ak[r]);
    Vt[((size_t)h * 32 + d) * 2048 + j] = (short)f2bf(av[r]);
  }
}

// fused flash attention: QK^T -> online softmax -> PV. grid (32 qtiles, 8 h), 4 waves.
// Each wave owns 16 q rows; P staged per-wave in LDS in A-fragment layout.
__global__ __launch_bounds__(256) void k_fattn(const short* __restrict__ Qb,
                                               const short* __restrict__ Kb,
                                               const short* __restrict__ Vt,
                                               float* __restrict__ Oa) {
  __shared__ short P_lds[4][16][136];
  int t = threadIdx.x, l = t & 63, wv = t >> 6;
  int h = blockIdx.y;
  int q0 = blockIdx.x * 64 + wv * 16;
  const short* Qh = Qb + (size_t)h * 2048 * 32;
  const short* Kh = Kb + (size_t)h * 2048 * 32;
  const short* Vh = Vt + (size_t)h * 32 * 2048;
  short8 a_q = *(const short8*)&Qh[(size_t)(q0 + (l & 15)) * 32 + (l >> 4) * 8];
  f32x4 o0 = {0.f, 0.f, 0.f, 0.f}, o1 = {0.f, 0.f, 0.f, 0.f};
  float m_run[4], l_run[4];
#pragma unroll
  for (int r = 0; r < 4; ++r) { m_run[r] = -3e38f; l_run[r] = 0.f; }
  const float scale = 0.17677669529663687f;
  for (int k0 = 0; k0 < 2048; k0 += 128) {
    f32x4 s[8];
#pragma unroll
    for (int kt = 0; kt < 8; ++kt) {
      f32x4 z = {0.f, 0.f, 0.f, 0.f};
      s[kt] = z;
      short8 b = *(const short8*)&Kh[(size_t)(k0 + kt * 16 + (l & 15)) * 32 + (l >> 4) * 8];
      mfma_bf16(s[kt], a_q, b);
    }
    asm volatile("s_nop 7\n\ts_nop 7" ::);
    float tm[4];
#pragma unroll
    for (int r = 0; r < 4; ++r) {
      float mx = s[0][r];
#pragma unroll
      for (int kt = 1; kt < 8; ++kt) mx = fmaxf(mx, s[kt][r]);
      tm[r] = mx * scale;
    }
#pragma unroll
    for (int mask = 1; mask < 16; mask <<= 1)
#pragma unroll
      for (int r = 0; r < 4; ++r) tm[r] = fmaxf(tm[r], __shfl_xor(tm[r], mask));
    float mn[4], al[4], rs[4];
#pragma unroll
    for (int r = 0; r < 4; ++r) {
      mn[r] = fmaxf(m_run[r], tm[r]);
      al[r] = __expf(m_run[r] - mn[r]);
      rs[r] = 0.f;
    }
#pragma unroll
    for (int kt = 0; kt < 8; ++kt)
#pragma unroll
      for (int r = 0; r < 4; ++r) {
        float pv = __expf(s[kt][r] * scale - mn[r]);
        s[kt][r] = pv;
        rs[r] += pv;
      }
#pragma unroll
    for (int mask = 1; mask < 16; mask <<= 1)
#pragma unroll
      for (int r = 0; r < 4; ++r) rs[r] += __shfl_xor(rs[r], mask);
#pragma unroll
    for (int r = 0; r < 4; ++r) {
      l_run[r] = l_run[r] * al[r] + rs[r];
      m_run[r] = mn[r];
      o0[r] *= al[r];
      o1[r] *= al[r];
    }
    // P to LDS (A-fragment layout: row q-local, col k-local)
#pragma unroll
    for (int kt = 0; kt < 8; ++kt)
#pragma unroll
      for (int r = 0; r < 4; ++r)
        P_lds[wv][(l >> 4) * 4 + r][kt * 16 + (l & 15)] = (short)f2bf(s[kt][r]);
#pragma unroll
    for (int kc = 0; kc < 4; ++kc) {
      short8 ap = *(const short8*)&P_lds[wv][l & 15][kc * 32 + (l >> 4) * 8];
      short8 b0 = *(const short8*)&Vh[(size_t)(l & 15) * 2048 + k0 + kc * 32 + (l >> 4) * 8];
      short8 b1 = *(const short8*)&Vh[(size_t)(16 + (l & 15)) * 2048 + k0 + kc * 32 + (l >> 4) * 8];
      mfma_bf16(o0, ap, b0);
      mfma_bf16(o1, ap, b1);
    }
  }
  asm volatile("s_nop 7\n\ts_nop 7" ::);
#pragma unroll
  for (int r = 0; r < 4; ++r) {
    float inv = 1.f / l_run[r];
    int qr = q0 + (l >> 4) * 4 + r;
    Oa[(size_t)qr * 256 + h * 32 + (l & 15)] = o0[r] * inv;
    Oa[(size_t)qr * 256 + h * 32 + 16 + (l & 15)] = o1[r] * inv;
  }
}

// out-projection (8 rows/block) fused with scatter into final output columns
__global__ __launch_bounds__(256) void k_outproj8(const float* __restrict__ Oa,
                                                  const float* __restrict__ owT,
                                                  const float* __restrict__ ob,
                                                  const int* __restrict__ idx,
                                                  float* __restrict__ out) {
  __shared__ float xo[8][256];
  int j0 = blockIdx.x * 8;
  int c = threadIdx.x;
  for (int r = 0; r < 8; ++r) xo[r][c] = Oa[(size_t)(j0 + r) * 256 + c];
  __syncthreads();
  float a[8];
#pragma unroll
  for (int r = 0; r < 8; ++r) a[r] = ob[c];
  for (int i = 0; i < 256; ++i) {
    float wv = owT[i * 256 + c];
#pragma unroll
    for (int r = 0; r < 8; ++r) a[r] += xo[r][i] * wv;
  }
#pragma unroll
  for (int r = 0; r < 8; ++r) out[(size_t)c * HWP + idx[j0 + r]] = a[r];
}

extern "C" void kernel_launch(void* const* d_in, const int* in_sizes, int n_in,
                              void* d_out, int out_size, void* d_ws, size_t ws_size,
                              hipStream_t stream) {
  const float* down  = (const float*)d_in[0];
  const float* swint = (const float*)d_in[1];
  const float* wt_w  = (const float*)d_in[2];
  const float* wt_b  = (const float*)d_in[3];
  const float* up_dw = (const float*)d_in[4];
  const float* up_db = (const float*)d_in[5];
  const float* up_cw = (const float*)d_in[6];
  const float* up_cb = (const float*)d_in[7];
  const float* gate_w = (const float*)d_in[8];
  const float* in_w  = (const float*)d_in[10];
  const float* in_b  = (const float*)d_in[11];
  const float* out_w = (const float*)d_in[12];
  const float* out_b = (const float*)d_in[13];
  float* out = (float*)d_out;
  char* ws = (char*)d_ws;

  float* bufA = (float*)ws;
  unsigned* actA = (unsigned*)ws;
  unsigned* actB = (unsigned*)(ws + BUF_B_OFF);
  unsigned int* keys = (unsigned int*)(ws + KEYS_OFF);
  unsigned int* hist = (unsigned int*)(ws + HIST_OFF);
  SelState* st = (SelState*)(ws + STATE_OFF);
  int* idx = (int*)(ws + IDX_OFF);
  int* eq = (int*)(ws + EQ_OFF);
  float* Oa = (float*)(ws + OA_OFF);
  float* wTi = (float*)(ws + WTI_OFF);
  float* wTo = (float*)(ws + WTO_OFF);
  float* srows = (float*)(ws + SROWS_OFF);
  float* wt5 = (float*)(ws + WT5_OFF);
  short* Qb = (short*)(ws + QB_OFF);
  short* Kb = (short*)(ws + KB_OFF);
  short* Vt = (short*)(ws + VT_OFF);
  short* cpk = (short*)(ws + CPK_OFF);
  short* dpk = (short*)(ws + DPK_OFF);

  k_init<<<1, 256, 0, stream>>>(hist, st);

  // fused gate + passthrough copy, then exact top-k (radix select)
  k_gatecopy<<<256, 256, 0, stream>>>(down, gate_w, out, keys);
  for (int r = 0; r < 4; ++r) {
    k_hist<<<256, 256, 0, stream>>>(keys, hist, st, r);
    k_scan<<<1, 256, 0, stream>>>(hist, st);
  }
  k_compact<<<256, 256, 0, stream>>>(keys, st, idx, eq);
  k_finalize<<<1, 64, 0, stream>>>(st, idx, eq);

  // weight packs (batched over layers)
  k_packc3<<<dim3(256, 4), 256, 0, stream>>>(up_cw, cpk);
  k_packdc<<<dim3(256, 4), 256, 0, stream>>>(up_dw, dpk);

  // upsampler chain: MFMA bf16 implicit-GEMM, packed-bf16 activations (A/B ping-pong)
  k_wtconv<<<256, 64, 0, stream>>>(swint, wt_w, wt_b, bufA);
  k_deconv<8><<<dim3(1, 256), 256, 0, stream>>>(bufA, up_dw, up_db, (unsigned short*)actB);
  k_conv3x2<16><<<dim3(8, 4), 256, 0, stream>>>(actB, cpk, up_cb, actA);
  k_deconvx3<16><<<dim3(8, 4, 2), 256, 0, stream>>>(actA, dpk, up_db + 256, actB);
  k_conv3x2<32><<<dim3(16, 4), 256, 0, stream>>>(actB, cpk + 589824, up_cb + 256, actA);
  k_deconvx3<32><<<dim3(16, 4, 2), 256, 0, stream>>>(actA, dpk + 1048576, up_db + 512, actB);
  k_conv3x2<64><<<dim3(32, 4), 256, 0, stream>>>(actB, cpk + 2 * 589824, up_cb + 512, actA);
  k_deconvx3<64><<<dim3(32, 4, 2), 256, 0, stream>>>(actA, dpk + 2 * 1048576, up_db + 768, actB);
  k_conv3x2<128><<<dim3(64, 4), 256, 0, stream>>>(actB, cpk + 3 * 589824, up_cb + 768, actA);
  k_deconvx3<128><<<dim3(64, 4, 2), 256, 0, stream>>>(actA, dpk + 3 * 1048576, up_db + 1024, actB);

  // transposed weights
  k_wt5<<<2304, 256, 0, stream>>>(up_cw + 2359296, wt5);
  k_transpose<<<768, 256, 0, stream>>>(in_w, wTi, 768);
  k_transpose<<<256, 256, 0, stream>>>(out_w, wTo, 256);

  // final conv3 only at the 2048 gathered positions (reads packed actB)
  k_conv3sT<<<256, 256, 0, stream>>>(actB, wt5, up_cb + 1024, idx, srows);

  // attention path: bf16 QKV, fused flash attention, out-projection
  k_qkv2<<<512, 256, 0, stream>>>(down, srows, idx, wTi, in_b, Qb, Kb, Vt);
  k_fattn<<<dim3(32, 8), 256, 0, stream>>>(Qb, Kb, Vt, Oa);
  k_outproj8<<<256, 256, 0, stream>>>(Oa, wTo, out_b, idx, out);
}

// Round 8
// 823.242 us; speedup vs baseline: 21.2929x; 1.0948x over previous
//
#include <hip/hip_runtime.h>
#include <math.h>

#define CCH 256
#define HWP 65536
#define PCI 40   // padded ci stride (shorts) in LDS

typedef short short8 __attribute__((ext_vector_type(8)));
typedef float f32x4 __attribute__((ext_vector_type(4)));
typedef unsigned short us4 __attribute__((ext_vector_type(4)));

__device__ inline unsigned short f2bf(float f) {
  unsigned u = __float_as_uint(f);
  return (unsigned short)((u + 0x7FFFu + ((u >> 16) & 1u)) >> 16);
}
__device__ inline float bf2f(unsigned short s) {
  return __uint_as_float(((unsigned)s) << 16);
}

__device__ inline void mfma_bf16(f32x4& d, short8 a, short8 b) {
  asm volatile("v_mfma_f32_16x16x32_bf16 %0, %1, %2, %0" : "+v"(d) : "v"(a), "v"(b));
}

// ---- ws layout (bytes) ----
static const size_t BUF_B_OFF = 67108864;        // bufA @0 (64MB), bufB @64MB
static const size_t TAIL_OFF  = 134217728;
static const size_t KEYS_OFF  = TAIL_OFF;
static const size_t HIST_OFF  = TAIL_OFF + 262144;
static const size_t STATE_OFF = TAIL_OFF + 263168;
static const size_t IDX_OFF   = TAIL_OFF + 263424;
static const size_t EQ_OFF    = TAIL_OFF + 271616;
// overlaid into bufA region (packed conv activations there stay <= 8.4MB):
static const size_t OA_OFF    = 6291456;
static const size_t WTI_OFF   = 8388608;
static const size_t WTO_OFF   = 9437184;
static const size_t SROWS_OFF = 10485760;
static const size_t WT5_OFF   = 20971520;        // bf16 wB[256][2304] 1.18MB
static const size_t QB_OFF    = 31457280;
static const size_t KB_OFF    = 32505856;
static const size_t VT_OFF    = 33554432;
static const size_t CPK_OFF   = 37748736;
static const size_t DPK_OFF   = 44040192;

struct SelState { unsigned int P; int kneed; int nGreater; int nEqual; };

__global__ void k_init(unsigned int* hist, SelState* st) {
  int t = threadIdx.x;
  hist[t] = 0;
  if (t == 0) { st->P = 0u; st->kneed = 2048; st->nGreater = 0; st->nEqual = 0; }
}

// 1x1 conv 768->256 on 8x8
__global__ void k_wtconv(const float* __restrict__ swint, const float* __restrict__ w,
                         const float* __restrict__ b, float* __restrict__ out) {
  int co = blockIdx.x, p = threadIdx.x;
  float acc = b[co];
  for (int ci = 0; ci < 768; ++ci) acc += swint[ci * 64 + p] * w[co * 768 + ci];
  out[co * 64 + p] = acc;
}

// deconv 4x4 stride2 pad2 + bias + relu, f32 in (S=8), packed-bf16 out
template <int S>
__global__ __launch_bounds__(256) void k_deconv(const float* __restrict__ x,
                                                const float* __restrict__ w,
                                                const float* __restrict__ bias,
                                                unsigned short* __restrict__ yp) {
  const int SO = 2 * S;
  const int TX = SO / 16;
  int co = blockIdx.y;
  int tile = blockIdx.x;
  int ty0 = (tile / TX) * 16, tx0 = (tile % TX) * 16;
  int t = threadIdx.x;
  int ly = t >> 4, lx = t & 15;
  int oy = ty0 + ly, ox = tx0 + lx;
  int iyb = (ty0 >> 1) - 1, ixb = (tx0 >> 1) - 1;
  int p = oy & 1, q = ox & 1;
  int iyA = ((oy + p - 2) >> 1) - iyb;
  int ixA = ((ox + q - 2) >> 1) - ixb;
  int i00 = (3 - p) * 4 + (3 - q);
  int i01 = (3 - p) * 4 + (1 - q);
  int i10 = (1 - p) * 4 + (3 - q);
  int i11 = (1 - p) * 4 + (1 - q);
  __shared__ float lx_s[8][10][10];
  __shared__ float lw_s[8][16];
  float acc = bias[co];
  for (int c0 = 0; c0 < CCH; c0 += 8) {
    __syncthreads();
    for (int i = t; i < 800; i += 256) {
      int u = i / 100, rem = i % 100;
      int r = rem / 10, c = rem % 10;
      int gy = iyb + r, gx = ixb + c;
      float v = 0.f;
      if (gy >= 0 && gy < S && gx >= 0 && gx < S)
        v = x[(size_t)(c0 + u) * S * S + gy * S + gx];
      lx_s[u][r][c] = v;
    }
    if (t < 128) {
      int u = t >> 4, e = t & 15;
      lw_s[u][e] = w[(size_t)(c0 + u) * 4096 + co * 16 + e];
    }
    __syncthreads();
#pragma unroll
    for (int u = 0; u < 8; ++u) {
      acc += lx_s[u][iyA][ixA]     * lw_s[u][i00]
           + lx_s[u][iyA][ixA + 1] * lw_s[u][i01]
           + lx_s[u][iyA + 1][ixA]     * lw_s[u][i10]
           + lx_s[u][iyA + 1][ixA + 1] * lw_s[u][i11];
    }
  }
  acc = fmaxf(acc, 0.f);
  yp[((size_t)(co >> 1) * SO * SO + (size_t)oy * SO + ox) * 2 + (co & 1)] = f2bf(acc);
}

// pack conv3 weights (4 layers): [co][ci][9] f32 -> bf16 [tap][co][ci]
__global__ void k_packc3(const float* __restrict__ w, short* __restrict__ wpk) {
  int layer = blockIdx.y;
  const float* wl = w + (size_t)layer * 589824;
  short* wo = wpk + (size_t)layer * 589824;
  int co = blockIdx.x, ci = threadIdx.x;
  for (int tap = 0; tap < 9; ++tap)
    wo[((size_t)(tap * 256 + co) * 256) + ci] = (short)f2bf(wl[((size_t)(co * 256 + ci)) * 9 + tap]);
}

// pack deconv weights (layers 1..4): [ci][co][4][4] f32 -> bf16 [pq][tt][co][ci]
__global__ void k_packdc(const float* __restrict__ w, short* __restrict__ wpk) {
  int layer = blockIdx.y;
  const float* wl = w + (size_t)(layer + 1) * 1048576;
  int co = blockIdx.x, ci = threadIdx.x;
  for (int pq = 0; pq < 4; ++pq) {
    int p = pq >> 1, q = pq & 1;
    for (int tt = 0; tt < 4; ++tt) {
      int dyi = tt >> 1, dxi = tt & 1;
      int wr = dyi ? (1 - p) : (3 - p);
      int wc = dxi ? (1 - q) : (3 - q);
      wpk[((size_t)layer * 1048576) + ((size_t)((pq * 4 + tt) * 256 + co) * 256) + ci] =
          (short)f2bf(wl[((size_t)(ci * 256 + co)) * 16 + wr * 4 + wc]);
    }
  }
}

// pack stage-5 conv weights: wB[co][c*288 + e*32 + cl] = w[co][(c*32+cl)*9 + e], bf16
__global__ void k_packc5(const float* __restrict__ w, short* __restrict__ wB) {
  int co = blockIdx.x;
  for (int kk = threadIdx.x; kk < 2304; kk += 256) {
    int c = kk / 288, r = kk % 288;
    int e = r >> 5, cl = r & 31;
    wB[(size_t)co * 2304 + kk] = (short)f2bf(w[(size_t)co * 2304 + (size_t)(c * 32 + cl) * 9 + e]);
  }
}

// MFMA conv3x3 pad1 + bias, 2 output rows per block. Packed bf16 in/out.
template <int S>
__global__ __launch_bounds__(256) void k_conv3x2(const unsigned* __restrict__ xp,
                                                 const short* __restrict__ wpk,
                                                 const float* __restrict__ bias,
                                                 unsigned* __restrict__ yp) {
  constexpr int SEG = S;
  constexpr int WPC = (SEG >= 64) ? 2 : 1;
  constexpr int WCO = 4 / WPC;
  constexpr int COS = 64 / WCO;
  constexpr int MR = COS / 16;
  constexpr int PSP = SEG / WPC;
  constexpr int NR = PSP / 16;
  constexpr int CBK = (SEG + 2 + 31) / 32;
  __shared__ short x_s[4 * (SEG + 2) * PCI];
  __shared__ short w_s[3 * 64 * PCI];
  unsigned* x_s32 = (unsigned*)x_s;
  int t = threadIdx.x;
  int l = t & 63, wv = t >> 6;
  int wcob = (wv % WCO) * COS;
  int wposb = (wv / WCO) * PSP;
  int row0 = blockIdx.x * 2;
  int co0 = blockIdx.y * 64;
  int colb = t & 31, ci2b = t >> 5;
  f32x4 acc[2][MR][NR];
#pragma unroll
  for (int o = 0; o < 2; ++o)
#pragma unroll
    for (int m = 0; m < MR; ++m)
#pragma unroll
      for (int n = 0; n < NR; ++n) { f32x4 z = {0.f, 0.f, 0.f, 0.f}; acc[o][m][n] = z; }
  for (int c0 = 0; c0 < CCH; c0 += 32) {
    int cb = c0 >> 1;
    __syncthreads();
#pragma unroll
    for (int r = 0; r < 4; ++r) {
      int gy = row0 - 1 + r;
      bool yok = (gy >= 0 && gy < S);
#pragma unroll
      for (int cbk = 0; cbk < CBK; ++cbk) {
        int col = colb + cbk * 32;
        if (col < SEG + 2) {
          int gx = col - 1;
          bool ok = yok && (gx >= 0) && (gx < S);
          unsigned v0 = 0, v1 = 0;
          if (ok) {
            size_t gbase = (size_t)(cb + ci2b) * S * S + (size_t)gy * S + gx;
            v0 = xp[gbase];
            v1 = xp[gbase + (size_t)8 * S * S];
          }
          int lb = (r * (SEG + 2) + col) * (PCI / 2);
          x_s32[lb + ci2b] = v0;
          x_s32[lb + ci2b + 8] = v1;
        }
      }
    }
    for (int dyg = 0; dyg < 3; ++dyg) {
      if (dyg) __syncthreads();
      for (int i = t; i < 1536; i += 256) {
        int ci4 = i & 7;
        int tc = i >> 3;
        int dx = tc >> 6, co = tc & 63;
        us4 wv4 = *(const us4*)&wpk[((size_t)((dyg * 3 + dx) * 256 + co0 + co) * 256) + c0 + ci4 * 4];
        *(us4*)&w_s[tc * PCI + ci4 * 4] = wv4;
      }
      __syncthreads();
#pragma unroll
      for (int o = 0; o < 2; ++o)
#pragma unroll
        for (int dx = 0; dx < 3; ++dx) {
          short8 a[MR], b[NR];
#pragma unroll
          for (int m = 0; m < MR; ++m)
            a[m] = *(const short8*)&w_s[(dx * 64 + wcob + m * 16 + (l & 15)) * PCI + (l >> 4) * 8];
#pragma unroll
          for (int n = 0; n < NR; ++n)
            b[n] = *(const short8*)&x_s[((dyg + o) * (SEG + 2) + wposb + n * 16 + (l & 15) + dx) * PCI + (l >> 4) * 8];
#pragma unroll
          for (int m = 0; m < MR; ++m)
#pragma unroll
            for (int n = 0; n < NR; ++n) mfma_bf16(acc[o][m][n], a[m], b[n]);
        }
    }
  }
  asm volatile("s_nop 7\n\ts_nop 7" ::);
#pragma unroll
  for (int o = 0; o < 2; ++o)
#pragma unroll
    for (int m = 0; m < MR; ++m)
#pragma unroll
      for (int n = 0; n < NR; ++n) {
        int cob = co0 + wcob + m * 16 + (l >> 4) * 4;
        int px = wposb + n * 16 + (l & 15);
#pragma unroll
        for (int r4p = 0; r4p < 2; ++r4p) {
          unsigned pk = (unsigned)f2bf(acc[o][m][n][2 * r4p] + bias[cob + 2 * r4p])
                      | ((unsigned)f2bf(acc[o][m][n][2 * r4p + 1] + bias[cob + 2 * r4p + 1]) << 16);
          yp[(size_t)((cob >> 1) + r4p) * S * S + (size_t)(row0 + o) * S + px] = pk;
        }
      }
}

// MFMA deconv4x4 s2 p2 + bias + relu, 2 input rows + both q parities per block.
template <int S>
__global__ __launch_bounds__(256) void k_deconvx3(const unsigned* __restrict__ xp,
                                                  const short* __restrict__ wpk,
                                                  const float* __restrict__ bias,
                                                  unsigned* __restrict__ yp) {
  constexpr int SEG = S;
  constexpr int WPC = (SEG >= 64) ? 2 : 1;
  constexpr int WCO = 4 / WPC;
  constexpr int COS = 64 / WCO;
  constexpr int MR = COS / 16;
  constexpr int PSP = SEG / WPC;
  constexpr int NR = PSP / 16;
  constexpr int CBK = (SEG + 2 + 31) / 32;
  const int SO = 2 * S;
  __shared__ short x_s[3 * (SEG + 2) * PCI];
  __shared__ short w_s[8 * 64 * PCI];
  unsigned* x_s32 = (unsigned*)x_s;
  int t = threadIdx.x;
  int l = t & 63, wv = t >> 6;
  int wcob = (wv % WCO) * COS;
  int wposb = (wv / WCO) * PSP;
  int row0 = blockIdx.x * 2;
  int co0 = blockIdx.y * 64;
  int p = blockIdx.z;
  int colb = t & 31, ci2b = t >> 5;
  f32x4 acc[2][2][MR][NR];  // [q][o][m][n]
#pragma unroll
  for (int q = 0; q < 2; ++q)
#pragma unroll
    for (int o = 0; o < 2; ++o)
#pragma unroll
      for (int m = 0; m < MR; ++m)
#pragma unroll
        for (int n = 0; n < NR; ++n) { f32x4 z = {0.f, 0.f, 0.f, 0.f}; acc[q][o][m][n] = z; }
  for (int c0 = 0; c0 < CCH; c0 += 32) {
    int cb = c0 >> 1;
    __syncthreads();
#pragma unroll
    for (int r = 0; r < 3; ++r) {
      int gy = row0 + p - 1 + r;
      bool yok = (gy >= 0 && gy < S);
#pragma unroll
      for (int cbk = 0; cbk < CBK; ++cbk) {
        int col = colb + cbk * 32;
        if (col < SEG + 2) {
          int gx = col - 1;
          bool ok = yok && (gx >= 0) && (gx < S);
          unsigned v0 = 0, v1 = 0;
          if (ok) {
            size_t gbase = (size_t)(cb + ci2b) * S * S + (size_t)gy * S + gx;
            v0 = xp[gbase];
            v1 = xp[gbase + (size_t)8 * S * S];
          }
          int lb = (r * (SEG + 2) + col) * (PCI / 2);
          x_s32[lb + ci2b] = v0;
          x_s32[lb + ci2b + 8] = v1;
        }
      }
    }
    for (int i = t; i < 4096; i += 256) {
      int seg8 = i & 7;
      int rowi = i >> 3;
      int c8 = rowi >> 6, co = rowi & 63;
      int qq = c8 >> 2, tt = c8 & 3;
      us4 wv4 = *(const us4*)&wpk[((size_t)(((2 * p + qq) * 4 + tt) * 256 + co0 + co) * 256) + c0 + seg8 * 4];
      *(us4*)&w_s[rowi * PCI + seg8 * 4] = wv4;
    }
    __syncthreads();
#pragma unroll
    for (int dyi = 0; dyi < 2; ++dyi)
#pragma unroll
      for (int o = 0; o < 2; ++o) {
        short8 b[3][NR];
#pragma unroll
        for (int off = 0; off < 3; ++off)
#pragma unroll
          for (int n = 0; n < NR; ++n)
            b[off][n] = *(const short8*)&x_s[((dyi + o) * (SEG + 2) + wposb + n * 16 + (l & 15) + off) * PCI + (l >> 4) * 8];
#pragma unroll
        for (int q = 0; q < 2; ++q)
#pragma unroll
          for (int dxi = 0; dxi < 2; ++dxi) {
            int c8 = q * 4 + dyi * 2 + dxi;
            short8 a[MR];
#pragma unroll
            for (int m = 0; m < MR; ++m)
              a[m] = *(const short8*)&w_s[(c8 * 64 + wcob + m * 16 + (l & 15)) * PCI + (l >> 4) * 8];
#pragma unroll
            for (int m = 0; m < MR; ++m)
#pragma unroll
              for (int n = 0; n < NR; ++n) mfma_bf16(acc[q][o][m][n], a[m], b[dxi + q][n]);
          }
      }
  }
  asm volatile("s_nop 7\n\ts_nop 7" ::);
#pragma unroll
  for (int o = 0; o < 2; ++o) {
    int oy = 2 * (row0 + o) + p;
#pragma unroll
    for (int m = 0; m < MR; ++m)
#pragma unroll
      for (int n = 0; n < NR; ++n) {
        int px = wposb + n * 16 + (l & 15);
#pragma unroll
        for (int r4p = 0; r4p < 2; ++r4p) {
          int cob = co0 + wcob + m * 16 + (l >> 4) * 4 + 2 * r4p;
          float b0 = bias[cob], b1 = bias[cob + 1];
          unsigned pk0 = (unsigned)f2bf(fmaxf(acc[0][o][m][n][2 * r4p] + b0, 0.f))
                       | ((unsigned)f2bf(fmaxf(acc[0][o][m][n][2 * r4p + 1] + b1, 0.f)) << 16);
          unsigned pk1 = (unsigned)f2bf(fmaxf(acc[1][o][m][n][2 * r4p] + b0, 0.f))
                       | ((unsigned)f2bf(fmaxf(acc[1][o][m][n][2 * r4p + 1] + b1, 0.f)) << 16);
          uint2 pk = make_uint2(pk0, pk1);
          *(uint2*)&yp[(size_t)(cob >> 1) * SO * SO + (size_t)oy * SO + 2 * px] = pk;
        }
      }
  }
}

// sparse final conv3 via MFMA. out[j][co] = sum_k A[j][k]*wB[co][k] + bias[co].
// k-order: (ci_chunk c)*288 + tap e*32 + ci_local. grid (128 j-tiles, 2 co-halves), 4 waves.
__global__ __launch_bounds__(256) void k_conv3sM(const unsigned* __restrict__ xp,
                                                 const short* __restrict__ wB,
                                                 const float* __restrict__ bias,
                                                 const int* __restrict__ idx,
                                                 float* __restrict__ out) {
  __shared__ short a_s[16][296];
  __shared__ int py_s[16], px_s[16];
  int t = threadIdx.x, l = t & 63, wv = t >> 6;
  int j0 = blockIdx.x * 16;
  int co0 = blockIdx.y * 128 + wv * 32;
  if (t < 16) {
    int p = idx[j0 + t];
    py_s[t] = p >> 8;
    px_s[t] = p & 255;
  }
  f32x4 acc[2];
  { f32x4 z = {0.f, 0.f, 0.f, 0.f}; acc[0] = z; acc[1] = z; }
  for (int c = 0; c < 8; ++c) {
    __syncthreads();
    for (int i = t; i < 2304; i += 256) {
      int ci2 = i & 15;
      int je = i >> 4;           // 0..143
      int j = je / 9, e = je % 9;
      int gy = py_s[j] - 1 + e / 3, gx = px_s[j] - 1 + e % 3;
      unsigned v = 0;
      if (gy >= 0 && gy < 256 && gx >= 0 && gx < 256)
        v = xp[(size_t)(c * 16 + ci2) * HWP + gy * 256 + gx];
      *(unsigned*)&a_s[j][e * 32 + 2 * ci2] = v;
    }
    __syncthreads();
#pragma unroll
    for (int s = 0; s < 9; ++s) {
      short8 a = *(const short8*)&a_s[l & 15][s * 32 + (l >> 4) * 8];
      int kg = c * 288 + s * 32 + (l >> 4) * 8;
      short8 b0 = *(const short8*)&wB[(size_t)(co0 + (l & 15)) * 2304 + kg];
      short8 b1 = *(const short8*)&wB[(size_t)(co0 + 16 + (l & 15)) * 2304 + kg];
      mfma_bf16(acc[0], a, b0);
      mfma_bf16(acc[1], a, b1);
    }
  }
  asm volatile("s_nop 7\n\ts_nop 7" ::);
#pragma unroll
  for (int n = 0; n < 2; ++n)
#pragma unroll
    for (int r = 0; r < 4; ++r) {
      int j = j0 + (l >> 4) * 4 + r;
      int co = co0 + n * 16 + (l & 15);
      out[(size_t)j * 256 + co] = acc[n][r] + bias[co];
    }
}

// fused: passthrough copy of down into out + gate keys
__global__ void k_gatecopy(const float* __restrict__ down, const float* __restrict__ gw,
                           float* __restrict__ out, unsigned int* __restrict__ keys) {
  int p = blockIdx.x * 256 + threadIdx.x;
  float acc = 0.f;
  for (int c = 0; c < CCH; ++c) {
    float v = down[(size_t)c * HWP + p];
    out[(size_t)c * HWP + p] = v;
    acc += v * gw[c];
  }
  unsigned int u = __float_as_uint(acc);
  keys[p] = (u & 0x80000000u) ? ~u : (u | 0x80000000u);
}

__global__ void k_hist(const unsigned int* __restrict__ keys, unsigned int* hist,
                       const SelState* st, int r) {
  __shared__ unsigned int lh[256];
  int t = threadIdx.x;
  lh[t] = 0;
  __syncthreads();
  unsigned int key = keys[blockIdx.x * 256 + t];
  bool ok = (r == 0) || ((key >> (32 - 8 * r)) == st->P);
  if (ok) atomicAdd(&lh[(key >> (24 - 8 * r)) & 255u], 1u);
  __syncthreads();
  if (lh[t]) atomicAdd(&hist[t], lh[t]);
}

__global__ void k_scan(unsigned int* hist, SelState* st) {
  if (threadIdx.x == 0) {
    int need = st->kneed;
    unsigned int cum = 0;
    for (int b = 255; b >= 0; --b) {
      unsigned int h = hist[b];
      if (cum + h >= (unsigned int)need) {
        st->P = (st->P << 8) | (unsigned int)b;
        st->kneed = need - (int)cum;
        break;
      }
      cum += h;
    }
  }
  __syncthreads();
  hist[threadIdx.x] = 0;
}

__global__ void k_compact(const unsigned int* __restrict__ keys, SelState* st,
                          int* __restrict__ idx, int* __restrict__ eq) {
  int p = blockIdx.x * 256 + threadIdx.x;
  unsigned int key = keys[p];
  unsigned int P = st->P;
  if (key > P) {
    int pos = atomicAdd(&st->nGreater, 1);
    idx[pos] = p;
  } else if (key == P) {
    int e = atomicAdd(&st->nEqual, 1);
    if (e < 4096) eq[e] = p;
  }
}

__global__ void k_finalize(SelState* st, int* idx, int* eq) {
  if (threadIdx.x != 0) return;
  int n = st->nEqual;
  if (n > 4096) n = 4096;
  for (int i = 1; i < n; ++i) {
    int v = eq[i], j = i - 1;
    while (j >= 0 && eq[j] > v) { eq[j + 1] = eq[j]; --j; }
    eq[j + 1] = v;
  }
  int g = st->nGreater;
  for (int i = 0; i < st->kneed; ++i) idx[g + i] = eq[i];
}

__global__ void k_transpose(const float* __restrict__ in, float* __restrict__ out, int rows) {
  int o = blockIdx.x, c = threadIdx.x;
  out[(size_t)c * rows + o] = in[(size_t)o * 256 + c];
}

// gather rows at idx, project to Q,K,V, emit bf16 Qb/Kb[h][q][d] and Vt[h][d][q]
__global__ __launch_bounds__(256) void k_qkv2(const float* __restrict__ down,
                                              const float* __restrict__ srows,
                                              const int* __restrict__ idx,
                                              const float* __restrict__ wT,
                                              const float* __restrict__ bias,
                                              short* __restrict__ Qb,
                                              short* __restrict__ Kb,
                                              short* __restrict__ Vt) {
  __shared__ float xq[4][256], xk[4][256];
  int j0 = blockIdx.x * 4;
  int c = threadIdx.x;
  for (int r = 0; r < 4; ++r) {
    int p = idx[j0 + r];
    xq[r][c] = down[(size_t)c * HWP + p];
    xk[r][c] = srows[(size_t)(j0 + r) * 256 + c];
  }
  __syncthreads();
  float aq[4], ak[4], av[4];
#pragma unroll
  for (int r = 0; r < 4; ++r) {
    aq[r] = bias[c]; ak[r] = bias[256 + c]; av[r] = bias[512 + c];
  }
  for (int i = 0; i < 256; ++i) {
    float wq = wT[i * 768 + c];
    float wk = wT[i * 768 + 256 + c];
    float wv = wT[i * 768 + 512 + c];
#pragma unroll
    for (int r = 0; r < 4; ++r) {
      float xv = xq[r][i], kv = xk[r][i];
      aq[r] += xv * wq;
      ak[r] += kv * wk;
      av[r] += kv * wv;
    }
  }
  int h = c >> 5, d = c & 31;
#pragma unroll
  for (int r = 0; r < 4; ++r) {
    int j = j0 + r;
    Qb[((size_t)h * 2048 + j) * 32 + d] = (short)f2bf(aq[r]);
    Kb[((size_t)h * 2048 + j) * 32 + d] = (short)f2bf(ak[r]);
    Vt[((size_t)h * 32 + d) * 2048 + j] = (short)f2bf(av[r]);
  }
}

// fused flash attention: QK^T -> online softmax -> PV. grid (32 qtiles, 8 h), 4 waves.
__global__ __launch_bounds__(256) void k_fattn(const short* __restrict__ Qb,
                                               const short* __restrict__ Kb,
                                               const short* __restrict__ Vt,
                                               float* __restrict__ Oa) {
  __shared__ short P_lds[4][16][136];
  int t = threadIdx.x, l = t & 63, wv = t >> 6;
  int h = blockIdx.y;
  int q0 = blockIdx.x * 64 + wv * 16;
  const short* Qh = Qb + (size_t)h * 2048 * 32;
  const short* Kh = Kb + (size_t)h * 2048 * 32;
  const short* Vh = Vt + (size_t)h * 32 * 2048;
  short8 a_q = *(const short8*)&Qh[(size_t)(q0 + (l & 15)) * 32 + (l >> 4) * 8];
  f32x4 o0 = {0.f, 0.f, 0.f, 0.f}, o1 = {0.f, 0.f, 0.f, 0.f};
  float m_run[4], l_run[4];
#pragma unroll
  for (int r = 0; r < 4; ++r) { m_run[r] = -3e38f; l_run[r] = 0.f; }
  const float scale = 0.17677669529663687f;
  for (int k0 = 0; k0 < 2048; k0 += 128) {
    f32x4 s[8];
#pragma unroll
    for (int kt = 0; kt < 8; ++kt) {
      f32x4 z = {0.f, 0.f, 0.f, 0.f};
      s[kt] = z;
      short8 b = *(const short8*)&Kh[(size_t)(k0 + kt * 16 + (l & 15)) * 32 + (l >> 4) * 8];
      mfma_bf16(s[kt], a_q, b);
    }
    asm volatile("s_nop 7\n\ts_nop 7" ::);
    float tm[4];
#pragma unroll
    for (int r = 0; r < 4; ++r) {
      float mx = s[0][r];
#pragma unroll
      for (int kt = 1; kt < 8; ++kt) mx = fmaxf(mx, s[kt][r]);
      tm[r] = mx * scale;
    }
#pragma unroll
    for (int mask = 1; mask < 16; mask <<= 1)
#pragma unroll
      for (int r = 0; r < 4; ++r) tm[r] = fmaxf(tm[r], __shfl_xor(tm[r], mask));
    float mn[4], al[4], rs[4];
#pragma unroll
    for (int r = 0; r < 4; ++r) {
      mn[r] = fmaxf(m_run[r], tm[r]);
      al[r] = __expf(m_run[r] - mn[r]);
      rs[r] = 0.f;
    }
#pragma unroll
    for (int kt = 0; kt < 8; ++kt)
#pragma unroll
      for (int r = 0; r < 4; ++r) {
        float pv = __expf(s[kt][r] * scale - mn[r]);
        s[kt][r] = pv;
        rs[r] += pv;
      }
#pragma unroll
    for (int mask = 1; mask < 16; mask <<= 1)
#pragma unroll
      for (int r = 0; r < 4; ++r) rs[r] += __shfl_xor(rs[r], mask);
#pragma unroll
    for (int r = 0; r < 4; ++r) {
      l_run[r] = l_run[r] * al[r] + rs[r];
      m_run[r] = mn[r];
      o0[r] *= al[r];
      o1[r] *= al[r];
    }
#pragma unroll
    for (int kt = 0; kt < 8; ++kt)
#pragma unroll
      for (int r = 0; r < 4; ++r)
        P_lds[wv][(l >> 4) * 4 + r][kt * 16 + (l & 15)] = (short)f2bf(s[kt][r]);
#pragma unroll
    for (int kc = 0; kc < 4; ++kc) {
      short8 ap = *(const short8*)&P_lds[wv][l & 15][kc * 32 + (l >> 4) * 8];
      short8 b0 = *(const short8*)&Vh[(size_t)(l & 15) * 2048 + k0 + kc * 32 + (l >> 4) * 8];
      short8 b1 = *(const short8*)&Vh[(size_t)(16 + (l & 15)) * 2048 + k0 + kc * 32 + (l >> 4) * 8];
      mfma_bf16(o0, ap, b0);
      mfma_bf16(o1, ap, b1);
    }
  }
  asm volatile("s_nop 7\n\ts_nop 7" ::);
#pragma unroll
  for (int r = 0; r < 4; ++r) {
    float inv = 1.f / l_run[r];
    int qr = q0 + (l >> 4) * 4 + r;
    Oa[(size_t)qr * 256 + h * 32 + (l & 15)] = o0[r] * inv;
    Oa[(size_t)qr * 256 + h * 32 + 16 + (l & 15)] = o1[r] * inv;
  }
}

// out-projection (8 rows/block) fused with scatter into final output columns
__global__ __launch_bounds__(256) void k_outproj8(const float* __restrict__ Oa,
                                                  const float* __restrict__ owT,
                                                  const float* __restrict__ ob,
                                                  const int* __restrict__ idx,
                                                  float* __restrict__ out) {
  __shared__ float xo[8][256];
  int j0 = blockIdx.x * 8;
  int c = threadIdx.x;
  for (int r = 0; r < 8; ++r) xo[r][c] = Oa[(size_t)(j0 + r) * 256 + c];
  __syncthreads();
  float a[8];
#pragma unroll
  for (int r = 0; r < 8; ++r) a[r] = ob[c];
  for (int i = 0; i < 256; ++i) {
    float wv = owT[i * 256 + c];
#pragma unroll
    for (int r = 0; r < 8; ++r) a[r] += xo[r][i] * wv;
  }
#pragma unroll
  for (int r = 0; r < 8; ++r) out[(size_t)c * HWP + idx[j0 + r]] = a[r];
}

extern "C" void kernel_launch(void* const* d_in, const int* in_sizes, int n_in,
                              void* d_out, int out_size, void* d_ws, size_t ws_size,
                              hipStream_t stream) {
  const float* down  = (const float*)d_in[0];
  const float* swint = (const float*)d_in[1];
  const float* wt_w  = (const float*)d_in[2];
  const float* wt_b  = (const float*)d_in[3];
  const float* up_dw = (const float*)d_in[4];
  const float* up_db = (const float*)d_in[5];
  const float* up_cw = (const float*)d_in[6];
  const float* up_cb = (const float*)d_in[7];
  const float* gate_w = (const float*)d_in[8];
  const float* in_w  = (const float*)d_in[10];
  const float* in_b  = (const float*)d_in[11];
  const float* out_w = (const float*)d_in[12];
  const float* out_b = (const float*)d_in[13];
  float* out = (float*)d_out;
  char* ws = (char*)d_ws;

  float* bufA = (float*)ws;
  unsigned* actA = (unsigned*)ws;
  unsigned* actB = (unsigned*)(ws + BUF_B_OFF);
  unsigned int* keys = (unsigned int*)(ws + KEYS_OFF);
  unsigned int* hist = (unsigned int*)(ws + HIST_OFF);
  SelState* st = (SelState*)(ws + STATE_OFF);
  int* idx = (int*)(ws + IDX_OFF);
  int* eq = (int*)(ws + EQ_OFF);
  float* Oa = (float*)(ws + OA_OFF);
  float* wTi = (float*)(ws + WTI_OFF);
  float* wTo = (float*)(ws + WTO_OFF);
  float* srows = (float*)(ws + SROWS_OFF);
  short* wB5 = (short*)(ws + WT5_OFF);
  short* Qb = (short*)(ws + QB_OFF);
  short* Kb = (short*)(ws + KB_OFF);
  short* Vt = (short*)(ws + VT_OFF);
  short* cpk = (short*)(ws + CPK_OFF);
  short* dpk = (short*)(ws + DPK_OFF);

  k_init<<<1, 256, 0, stream>>>(hist, st);

  // fused gate + passthrough copy, then exact top-k (radix select)
  k_gatecopy<<<256, 256, 0, stream>>>(down, gate_w, out, keys);
  for (int r = 0; r < 4; ++r) {
    k_hist<<<256, 256, 0, stream>>>(keys, hist, st, r);
    k_scan<<<1, 256, 0, stream>>>(hist, st);
  }
  k_compact<<<256, 256, 0, stream>>>(keys, st, idx, eq);
  k_finalize<<<1, 64, 0, stream>>>(st, idx, eq);

  // weight packs (batched over layers)
  k_packc3<<<dim3(256, 4), 256, 0, stream>>>(up_cw, cpk);
  k_packdc<<<dim3(256, 4), 256, 0, stream>>>(up_dw, dpk);
  k_packc5<<<256, 256, 0, stream>>>(up_cw + 2359296, wB5);

  // upsampler chain: MFMA bf16 implicit-GEMM, packed-bf16 activations (A/B ping-pong)
  k_wtconv<<<256, 64, 0, stream>>>(swint, wt_w, wt_b, bufA);
  k_deconv<8><<<dim3(1, 256), 256, 0, stream>>>(bufA, up_dw, up_db, (unsigned short*)actB);
  k_conv3x2<16><<<dim3(8, 4), 256, 0, stream>>>(actB, cpk, up_cb, actA);
  k_deconvx3<16><<<dim3(8, 4, 2), 256, 0, stream>>>(actA, dpk, up_db + 256, actB);
  k_conv3x2<32><<<dim3(16, 4), 256, 0, stream>>>(actB, cpk + 589824, up_cb + 256, actA);
  k_deconvx3<32><<<dim3(16, 4, 2), 256, 0, stream>>>(actA, dpk + 1048576, up_db + 512, actB);
  k_conv3x2<64><<<dim3(32, 4), 256, 0, stream>>>(actB, cpk + 2 * 589824, up_cb + 512, actA);
  k_deconvx3<64><<<dim3(32, 4, 2), 256, 0, stream>>>(actA, dpk + 2 * 1048576, up_db + 768, actB);
  k_conv3x2<128><<<dim3(64, 4), 256, 0, stream>>>(actB, cpk + 3 * 589824, up_cb + 768, actA);
  k_deconvx3<128><<<dim3(64, 4, 2), 256, 0, stream>>>(actA, dpk + 3 * 1048576, up_db + 1024, actB);

  // in/out projection transposed weights
  k_transpose<<<768, 256, 0, stream>>>(in_w, wTi, 768);
  k_transpose<<<256, 256, 0, stream>>>(out_w, wTo, 256);

  // final conv3 via MFMA at the 2048 gathered positions (reads packed actB)
  k_conv3sM<<<dim3(128, 2), 256, 0, stream>>>(actB, wB5, up_cb + 1024, idx, srows);

  // attention path: bf16 QKV, fused flash attention, out-projection
  k_qkv2<<<512, 256, 0, stream>>>(down, srows, idx, wTi, in_b, Qb, Kb, Vt);
  k_fattn<<<dim3(32, 8), 256, 0, stream>>>(Qb, Kb, Vt, Oa);
  k_outproj8<<<256, 256, 0, stream>>>(Oa, wTo, out_b, idx, out);
}

// Round 9
// 787.456 us; speedup vs baseline: 22.2605x; 1.0454x over previous
//
#include <hip/hip_runtime.h>
#include <math.h>

#define CCH 256
#define HWP 65536
#define PCI 40   // padded ci stride (shorts) in LDS

typedef short short8 __attribute__((ext_vector_type(8)));
typedef float f32x4 __attribute__((ext_vector_type(4)));
typedef unsigned short us4 __attribute__((ext_vector_type(4)));

__device__ inline unsigned short f2bf(float f) {
  unsigned u = __float_as_uint(f);
  return (unsigned short)((u + 0x7FFFu + ((u >> 16) & 1u)) >> 16);
}
__device__ inline float bf2f(unsigned short s) {
  return __uint_as_float(((unsigned)s) << 16);
}

__device__ inline void mfma_bf16(f32x4& d, short8 a, short8 b) {
  asm volatile("v_mfma_f32_16x16x32_bf16 %0, %1, %2, %0" : "+v"(d) : "v"(a), "v"(b));
}

// ---- ws layout (bytes) ----
static const size_t BUF_B_OFF = 67108864;        // bufA @0 (64MB), bufB @64MB
static const size_t TAIL_OFF  = 134217728;
static const size_t KEYS_OFF  = TAIL_OFF;
static const size_t HIST_OFF  = TAIL_OFF + 262144;
static const size_t STATE_OFF = TAIL_OFF + 263168;
static const size_t IDX_OFF   = TAIL_OFF + 263424;
static const size_t EQ_OFF    = TAIL_OFF + 271616;
static const size_t OA_OFF    = 6291456;
static const size_t WTI_OFF   = 8388608;
static const size_t WTO_OFF   = 9437184;
static const size_t SROWS_OFF = 10485760;
static const size_t WT5_OFF   = 20971520;        // bf16 wB[256][2304] 1.18MB
static const size_t QB_OFF    = 31457280;
static const size_t KB_OFF    = 32505856;
static const size_t VT_OFF    = 33554432;
static const size_t CPK_OFF   = 37748736;
static const size_t DPK_OFF   = 44040192;

struct SelState { unsigned int P; int kneed; int nGreater; int nEqual; };

__global__ void k_init(unsigned int* hist, SelState* st) {
  int t = threadIdx.x;
  hist[t] = 0;
  if (t == 0) { st->P = 0u; st->kneed = 2048; st->nGreater = 0; st->nEqual = 0; }
}

// 1x1 conv 768->256 on 8x8
__global__ void k_wtconv(const float* __restrict__ swint, const float* __restrict__ w,
                         const float* __restrict__ b, float* __restrict__ out) {
  int co = blockIdx.x, p = threadIdx.x;
  float acc = b[co];
  for (int ci = 0; ci < 768; ++ci) acc += swint[ci * 64 + p] * w[co * 768 + ci];
  out[co * 64 + p] = acc;
}

// deconv 4x4 stride2 pad2 + bias + relu, f32 in (S=8), packed-bf16 out
template <int S>
__global__ __launch_bounds__(256) void k_deconv(const float* __restrict__ x,
                                                const float* __restrict__ w,
                                                const float* __restrict__ bias,
                                                unsigned short* __restrict__ yp) {
  const int SO = 2 * S;
  const int TX = SO / 16;
  int co = blockIdx.y;
  int tile = blockIdx.x;
  int ty0 = (tile / TX) * 16, tx0 = (tile % TX) * 16;
  int t = threadIdx.x;
  int ly = t >> 4, lx = t & 15;
  int oy = ty0 + ly, ox = tx0 + lx;
  int iyb = (ty0 >> 1) - 1, ixb = (tx0 >> 1) - 1;
  int p = oy & 1, q = ox & 1;
  int iyA = ((oy + p - 2) >> 1) - iyb;
  int ixA = ((ox + q - 2) >> 1) - ixb;
  int i00 = (3 - p) * 4 + (3 - q);
  int i01 = (3 - p) * 4 + (1 - q);
  int i10 = (1 - p) * 4 + (3 - q);
  int i11 = (1 - p) * 4 + (1 - q);
  __shared__ float lx_s[8][10][10];
  __shared__ float lw_s[8][16];
  float acc = bias[co];
  for (int c0 = 0; c0 < CCH; c0 += 8) {
    __syncthreads();
    for (int i = t; i < 800; i += 256) {
      int u = i / 100, rem = i % 100;
      int r = rem / 10, c = rem % 10;
      int gy = iyb + r, gx = ixb + c;
      float v = 0.f;
      if (gy >= 0 && gy < S && gx >= 0 && gx < S)
        v = x[(size_t)(c0 + u) * S * S + gy * S + gx];
      lx_s[u][r][c] = v;
    }
    if (t < 128) {
      int u = t >> 4, e = t & 15;
      lw_s[u][e] = w[(size_t)(c0 + u) * 4096 + co * 16 + e];
    }
    __syncthreads();
#pragma unroll
    for (int u = 0; u < 8; ++u) {
      acc += lx_s[u][iyA][ixA]     * lw_s[u][i00]
           + lx_s[u][iyA][ixA + 1] * lw_s[u][i01]
           + lx_s[u][iyA + 1][ixA]     * lw_s[u][i10]
           + lx_s[u][iyA + 1][ixA + 1] * lw_s[u][i11];
    }
  }
  acc = fmaxf(acc, 0.f);
  yp[((size_t)(co >> 1) * SO * SO + (size_t)oy * SO + ox) * 2 + (co & 1)] = f2bf(acc);
}

// pack conv3 weights (4 layers): [co][ci][9] f32 -> bf16 [tap][co][ci]
__global__ void k_packc3(const float* __restrict__ w, short* __restrict__ wpk) {
  int layer = blockIdx.y;
  const float* wl = w + (size_t)layer * 589824;
  short* wo = wpk + (size_t)layer * 589824;
  int co = blockIdx.x, ci = threadIdx.x;
  for (int tap = 0; tap < 9; ++tap)
    wo[((size_t)(tap * 256 + co) * 256) + ci] = (short)f2bf(wl[((size_t)(co * 256 + ci)) * 9 + tap]);
}

// pack deconv weights (layers 1..4): [ci][co][4][4] f32 -> bf16 [pq][tt][co][ci]
__global__ void k_packdc(const float* __restrict__ w, short* __restrict__ wpk) {
  int layer = blockIdx.y;
  const float* wl = w + (size_t)(layer + 1) * 1048576;
  int co = blockIdx.x, ci = threadIdx.x;
  for (int pq = 0; pq < 4; ++pq) {
    int p = pq >> 1, q = pq & 1;
    for (int tt = 0; tt < 4; ++tt) {
      int dyi = tt >> 1, dxi = tt & 1;
      int wr = dyi ? (1 - p) : (3 - p);
      int wc = dxi ? (1 - q) : (3 - q);
      wpk[((size_t)layer * 1048576) + ((size_t)((pq * 4 + tt) * 256 + co) * 256) + ci] =
          (short)f2bf(wl[((size_t)(ci * 256 + co)) * 16 + wr * 4 + wc]);
    }
  }
}

// pack stage-5 conv weights: wB[co][c*288 + e*32 + cl] = w[co][(c*32+cl)*9 + e], bf16
__global__ void k_packc5(const float* __restrict__ w, short* __restrict__ wB) {
  int co = blockIdx.x;
  for (int kk = threadIdx.x; kk < 2304; kk += 256) {
    int c = kk / 288, r = kk % 288;
    int e = r >> 5, cl = r & 31;
    wB[(size_t)co * 2304 + kk] = (short)f2bf(w[(size_t)co * 2304 + (size_t)(c * 32 + cl) * 9 + e]);
  }
}

// MFMA conv3x3 pad1 + bias, O output rows per block, all-9-tap weight stage
// (2 barriers per ci-chunk). Packed bf16 in/out.
template <int S, int O>
__global__ __launch_bounds__(256) void k_conv3u(const unsigned* __restrict__ xp,
                                                const short* __restrict__ wpk,
                                                const float* __restrict__ bias,
                                                unsigned* __restrict__ yp) {
  constexpr int WPC = (S >= 64) ? 2 : 1;
  constexpr int WCO = 4 / WPC;
  constexpr int COS = 64 / WCO;
  constexpr int MR = COS / 16;
  constexpr int PSP = S / WPC;
  constexpr int NR = PSP / 16;
  constexpr int CBK = (S + 2 + 31) / 32;
  constexpr int RS = O + 2;
  __shared__ short x_s[RS * (S + 2) * PCI];
  __shared__ short w_s[9 * 64 * PCI];
  unsigned* x_s32 = (unsigned*)x_s;
  int t = threadIdx.x, l = t & 63, wv = t >> 6;
  int wcob = (wv % WCO) * COS;
  int wposb = (wv / WCO) * PSP;
  int row0 = blockIdx.x * O;
  int co0 = blockIdx.y * 64;
  int colb = t & 31, ci2b = t >> 5;
  f32x4 acc[O][MR][NR];
#pragma unroll
  for (int o = 0; o < O; ++o)
#pragma unroll
    for (int m = 0; m < MR; ++m)
#pragma unroll
      for (int n = 0; n < NR; ++n) { f32x4 z = {0.f, 0.f, 0.f, 0.f}; acc[o][m][n] = z; }
  for (int c0 = 0; c0 < CCH; c0 += 32) {
    int cb = c0 >> 1;
    __syncthreads();
#pragma unroll
    for (int r = 0; r < RS; ++r) {
      int gy = row0 - 1 + r;
      bool yok = (gy >= 0 && gy < S);
#pragma unroll
      for (int cbk = 0; cbk < CBK; ++cbk) {
        int col = colb + cbk * 32;
        if (col < S + 2) {
          int gx = col - 1;
          bool ok = yok && (gx >= 0) && (gx < S);
          unsigned v0 = 0, v1 = 0;
          if (ok) {
            size_t gbase = (size_t)(cb + ci2b) * S * S + (size_t)gy * S + gx;
            v0 = xp[gbase];
            v1 = xp[gbase + (size_t)8 * S * S];
          }
          int lb = (r * (S + 2) + col) * (PCI / 2);
          x_s32[lb + ci2b] = v0;
          x_s32[lb + ci2b + 8] = v1;
        }
      }
    }
    // stage all 9 taps of weights: 9*64 rows x 32 ci
    for (int i = t; i < 4608; i += 256) {
      int ci4 = i & 7;
      int tc = i >> 3;            // tap*64 + co
      int tap = tc >> 6, co = tc & 63;
      us4 wv4 = *(const us4*)&wpk[((size_t)(tap * 256 + co0 + co) * 256) + c0 + ci4 * 4];
      *(us4*)&w_s[tc * PCI + ci4 * 4] = wv4;
    }
    __syncthreads();
#pragma unroll
    for (int dyg = 0; dyg < 3; ++dyg)
#pragma unroll
      for (int dx = 0; dx < 3; ++dx) {
        short8 a[MR];
#pragma unroll
        for (int m = 0; m < MR; ++m)
          a[m] = *(const short8*)&w_s[((dyg * 3 + dx) * 64 + wcob + m * 16 + (l & 15)) * PCI + (l >> 4) * 8];
#pragma unroll
        for (int o = 0; o < O; ++o) {
          short8 b[NR];
#pragma unroll
          for (int n = 0; n < NR; ++n)
            b[n] = *(const short8*)&x_s[((dyg + o) * (S + 2) + wposb + n * 16 + (l & 15) + dx) * PCI + (l >> 4) * 8];
#pragma unroll
          for (int m = 0; m < MR; ++m)
#pragma unroll
            for (int n = 0; n < NR; ++n) mfma_bf16(acc[o][m][n], a[m], b[n]);
        }
      }
  }
  asm volatile("s_nop 7\n\ts_nop 7" ::);
#pragma unroll
  for (int o = 0; o < O; ++o)
#pragma unroll
    for (int m = 0; m < MR; ++m)
#pragma unroll
      for (int n = 0; n < NR; ++n) {
        int cob = co0 + wcob + m * 16 + (l >> 4) * 4;
        int px = wposb + n * 16 + (l & 15);
#pragma unroll
        for (int r4p = 0; r4p < 2; ++r4p) {
          unsigned pk = (unsigned)f2bf(acc[o][m][n][2 * r4p] + bias[cob + 2 * r4p])
                      | ((unsigned)f2bf(acc[o][m][n][2 * r4p + 1] + bias[cob + 2 * r4p + 1]) << 16);
          yp[(size_t)((cob >> 1) + r4p) * S * S + (size_t)(row0 + o) * S + px] = pk;
        }
      }
}

// MFMA deconv4x4 s2 p2 + bias + relu, O input rows + both q parities per block.
template <int S, int O>
__global__ __launch_bounds__(256) void k_deconvu(const unsigned* __restrict__ xp,
                                                 const short* __restrict__ wpk,
                                                 const float* __restrict__ bias,
                                                 unsigned* __restrict__ yp) {
  constexpr int WPC = (S >= 64) ? 2 : 1;
  constexpr int WCO = 4 / WPC;
  constexpr int COS = 64 / WCO;
  constexpr int MR = COS / 16;
  constexpr int PSP = S / WPC;
  constexpr int NR = PSP / 16;
  constexpr int CBK = (S + 2 + 31) / 32;
  constexpr int RS = O + 1;
  const int SO = 2 * S;
  __shared__ short x_s[RS * (S + 2) * PCI];
  __shared__ short w_s[8 * 64 * PCI];
  unsigned* x_s32 = (unsigned*)x_s;
  int t = threadIdx.x, l = t & 63, wv = t >> 6;
  int wcob = (wv % WCO) * COS;
  int wposb = (wv / WCO) * PSP;
  int row0 = blockIdx.x * O;
  int co0 = blockIdx.y * 64;
  int p = blockIdx.z;
  int colb = t & 31, ci2b = t >> 5;
  f32x4 acc[2][O][MR][NR];  // [q][o][m][n]
#pragma unroll
  for (int q = 0; q < 2; ++q)
#pragma unroll
    for (int o = 0; o < O; ++o)
#pragma unroll
      for (int m = 0; m < MR; ++m)
#pragma unroll
        for (int n = 0; n < NR; ++n) { f32x4 z = {0.f, 0.f, 0.f, 0.f}; acc[q][o][m][n] = z; }
  for (int c0 = 0; c0 < CCH; c0 += 32) {
    int cb = c0 >> 1;
    __syncthreads();
#pragma unroll
    for (int r = 0; r < RS; ++r) {
      int gy = row0 + p - 1 + r;
      bool yok = (gy >= 0 && gy < S);
#pragma unroll
      for (int cbk = 0; cbk < CBK; ++cbk) {
        int col = colb + cbk * 32;
        if (col < S + 2) {
          int gx = col - 1;
          bool ok = yok && (gx >= 0) && (gx < S);
          unsigned v0 = 0, v1 = 0;
          if (ok) {
            size_t gbase = (size_t)(cb + ci2b) * S * S + (size_t)gy * S + gx;
            v0 = xp[gbase];
            v1 = xp[gbase + (size_t)8 * S * S];
          }
          int lb = (r * (S + 2) + col) * (PCI / 2);
          x_s32[lb + ci2b] = v0;
          x_s32[lb + ci2b + 8] = v1;
        }
      }
    }
    for (int i = t; i < 4096; i += 256) {
      int seg8 = i & 7;
      int rowi = i >> 3;
      int c8 = rowi >> 6, co = rowi & 63;
      int qq = c8 >> 2, tt = c8 & 3;
      us4 wv4 = *(const us4*)&wpk[((size_t)(((2 * p + qq) * 4 + tt) * 256 + co0 + co) * 256) + c0 + seg8 * 4];
      *(us4*)&w_s[rowi * PCI + seg8 * 4] = wv4;
    }
    __syncthreads();
#pragma unroll
    for (int dyi = 0; dyi < 2; ++dyi)
#pragma unroll
      for (int o = 0; o < O; ++o) {
        short8 b[3][NR];
#pragma unroll
        for (int off = 0; off < 3; ++off)
#pragma unroll
          for (int n = 0; n < NR; ++n)
            b[off][n] = *(const short8*)&x_s[((dyi + o) * (S + 2) + wposb + n * 16 + (l & 15) + off) * PCI + (l >> 4) * 8];
#pragma unroll
        for (int q = 0; q < 2; ++q)
#pragma unroll
          for (int dxi = 0; dxi < 2; ++dxi) {
            int c8 = q * 4 + dyi * 2 + dxi;
            short8 a[MR];
#pragma unroll
            for (int m = 0; m < MR; ++m)
              a[m] = *(const short8*)&w_s[(c8 * 64 + wcob + m * 16 + (l & 15)) * PCI + (l >> 4) * 8];
#pragma unroll
            for (int m = 0; m < MR; ++m)
#pragma unroll
              for (int n = 0; n < NR; ++n) mfma_bf16(acc[q][o][m][n], a[m], b[dxi + q][n]);
          }
      }
  }
  asm volatile("s_nop 7\n\ts_nop 7" ::);
#pragma unroll
  for (int o = 0; o < O; ++o) {
    int oy = 2 * (row0 + o) + p;
#pragma unroll
    for (int m = 0; m < MR; ++m)
#pragma unroll
      for (int n = 0; n < NR; ++n) {
        int px = wposb + n * 16 + (l & 15);
#pragma unroll
        for (int r4p = 0; r4p < 2; ++r4p) {
          int cob = co0 + wcob + m * 16 + (l >> 4) * 4 + 2 * r4p;
          float b0 = bias[cob], b1 = bias[cob + 1];
          unsigned pk0 = (unsigned)f2bf(fmaxf(acc[0][o][m][n][2 * r4p] + b0, 0.f))
                       | ((unsigned)f2bf(fmaxf(acc[0][o][m][n][2 * r4p + 1] + b1, 0.f)) << 16);
          unsigned pk1 = (unsigned)f2bf(fmaxf(acc[1][o][m][n][2 * r4p] + b0, 0.f))
                       | ((unsigned)f2bf(fmaxf(acc[1][o][m][n][2 * r4p + 1] + b1, 0.f)) << 16);
          uint2 pk = make_uint2(pk0, pk1);
          *(uint2*)&yp[(size_t)(cob >> 1) * SO * SO + (size_t)oy * SO + 2 * px] = pk;
        }
      }
  }
}

// sparse final conv3 via MFMA. out[j][co] = sum_k A[j][k]*wB[co][k] + bias[co].
__global__ __launch_bounds__(256) void k_conv3sM(const unsigned* __restrict__ xp,
                                                 const short* __restrict__ wB,
                                                 const float* __restrict__ bias,
                                                 const int* __restrict__ idx,
                                                 float* __restrict__ out) {
  __shared__ short a_s[16][296];
  __shared__ int py_s[16], px_s[16];
  int t = threadIdx.x, l = t & 63, wv = t >> 6;
  int j0 = blockIdx.x * 16;
  int co0 = blockIdx.y * 128 + wv * 32;
  if (t < 16) {
    int p = idx[j0 + t];
    py_s[t] = p >> 8;
    px_s[t] = p & 255;
  }
  f32x4 acc[2];
  { f32x4 z = {0.f, 0.f, 0.f, 0.f}; acc[0] = z; acc[1] = z; }
  for (int c = 0; c < 8; ++c) {
    __syncthreads();
    for (int i = t; i < 2304; i += 256) {
      int ci2 = i & 15;
      int je = i >> 4;
      int j = je / 9, e = je % 9;
      int gy = py_s[j] - 1 + e / 3, gx = px_s[j] - 1 + e % 3;
      unsigned v = 0;
      if (gy >= 0 && gy < 256 && gx >= 0 && gx < 256)
        v = xp[(size_t)(c * 16 + ci2) * HWP + gy * 256 + gx];
      *(unsigned*)&a_s[j][e * 32 + 2 * ci2] = v;
    }
    __syncthreads();
#pragma unroll
    for (int s = 0; s < 9; ++s) {
      short8 a = *(const short8*)&a_s[l & 15][s * 32 + (l >> 4) * 8];
      int kg = c * 288 + s * 32 + (l >> 4) * 8;
      short8 b0 = *(const short8*)&wB[(size_t)(co0 + (l & 15)) * 2304 + kg];
      short8 b1 = *(const short8*)&wB[(size_t)(co0 + 16 + (l & 15)) * 2304 + kg];
      mfma_bf16(acc[0], a, b0);
      mfma_bf16(acc[1], a, b1);
    }
  }
  asm volatile("s_nop 7\n\ts_nop 7" ::);
#pragma unroll
  for (int n = 0; n < 2; ++n)
#pragma unroll
    for (int r = 0; r < 4; ++r) {
      int j = j0 + (l >> 4) * 4 + r;
      int co = co0 + n * 16 + (l & 15);
      out[(size_t)j * 256 + co] = acc[n][r] + bias[co];
    }
}

// fused: passthrough copy of down into out + gate keys
__global__ void k_gatecopy(const float* __restrict__ down, const float* __restrict__ gw,
                           float* __restrict__ out, unsigned int* __restrict__ keys) {
  int p = blockIdx.x * 256 + threadIdx.x;
  float acc = 0.f;
  for (int c = 0; c < CCH; ++c) {
    float v = down[(size_t)c * HWP + p];
    out[(size_t)c * HWP + p] = v;
    acc += v * gw[c];
  }
  unsigned int u = __float_as_uint(acc);
  keys[p] = (u & 0x80000000u) ? ~u : (u | 0x80000000u);
}

__global__ void k_hist(const unsigned int* __restrict__ keys, unsigned int* hist,
                       const SelState* st, int r) {
  __shared__ unsigned int lh[256];
  int t = threadIdx.x;
  lh[t] = 0;
  __syncthreads();
  unsigned int key = keys[blockIdx.x * 256 + t];
  bool ok = (r == 0) || ((key >> (32 - 8 * r)) == st->P);
  if (ok) atomicAdd(&lh[(key >> (24 - 8 * r)) & 255u], 1u);
  __syncthreads();
  if (lh[t]) atomicAdd(&hist[t], lh[t]);
}

__global__ void k_scan(unsigned int* hist, SelState* st) {
  if (threadIdx.x == 0) {
    int need = st->kneed;
    unsigned int cum = 0;
    for (int b = 255; b >= 0; --b) {
      unsigned int h = hist[b];
      if (cum + h >= (unsigned int)need) {
        st->P = (st->P << 8) | (unsigned int)b;
        st->kneed = need - (int)cum;
        break;
      }
      cum += h;
    }
  }
  __syncthreads();
  hist[threadIdx.x] = 0;
}

__global__ void k_compact(const unsigned int* __restrict__ keys, SelState* st,
                          int* __restrict__ idx, int* __restrict__ eq) {
  int p = blockIdx.x * 256 + threadIdx.x;
  unsigned int key = keys[p];
  unsigned int P = st->P;
  if (key > P) {
    int pos = atomicAdd(&st->nGreater, 1);
    idx[pos] = p;
  } else if (key == P) {
    int e = atomicAdd(&st->nEqual, 1);
    if (e < 4096) eq[e] = p;
  }
}

__global__ void k_finalize(SelState* st, int* idx, int* eq) {
  if (threadIdx.x != 0) return;
  int n = st->nEqual;
  if (n > 4096) n = 4096;
  for (int i = 1; i < n; ++i) {
    int v = eq[i], j = i - 1;
    while (j >= 0 && eq[j] > v) { eq[j + 1] = eq[j]; --j; }
    eq[j + 1] = v;
  }
  int g = st->nGreater;
  for (int i = 0; i < st->kneed; ++i) idx[g + i] = eq[i];
}

__global__ void k_transpose(const float* __restrict__ in, float* __restrict__ out, int rows) {
  int o = blockIdx.x, c = threadIdx.x;
  out[(size_t)c * rows + o] = in[(size_t)o * 256 + c];
}

// gather rows at idx, project to Q,K,V, emit bf16 Qb/Kb[h][q][d] and Vt[h][d][q]
__global__ __launch_bounds__(256) void k_qkv2(const float* __restrict__ down,
                                              const float* __restrict__ srows,
                                              const int* __restrict__ idx,
                                              const float* __restrict__ wT,
                                              const float* __restrict__ bias,
                                              short* __restrict__ Qb,
                                              short* __restrict__ Kb,
                                              short* __restrict__ Vt) {
  __shared__ float xq[4][256], xk[4][256];
  int j0 = blockIdx.x * 4;
  int c = threadIdx.x;
  for (int r = 0; r < 4; ++r) {
    int p = idx[j0 + r];
    xq[r][c] = down[(size_t)c * HWP + p];
    xk[r][c] = srows[(size_t)(j0 + r) * 256 + c];
  }
  __syncthreads();
  float aq[4], ak[4], av[4];
#pragma unroll
  for (int r = 0; r < 4; ++r) {
    aq[r] = bias[c]; ak[r] = bias[256 + c]; av[r] = bias[512 + c];
  }
  for (int i = 0; i < 256; ++i) {
    float wq = wT[i * 768 + c];
    float wk = wT[i * 768 + 256 + c];
    float wv = wT[i * 768 + 512 + c];
#pragma unroll
    for (int r = 0; r < 4; ++r) {
      float xv = xq[r][i], kv = xk[r][i];
      aq[r] += xv * wq;
      ak[r] += kv * wk;
      av[r] += kv * wv;
    }
  }
  int h = c >> 5, d = c & 31;
#pragma unroll
  for (int r = 0; r < 4; ++r) {
    int j = j0 + r;
    Qb[((size_t)h * 2048 + j) * 32 + d] = (short)f2bf(aq[r]);
    Kb[((size_t)h * 2048 + j) * 32 + d] = (short)f2bf(ak[r]);
    Vt[((size_t)h * 32 + d) * 2048 + j] = (short)f2bf(av[r]);
  }
}

// fused flash attention: QK^T -> online softmax -> PV. grid (32 qtiles, 8 h), 4 waves.
__global__ __launch_bounds__(256) void k_fattn(const short* __restrict__ Qb,
                                               const short* __restrict__ Kb,
                                               const short* __restrict__ Vt,
                                               float* __restrict__ Oa) {
  __shared__ short P_lds[4][16][136];
  int t = threadIdx.x, l = t & 63, wv = t >> 6;
  int h = blockIdx.y;
  int q0 = blockIdx.x * 64 + wv * 16;
  const short* Qh = Qb + (size_t)h * 2048 * 32;
  const short* Kh = Kb + (size_t)h * 2048 * 32;
  const short* Vh = Vt + (size_t)h * 32 * 2048;
  short8 a_q = *(const short8*)&Qh[(size_t)(q0 + (l & 15)) * 32 + (l >> 4) * 8];
  f32x4 o0 = {0.f, 0.f, 0.f, 0.f}, o1 = {0.f, 0.f, 0.f, 0.f};
  float m_run[4], l_run[4];
#pragma unroll
  for (int r = 0; r < 4; ++r) { m_run[r] = -3e38f; l_run[r] = 0.f; }
  const float scale = 0.17677669529663687f;
  for (int k0 = 0; k0 < 2048; k0 += 128) {
    f32x4 s[8];
#pragma unroll
    for (int kt = 0; kt < 8; ++kt) {
      f32x4 z = {0.f, 0.f, 0.f, 0.f};
      s[kt] = z;
      short8 b = *(const short8*)&Kh[(size_t)(k0 + kt * 16 + (l & 15)) * 32 + (l >> 4) * 8];
      mfma_bf16(s[kt], a_q, b);
    }
    asm volatile("s_nop 7\n\ts_nop 7" ::);
    float tm[4];
#pragma unroll
    for (int r = 0; r < 4; ++r) {
      float mx = s[0][r];
#pragma unroll
      for (int kt = 1; kt < 8; ++kt) mx = fmaxf(mx, s[kt][r]);
      tm[r] = mx * scale;
    }
#pragma unroll
    for (int mask = 1; mask < 16; mask <<= 1)
#pragma unroll
      for (int r = 0; r < 4; ++r) tm[r] = fmaxf(tm[r], __shfl_xor(tm[r], mask));
    float mn[4], al[4], rs[4];
#pragma unroll
    for (int r = 0; r < 4; ++r) {
      mn[r] = fmaxf(m_run[r], tm[r]);
      al[r] = __expf(m_run[r] - mn[r]);
      rs[r] = 0.f;
    }
#pragma unroll
    for (int kt = 0; kt < 8; ++kt)
#pragma unroll
      for (int r = 0; r < 4; ++r) {
        float pv = __expf(s[kt][r] * scale - mn[r]);
        s[kt][r] = pv;
        rs[r] += pv;
      }
#pragma unroll
    for (int mask = 1; mask < 16; mask <<= 1)
#pragma unroll
      for (int r = 0; r < 4; ++r) rs[r] += __shfl_xor(rs[r], mask);
#pragma unroll
    for (int r = 0; r < 4; ++r) {
      l_run[r] = l_run[r] * al[r] + rs[r];
      m_run[r] = mn[r];
      o0[r] *= al[r];
      o1[r] *= al[r];
    }
#pragma unroll
    for (int kt = 0; kt < 8; ++kt)
#pragma unroll
      for (int r = 0; r < 4; ++r)
        P_lds[wv][(l >> 4) * 4 + r][kt * 16 + (l & 15)] = (short)f2bf(s[kt][r]);
#pragma unroll
    for (int kc = 0; kc < 4; ++kc) {
      short8 ap = *(const short8*)&P_lds[wv][l & 15][kc * 32 + (l >> 4) * 8];
      short8 b0 = *(const short8*)&Vh[(size_t)(l & 15) * 2048 + k0 + kc * 32 + (l >> 4) * 8];
      short8 b1 = *(const short8*)&Vh[(size_t)(16 + (l & 15)) * 2048 + k0 + kc * 32 + (l >> 4) * 8];
      mfma_bf16(o0, ap, b0);
      mfma_bf16(o1, ap, b1);
    }
  }
  asm volatile("s_nop 7\n\ts_nop 7" ::);
#pragma unroll
  for (int r = 0; r < 4; ++r) {
    float inv = 1.f / l_run[r];
    int qr = q0 + (l >> 4) * 4 + r;
    Oa[(size_t)qr * 256 + h * 32 + (l & 15)] = o0[r] * inv;
    Oa[(size_t)qr * 256 + h * 32 + 16 + (l & 15)] = o1[r] * inv;
  }
}

// out-projection (8 rows/block) fused with scatter into final output columns
__global__ __launch_bounds__(256) void k_outproj8(const float* __restrict__ Oa,
                                                  const float* __restrict__ owT,
                                                  const float* __restrict__ ob,
                                                  const int* __restrict__ idx,
                                                  float* __restrict__ out) {
  __shared__ float xo[8][256];
  int j0 = blockIdx.x * 8;
  int c = threadIdx.x;
  for (int r = 0; r < 8; ++r) xo[r][c] = Oa[(size_t)(j0 + r) * 256 + c];
  __syncthreads();
  float a[8];
#pragma unroll
  for (int r = 0; r < 8; ++r) a[r] = ob[c];
  for (int i = 0; i < 256; ++i) {
    float wv = owT[i * 256 + c];
#pragma unroll
    for (int r = 0; r < 8; ++r) a[r] += xo[r][i] * wv;
  }
#pragma unroll
  for (int r = 0; r < 8; ++r) out[(size_t)c * HWP + idx[j0 + r]] = a[r];
}

extern "C" void kernel_launch(void* const* d_in, const int* in_sizes, int n_in,
                              void* d_out, int out_size, void* d_ws, size_t ws_size,
                              hipStream_t stream) {
  const float* down  = (const float*)d_in[0];
  const float* swint = (const float*)d_in[1];
  const float* wt_w  = (const float*)d_in[2];
  const float* wt_b  = (const float*)d_in[3];
  const float* up_dw = (const float*)d_in[4];
  const float* up_db = (const float*)d_in[5];
  const float* up_cw = (const float*)d_in[6];
  const float* up_cb = (const float*)d_in[7];
  const float* gate_w = (const float*)d_in[8];
  const float* in_w  = (const float*)d_in[10];
  const float* in_b  = (const float*)d_in[11];
  const float* out_w = (const float*)d_in[12];
  const float* out_b = (const float*)d_in[13];
  float* out = (float*)d_out;
  char* ws = (char*)d_ws;

  float* bufA = (float*)ws;
  unsigned* actA = (unsigned*)ws;
  unsigned* actB = (unsigned*)(ws + BUF_B_OFF);
  unsigned int* keys = (unsigned int*)(ws + KEYS_OFF);
  unsigned int* hist = (unsigned int*)(ws + HIST_OFF);
  SelState* st = (SelState*)(ws + STATE_OFF);
  int* idx = (int*)(ws + IDX_OFF);
  int* eq = (int*)(ws + EQ_OFF);
  float* Oa = (float*)(ws + OA_OFF);
  float* wTi = (float*)(ws + WTI_OFF);
  float* wTo = (float*)(ws + WTO_OFF);
  float* srows = (float*)(ws + SROWS_OFF);
  short* wB5 = (short*)(ws + WT5_OFF);
  short* Qb = (short*)(ws + QB_OFF);
  short* Kb = (short*)(ws + KB_OFF);
  short* Vt = (short*)(ws + VT_OFF);
  short* cpk = (short*)(ws + CPK_OFF);
  short* dpk = (short*)(ws + DPK_OFF);

  k_init<<<1, 256, 0, stream>>>(hist, st);

  // fused gate + passthrough copy, then exact top-k (radix select)
  k_gatecopy<<<256, 256, 0, stream>>>(down, gate_w, out, keys);
  for (int r = 0; r < 4; ++r) {
    k_hist<<<256, 256, 0, stream>>>(keys, hist, st, r);
    k_scan<<<1, 256, 0, stream>>>(hist, st);
  }
  k_compact<<<256, 256, 0, stream>>>(keys, st, idx, eq);
  k_finalize<<<1, 64, 0, stream>>>(st, idx, eq);

  // weight packs (batched over layers)
  k_packc3<<<dim3(256, 4), 256, 0, stream>>>(up_cw, cpk);
  k_packdc<<<dim3(256, 4), 256, 0, stream>>>(up_dw, dpk);
  k_packc5<<<256, 256, 0, stream>>>(up_cw + 2359296, wB5);

  // upsampler chain: MFMA bf16 implicit-GEMM, packed-bf16 activations (A/B ping-pong)
  k_wtconv<<<256, 64, 0, stream>>>(swint, wt_w, wt_b, bufA);
  k_deconv<8><<<dim3(1, 256), 256, 0, stream>>>(bufA, up_dw, up_db, (unsigned short*)actB);
  k_conv3u<16, 2><<<dim3(8, 4), 256, 0, stream>>>(actB, cpk, up_cb, actA);
  k_deconvu<16, 2><<<dim3(8, 4, 2), 256, 0, stream>>>(actA, dpk, up_db + 256, actB);
  k_conv3u<32, 2><<<dim3(16, 4), 256, 0, stream>>>(actB, cpk + 589824, up_cb + 256, actA);
  k_deconvu<32, 2><<<dim3(16, 4, 2), 256, 0, stream>>>(actA, dpk + 1048576, up_db + 512, actB);
  k_conv3u<64, 1><<<dim3(64, 4), 256, 0, stream>>>(actB, cpk + 2 * 589824, up_cb + 512, actA);
  k_deconvu<64, 1><<<dim3(64, 4, 2), 256, 0, stream>>>(actA, dpk + 2 * 1048576, up_db + 768, actB);
  k_conv3u<128, 1><<<dim3(128, 4), 256, 0, stream>>>(actB, cpk + 3 * 589824, up_cb + 768, actA);
  k_deconvu<128, 2><<<dim3(64, 4, 2), 256, 0, stream>>>(actA, dpk + 3 * 1048576, up_db + 1024, actB);

  // in/out projection transposed weights
  k_transpose<<<768, 256, 0, stream>>>(in_w, wTi, 768);
  k_transpose<<<256, 256, 0, stream>>>(out_w, wTo, 256);

  // final conv3 via MFMA at the 2048 gathered positions (reads packed actB)
  k_conv3sM<<<dim3(128, 2), 256, 0, stream>>>(actB, wB5, up_cb + 1024, idx, srows);

  // attention path: bf16 QKV, fused flash attention, out-projection
  k_qkv2<<<512, 256, 0, stream>>>(down, srows, idx, wTi, in_b, Qb, Kb, Vt);
  k_fattn<<<dim3(32, 8), 256, 0, stream>>>(Qb, Kb, Vt, Oa);
  k_outproj8<<<256, 256, 0, stream>>>(Oa, wTo, out_b, idx, out);
}